// Round 2
// baseline (1961.513 us; speedup 1.0000x reference)
//
#include <hip/hip_runtime.h>
#include <math.h>
#include <stdint.h>

#define NLAT 128
#define NLON 256
#define PI_F 3.14159265358979323846f
#define TWO_PI_F 6.28318530717958647692f

typedef unsigned short u16;
typedef __attribute__((ext_vector_type(8))) short bf16x8;
typedef __attribute__((ext_vector_type(4))) float f32x4;

__device__ __forceinline__ u16 f2b(float f) {
    union { float f; uint32_t u; } v; v.f = f;
    uint32_t r = v.u + 0x7fffu + ((v.u >> 16) & 1u);
    return (u16)(r >> 16);
}
__device__ __forceinline__ float b2f(u16 u) {
    union { uint32_t u; float f; } v; v.u = ((uint32_t)u) << 16;
    return v.f;
}
__device__ __forceinline__ ushort4 pack4(float a, float b, float c, float d) {
    ushort4 r; r.x = f2b(a); r.y = f2b(b); r.z = f2b(c); r.w = f2b(d); return r;
}
__device__ __forceinline__ float gelu_tanh(float x) {
    float x3 = x * x * x;
    return 0.5f * x * (1.0f + tanhf(0.7978845608028654f * (x + 0.044715f * x3)));
}
__device__ __forceinline__ float leaky(float x) { return x >= 0.0f ? x : 0.2f * x; }

__device__ __forceinline__ float lat_weight(const float* __restrict__ lat, int i, int n) {
    float w = cosf(lat[i]);
    if ((i == 0 || i == n - 1) && w < 0.001f) {
        float dlat = lat[1] - lat[0];
        float s = sinf(dlat * 0.25f);
        w = s * s / sinf(dlat * 0.5f);
    }
    return w;
}

// async global->LDS, 16B per lane; LDS dest is wave-uniform base + lane*16
__device__ __forceinline__ void gload16(const void* g, void* l) {
    __builtin_amdgcn_global_load_lds(
        (const __attribute__((address_space(1))) void*)(uintptr_t)g,
        (__attribute__((address_space(3))) void*)(uintptr_t)l,
        16, 0, 0);
}

// ================================================================ generic 128x128 MFMA GEMM
// A: [M][KD] (bf16 K-major, or fp32 if AF32). B: [N][KD] bf16 (n-major rows).
// BK=64, global_load_lds staging, both-sides XOR chunk swizzle (chunk ^= row&7).
// Grid: (N/128, M/128) — col fastest so A panels are read once (B is small & L2-resident).
// EPI: 0 gelu->bf16 O0[row][1536]; 1 split v/uu/uskip; 2 +bias2+uskip -> fp32 O0[row][256];
//      3 plain fp32 O0[row][256].
template<int KD, int EPI, bool AF32>
__global__ __launch_bounds__(256) void gemm128_kernel(
    const void* __restrict__ Aptr, const u16* __restrict__ B,
    const float* __restrict__ bias, const float* __restrict__ uskip,
    void* __restrict__ O0, void* __restrict__ O1, void* __restrict__ O2)
{
    __shared__ __align__(16) u16 sA[128][64];
    __shared__ __align__(16) u16 sB[128][64];
    const int t = threadIdx.x;
    const int lane = t & 63, w = t >> 6;
    const int ln = lane & 15, q = lane >> 4;
    const int wr = w >> 1, wc = w & 1;
    const int row0 = blockIdx.y * 128;
    const int col0 = blockIdx.x * 128;
    // async staging geometry: wave w, issue s covers rows s*32 + w*8 + (lane>>3);
    // each lane loads the 16B chunk (lane&7) XOR-swizzled by row&7 (= (lane>>3))
    const int grow = w * 8 + (lane >> 3);
    const int gcol = ((lane & 7) ^ (lane >> 3)) * 8;
    const int sr = t >> 1, sh = t & 1;

    f32x4 acc[16];
    #pragma unroll
    for (int i = 0; i < 16; ++i) acc[i] = (f32x4){0.f, 0.f, 0.f, 0.f};

    for (int k0 = 0; k0 < KD; k0 += 64) {
        __syncthreads();
        if (AF32) {
            // reg-stage fp32 -> bf16 (can't async): thread t covers row sr, cols sh*32..+31
            const float* Ag = (const float*)Aptr + (size_t)(row0 + sr) * KD + k0 + sh * 32;
            #pragma unroll
            for (int j = 0; j < 8; ++j) {
                float4 f = *(const float4*)(Ag + j * 4);
                int cp = (((4 * sh + (j >> 1)) ^ (sr & 7)) * 8) + (j & 1) * 4;
                *(ushort4*)&sA[sr][cp] = pack4(f.x, f.y, f.z, f.w);
            }
        } else {
            const u16* Ag = (const u16*)Aptr + (size_t)(row0 + grow) * KD + k0 + gcol;
            #pragma unroll
            for (int s = 0; s < 4; ++s)
                gload16(Ag + (size_t)(s * 32) * KD, &sA[s * 32 + w * 8][0]);
        }
        {
            const u16* Bg = B + (size_t)(col0 + grow) * KD + k0 + gcol;
            #pragma unroll
            for (int s = 0; s < 4; ++s)
                gload16(Bg + (size_t)(s * 32) * KD, &sB[s * 32 + w * 8][0]);
        }
        __syncthreads();
        #pragma unroll
        for (int kk = 0; kk < 2; ++kk) {
            bf16x8 af[4], bfr[4];
            #pragma unroll
            for (int x = 0; x < 4; ++x) {
                int ra = wr * 64 + x * 16 + ln;
                af[x] = *(const bf16x8*)&sA[ra][((kk * 4 + q) ^ (ra & 7)) * 8];
            }
            #pragma unroll
            for (int x = 0; x < 4; ++x) {
                int rb = wc * 64 + x * 16 + ln;
                bfr[x] = *(const bf16x8*)&sB[rb][((kk * 4 + q) ^ (rb & 7)) * 8];
            }
            #pragma unroll
            for (int rt = 0; rt < 4; ++rt)
                #pragma unroll
                for (int ct = 0; ct < 4; ++ct)
                    acc[rt * 4 + ct] = __builtin_amdgcn_mfma_f32_16x16x32_bf16(af[rt], bfr[ct], acc[rt * 4 + ct], 0, 0, 0);
        }
    }

    #pragma unroll
    for (int rt = 0; rt < 4; ++rt)
        #pragma unroll
        for (int ct = 0; ct < 4; ++ct) {
            int col = col0 + wc * 64 + ct * 16 + ln;
            float bv = (EPI == 3) ? 0.f : bias[col];
            #pragma unroll
            for (int r = 0; r < 4; ++r) {
                int row = row0 + wr * 64 + rt * 16 + q * 4 + r;
                float x = acc[rt * 4 + ct][r] + bv;
                if (EPI == 0) {
                    ((u16*)O0)[(size_t)row * 1536 + col] = f2b(gelu_tanh(x));
                } else if (EPI == 1) {
                    if (col < 512)      ((u16*)O0)[(size_t)row * 512 + col] = f2b(x);
                    else if (col < 768) ((u16*)O1)[(size_t)row * 256 + col - 512] = f2b(x);
                    else                ((float*)O2)[(size_t)row * 256 + col - 768] = x;
                } else if (EPI == 2) {
                    ((float*)O0)[(size_t)row * 256 + col] = x + uskip[(size_t)row * 256 + col];
                } else {
                    ((float*)O0)[(size_t)row * 256 + col] = x;
                }
            }
        }
}

// ---------------------------------------------------------------- W conversions
__global__ void conv_w1t_kernel(const float* __restrict__ w1, u16* __restrict__ w1t) {
    int idx = blockIdx.x * 256 + threadIdx.x;       // grid 1536: w1t[1536][256]
    int j = idx >> 8, i = idx & 255;
    w1t[idx] = f2b(w1[(size_t)i * 1536 + j]);
}
__global__ void conv_w2t_kernel(const float* __restrict__ w2, u16* __restrict__ w2t) {
    int k = blockIdx.x / 6, s = blockIdx.x % 6;     // grid 6144: w2t[1024][1536]
    int i = s * 256 + threadIdx.x;
    w2t[(size_t)k * 1536 + i] = f2b(w2[(size_t)i * 1024 + k]);
}
__global__ void conv_owt_kernel(const float* __restrict__ ow, u16* __restrict__ owt) {
    int n = blockIdx.x, k = threadIdx.x;            // owt[256][256]
    owt[(size_t)n * 256 + k] = f2b(ow[(size_t)k * 256 + n]);
}

// ---------------------------------------------------------------- K1 fallback: fused cm MLP (R4, verified)
__global__ __launch_bounds__(256, 2) void cm_mlp_mfma_kernel(
    const float* __restrict__ u, const u16* __restrict__ w1t, const float* __restrict__ b1,
    const u16* __restrict__ w2t, const float* __restrict__ b2,
    u16* __restrict__ v, u16* __restrict__ uu, float* __restrict__ uskip)
{
    __shared__ __align__(16) u16 sA[16][264];
    __shared__ __align__(16) u16 sH[16][520];
    const int t = threadIdx.x;
    const int lane = t & 63, w = t >> 6;
    const int ln = lane & 15, q = lane >> 4;
    const int row0 = blockIdx.x * 16;

    for (int x = t; x < 1024; x += 256) {
        int r = x >> 6, c0 = (x & 63) * 4;
        float4 xx = *(const float4*)(u + (size_t)(row0 + r) * 256 + c0);
        sA[r][c0 + 0] = f2b(xx.x); sA[r][c0 + 1] = f2b(xx.y);
        sA[r][c0 + 2] = f2b(xx.z); sA[r][c0 + 3] = f2b(xx.w);
    }
    f32x4 c2[16];
    #pragma unroll
    for (int i = 0; i < 16; ++i) c2[i] = (f32x4){0.f, 0.f, 0.f, 0.f};

    for (int jj = 0; jj < 3; ++jj) {
        __syncthreads();
        f32x4 c1[8];
        #pragma unroll
        for (int i = 0; i < 8; ++i) c1[i] = (f32x4){0.f, 0.f, 0.f, 0.f};
        {
            const u16* w1p = w1t + (size_t)(jj * 512 + w * 128 + ln) * 256 + q * 8;
            #pragma unroll
            for (int k0 = 0; k0 < 256; k0 += 32) {
                bf16x8 a = *(const bf16x8*)&sA[ln][k0 + q * 8];
                #pragma unroll
                for (int nt = 0; nt < 8; ++nt) {
                    bf16x8 b = *(const bf16x8*)(w1p + (size_t)nt * 16 * 256 + k0);
                    c1[nt] = __builtin_amdgcn_mfma_f32_16x16x32_bf16(a, b, c1[nt], 0, 0, 0);
                }
            }
        }
        #pragma unroll
        for (int nt = 0; nt < 8; ++nt) {
            int col = w * 128 + nt * 16 + ln;
            float bias = b1[jj * 512 + col];
            #pragma unroll
            for (int r = 0; r < 4; ++r)
                sH[q * 4 + r][col] = f2b(gelu_tanh(c1[nt][r] + bias));
        }
        __syncthreads();
        const u16* w2p = w2t + (size_t)(w * 256 + ln) * 1536 + jj * 512 + q * 8;
        #pragma unroll 2
        for (int k0 = 0; k0 < 512; k0 += 32) {
            bf16x8 a = *(const bf16x8*)&sH[ln][k0 + q * 8];
            #pragma unroll
            for (int nt = 0; nt < 16; ++nt) {
                bf16x8 b = *(const bf16x8*)(w2p + (size_t)nt * 16 * 1536 + k0);
                c2[nt] = __builtin_amdgcn_mfma_f32_16x16x32_bf16(a, b, c2[nt], 0, 0, 0);
            }
        }
    }
    #pragma unroll
    for (int nt = 0; nt < 16; ++nt) {
        int col = w * 256 + nt * 16 + ln;
        float bias = b2[col];
        #pragma unroll
        for (int r = 0; r < 4; ++r) {
            int row = row0 + q * 4 + r;
            float val = c2[nt][r] + bias;
            if (col < 512)      v[(size_t)row * 512 + col] = f2b(val);
            else if (col < 768) uu[(size_t)row * 256 + (col - 512)] = f2b(val);
            else                uskip[(size_t)row * 256 + (col - 768)] = val;
        }
    }
}

// ---------------------------------------------------------------- K2: means of uu
__global__ void mean_over_lat_kernel(const u16* __restrict__ uu, float* __restrict__ Mlong) {
    int l = blockIdx.x, d = threadIdx.x;
    float s = 0.f;
    for (int i = 0; i < NLAT; ++i) s += b2f(uu[((size_t)i * NLON + l) * 256 + d]);
    Mlong[(size_t)l * 256 + d] = s * (1.0f / NLAT);
}
__global__ void mean_over_lon_kernel(const u16* __restrict__ uu, float* __restrict__ Mlat) {
    int i = blockIdx.x, d = threadIdx.x;
    const u16* p = uu + (size_t)i * NLON * 256 + d;
    float s = 0.f;
    for (int l = 0; l < NLON; ++l) s += b2f(p[(size_t)l * 256]);
    Mlat[(size_t)i * 256 + d] = s * (1.0f / NLON);
}

__device__ float block_sum256(float x, float* red) {
    #pragma unroll
    for (int o = 32; o > 0; o >>= 1) x += __shfl_down(x, o, 64);
    int wid = threadIdx.x >> 6, lane = threadIdx.x & 63;
    if (lane == 0) red[wid] = x;
    __syncthreads();
    float s = red[0] + red[1] + red[2] + red[3];
    __syncthreads();
    return s;
}

// ---------------------------------------------------------------- K3: pool MLP
__global__ __launch_bounds__(256) void pool_mlp_kernel(
    const float* __restrict__ xin, const float* __restrict__ in_w,
    const float* __restrict__ ln_g, const float* __restrict__ ln_b,
    const float* __restrict__ fc1_w, const float* __restrict__ fc1_b,
    const float* __restrict__ fc2_w, const float* __restrict__ fc2_b,
    const float* __restrict__ lat, float* __restrict__ out)
{
    __shared__ float sx[256], sy[256], sg[256], red[4];
    int row = blockIdx.x, t = threadIdx.x;
    sx[t] = xin[(size_t)row * 256 + t];
    __syncthreads();
    float acc = 0.f;
    #pragma unroll 4
    for (int i = 0; i < 256; ++i) acc = fmaf(sx[i], in_w[i * 256 + t], acc);
    if (lat) acc *= lat_weight(lat, row, NLAT);
    float m = block_sum256(acc, red) * (1.f / 256.f);
    float var = block_sum256(acc * acc, red) * (1.f / 256.f) - m * m;
    float xn = (acc - m) * rsqrtf(var + 1e-5f) * ln_g[t] + ln_b[t];
    sy[t] = xn;
    __syncthreads();
    float h1 = fc1_b[t], h2 = fc1_b[t + 256];
    #pragma unroll 4
    for (int i = 0; i < 256; ++i) {
        float s = sy[i];
        h1 = fmaf(s, fc1_w[i * 512 + t], h1);
        h2 = fmaf(s, fc1_w[i * 512 + 256 + t], h2);
    }
    float g = h1 * gelu_tanh(h2);
    sg[t] = g;
    __syncthreads();
    float o = fc2_b[t];
    #pragma unroll 4
    for (int i = 0; i < 256; ++i) o = fmaf(sg[i], fc2_w[i * 256 + t], o);
    out[(size_t)row * 256 + t] = o;
}

// ---------------------------------------------------------------- K4: bessel
__global__ void bessel_kernel(const float* __restrict__ coord, int n,
                              const float* __restrict__ freq, int nf,
                              const float* __restrict__ w, float* __restrict__ mod,
                              int periodic)
{
    int i = blockIdx.x, j = threadIdx.x;
    float d = fabsf(coord[j] - coord[i]);
    if (periodic) d = fminf(d, TWO_PI_F - d);
    float acc[8];
    #pragma unroll
    for (int h = 0; h < 8; ++h) acc[h] = 0.f;
    bool big = d > 1e-6f;
    float inv = big ? 1.f / d : 0.f;
    for (int k = 0; k < nf; ++k) {
        float f = freq[k];
        float basis = big ? sinf(f * d) * inv : f;
        #pragma unroll
        for (int h = 0; h < 8; ++h) acc[h] = fmaf(basis, w[k * 8 + h], acc[h]);
    }
    #pragma unroll
    for (int h = 0; h < 8; ++h) mod[((size_t)h * n + i) * n + j] = acc[h];
}

// ---------------------------------------------------------------- K5: projections (tiled, latency-fixed)
__global__ __launch_bounds__(256) void proj_tile_kernel(
    const float* __restrict__ x, const float* __restrict__ w,
    float* __restrict__ c)
{
    const int t = threadIdx.x;
    const int j = blockIdx.y * 256 + t;
    const float* xp = x + (size_t)blockIdx.x * 16 * 256;
    const float* wp = w + j;
    float acc[16];
    #pragma unroll
    for (int r = 0; r < 16; ++r) acc[r] = 0.f;
    for (int i0 = 0; i0 < 256; i0 += 4) {
        float w0 = wp[(size_t)(i0 + 0) * 1536];
        float w1 = wp[(size_t)(i0 + 1) * 1536];
        float w2 = wp[(size_t)(i0 + 2) * 1536];
        float w3 = wp[(size_t)(i0 + 3) * 1536];
        #pragma unroll
        for (int r = 0; r < 16; ++r) {
            float4 xv = *(const float4*)(xp + r * 256 + i0);   // uniform -> s_load_dwordx4
            acc[r] = fmaf(xv.x, w0, acc[r]);
            acc[r] = fmaf(xv.y, w1, acc[r]);
            acc[r] = fmaf(xv.z, w2, acc[r]);
            acc[r] = fmaf(xv.w, w3, acc[r]);
        }
    }
    float* cp = c + (size_t)blockIdx.x * 16 * 1536 + j;
    #pragma unroll
    for (int r = 0; r < 16; ++r) cp[(size_t)r * 1536] = acc[r];
}

// ---------------------------------------------------------------- K6a: k_long -> KlongA[h][l][m] bf16 (K-major)
__global__ __launch_bounds__(256) void kmat_long_kernel(
    const float* __restrict__ q, const float* __restrict__ kp,
    const float* __restrict__ mod, u16* __restrict__ KA)
{
    int blk = blockIdx.x;              // h*256 + l   (grid 2048)
    int l = blk & 255, h = blk >> 8;
    __shared__ float sq[192];
    int t = threadIdx.x;
    if (t < 192) sq[t] = q[(size_t)l * 1536 + h * 192 + t];
    __syncthreads();
    const float* kpp = kp + (size_t)t * 1536 + h * 192;
    float acc = 0.f;
    #pragma unroll 4
    for (int c = 0; c < 192; ++c) acc = fmaf(kpp[c], sq[c], acc);
    float mv = mod[((size_t)h * 256 + l) * 256 + t];
    float val = leaky(acc * mv) * (TWO_PI_F / 256.f);
    KA[((size_t)h * 256 + l) * 256 + t] = f2b(val);
}

// ---------------------------------------------------------------- K6b: k_lat -> KlatA[h][i][j] bf16 (K-major)
__global__ __launch_bounds__(128) void kmat_lat_kernel(
    const float* __restrict__ q, const float* __restrict__ kp,
    const float* __restrict__ mod, const float* __restrict__ lat, u16* __restrict__ KA)
{
    int blk = blockIdx.x;              // h*128 + i   (grid 1024)
    int i = blk & 127, h = blk >> 7;
    __shared__ float sq[192];
    int t = threadIdx.x;
    for (int c = t; c < 192; c += 128) sq[c] = q[(size_t)i * 1536 + h * 192 + c];
    __syncthreads();
    const float* kpp = kp + (size_t)t * 1536 + h * 192;
    float acc = 0.f;
    #pragma unroll 4
    for (int c = 0; c < 192; ++c) acc = fmaf(kpp[c], sq[c], acc);
    float mv = mod[((size_t)h * 128 + i) * 128 + t];
    float wl = lat_weight(lat, t, NLAT);
    float val = leaky(acc * mv) * wl * (PI_F / 128.f);
    KA[((size_t)h * 128 + i) * 128 + t] = f2b(val);
}

// ---------------------------------------------------------------- K7: einsum1 MFMA (per batch)
__global__ __launch_bounds__(256) void einsum1_kernel(
    const u16* __restrict__ KlatA, const u16* __restrict__ v, u16* __restrict__ tmp1)
{
    int blk = blockIdx.x;              // h*256 + m (grid 2048)
    int m = blk & 255, h = blk >> 8;
    __shared__ __align__(16) u16 sV[64][136];   // [c][j], rows 272 B (16-aligned)
    const int t = threadIdx.x;
    const int lane = t & 63, w = t >> 6;
    const int ln = lane & 15, q = lane >> 4;

    {   // transpose-stage v slice [j=128][c=64] -> sV[c][j]
        int j = t >> 1, c0 = (t & 1) * 32;
        const u16* vp = v + ((size_t)j * 256 + m) * 512 + h * 64 + c0;
        union { uint4 q4[4]; u16 s[32]; } buf;
        buf.q4[0] = *(const uint4*)(vp);
        buf.q4[1] = *(const uint4*)(vp + 8);
        buf.q4[2] = *(const uint4*)(vp + 16);
        buf.q4[3] = *(const uint4*)(vp + 24);
        #pragma unroll
        for (int cc = 0; cc < 32; ++cc) sV[c0 + cc][j] = buf.s[cc];
    }
    __syncthreads();

    f32x4 acc[8];
    #pragma unroll
    for (int i = 0; i < 8; ++i) acc[i] = (f32x4){0.f, 0.f, 0.f, 0.f};
    const u16* ka = KlatA + (size_t)h * 128 * 128;
    for (int ch = 0; ch < 4; ++ch) {
        int j0 = ch * 32;
        bf16x8 b = *(const bf16x8*)&sV[w * 16 + ln][j0 + q * 8];
        #pragma unroll
        for (int it = 0; it < 8; ++it) {
            bf16x8 a = *(const bf16x8*)(ka + (size_t)(it * 16 + ln) * 128 + j0 + q * 8);
            acc[it] = __builtin_amdgcn_mfma_f32_16x16x32_bf16(a, b, acc[it], 0, 0, 0);
        }
    }
    int c = w * 16 + ln;
    #pragma unroll
    for (int it = 0; it < 8; ++it)
        #pragma unroll
        for (int r = 0; r < 4; ++r) {
            int i = it * 16 + q * 4 + r;
            tmp1[(((size_t)h * 128 + i) * 256 + m) * 64 + c] = f2b(acc[it][r]);
        }
}

// ---------------------------------------------------------------- K8: einsum2 MFMA + GN stats (per batch)
__global__ __launch_bounds__(256) void einsum2_kernel(
    const u16* __restrict__ tmp1, const u16* __restrict__ KlongA,
    u16* __restrict__ Aout, float* __restrict__ gnstat)
{
    int blk = blockIdx.x;              // h*128 + i (grid 1024)
    int i = blk & 127, h = blk >> 7;
    __shared__ __align__(16) u16 sT[64][264];   // [c][m], rows 528 B (16-aligned)
    __shared__ float red2[8];
    const int t = threadIdx.x;
    const int lane = t & 63, w = t >> 6;
    const int ln = lane & 15, q = lane >> 4;

    {   // transpose-stage tmp1 slice [m=256][c=64] -> sT[c][m]
        const u16* tp = tmp1 + (((size_t)h * 128 + i) * 256 + t) * 64;
        union { uint4 q4[8]; u16 s[64]; } buf;
        #pragma unroll
        for (int x = 0; x < 8; ++x) buf.q4[x] = *(const uint4*)(tp + x * 8);
        #pragma unroll
        for (int cc = 0; cc < 64; ++cc) sT[cc][t] = buf.s[cc];
    }
    __syncthreads();

    f32x4 acc[16];
    #pragma unroll
    for (int x = 0; x < 16; ++x) acc[x] = (f32x4){0.f, 0.f, 0.f, 0.f};
    const u16* ka = KlongA + (size_t)h * 256 * 256;
    for (int ch = 0; ch < 8; ++ch) {
        int m0 = ch * 32;
        bf16x8 bf[4];
        #pragma unroll
        for (int ct = 0; ct < 4; ++ct) bf[ct] = *(const bf16x8*)&sT[ct * 16 + ln][m0 + q * 8];
        #pragma unroll
        for (int lt = 0; lt < 4; ++lt) {
            bf16x8 a = *(const bf16x8*)(ka + (size_t)(w * 64 + lt * 16 + ln) * 256 + m0 + q * 8);
            #pragma unroll
            for (int ct = 0; ct < 4; ++ct)
                acc[lt * 4 + ct] = __builtin_amdgcn_mfma_f32_16x16x32_bf16(a, bf[ct], acc[lt * 4 + ct], 0, 0, 0);
        }
    }
    float lsum = 0.f, lsq = 0.f;
    #pragma unroll
    for (int lt = 0; lt < 4; ++lt)
        #pragma unroll
        for (int ct = 0; ct < 4; ++ct) {
            int c = ct * 16 + ln;
            #pragma unroll
            for (int r = 0; r < 4; ++r) {
                int l = w * 64 + lt * 16 + q * 4 + r;
                float val = acc[lt * 4 + ct][r];
                Aout[((size_t)i * 256 + l) * 512 + h * 64 + c] = f2b(val);
                lsum += val; lsq += val * val;
            }
        }
    #pragma unroll
    for (int o = 32; o > 0; o >>= 1) {
        lsum += __shfl_down(lsum, o, 64);
        lsq  += __shfl_down(lsq, o, 64);
    }
    if ((t & 63) == 0) { red2[w] = lsum; red2[4 + w] = lsq; }
    __syncthreads();
    if (t == 0) {
        atomicAdd(&gnstat[h * 2],     red2[0] + red2[1] + red2[2] + red2[3]);
        atomicAdd(&gnstat[h * 2 + 1], red2[4] + red2[5] + red2[6] + red2[7]);
    }
}

// ---------------------------------------------------------------- K9: fold GN into merge weights (per batch)
__global__ __launch_bounds__(256) void gn_fold_kernel(
    const float* __restrict__ gnstat, const float* __restrict__ gn_g, const float* __restrict__ gn_b,
    const float* __restrict__ mw, u16* __restrict__ Wp, float* __restrict__ bias2)
{
    __shared__ float red[4];
    int j = blockIdx.x, t = threadIdx.x;
    const float Ninv = 1.f / 2097152.f;   // 128*256*64
    float partial = 0.f;
    for (int k = t; k < 512; k += 256) {
        int h = k >> 6;
        float m = gnstat[h * 2] * Ninv;
        float var = gnstat[h * 2 + 1] * Ninv - m * m;
        float siv = rsqrtf(var + 1e-5f);
        float s = siv * gn_g[k];
        float tt = gn_b[k] - m * s;
        float wv = mw[(size_t)k * 256 + j];
        Wp[(size_t)j * 512 + k] = f2b(s * wv);
        partial += tt * wv;
    }
    float tot = block_sum256(partial, red);
    if (t == 0) bias2[j] = tot;
}

__global__ void zero_kernel(float* __restrict__ p, int n) {
    int i = blockIdx.x * blockDim.x + threadIdx.x;
    if (i < n) p[i] = 0.f;
}

// ================================================================ launch
extern "C" void kernel_launch(void* const* d_in, const int* in_sizes, int n_in,
                              void* d_out, int out_size, void* d_ws, size_t ws_size,
                              hipStream_t stream) {
    if (ws_size < 77856896ULL) return;   // known-good minimum from R3/R4
    const bool BIG = (ws_size >= 184549376ULL);  // de-fused cm path needs 96MB hidden

    const float* u        = (const float*)d_in[0];
    const float* lat      = (const float*)d_in[1];
    const float* lon      = (const float*)d_in[2];
    const float* cm_w1    = (const float*)d_in[3];
    const float* cm_b1    = (const float*)d_in[4];
    const float* cm_w2    = (const float*)d_in[5];
    const float* cm_b2    = (const float*)d_in[6];
    const float* long_in_w  = (const float*)d_in[7];
    const float* long_ln_g  = (const float*)d_in[8];
    const float* long_ln_b  = (const float*)d_in[9];
    const float* long_fc1_w = (const float*)d_in[10];
    const float* long_fc1_b = (const float*)d_in[11];
    const float* long_fc2_w = (const float*)d_in[12];
    const float* long_fc2_b = (const float*)d_in[13];
    const float* lat_in_w   = (const float*)d_in[14];
    const float* lat_ln_g   = (const float*)d_in[15];
    const float* lat_ln_b   = (const float*)d_in[16];
    const float* lat_fc1_w  = (const float*)d_in[17];
    const float* lat_fc1_b  = (const float*)d_in[18];
    const float* lat_fc2_w  = (const float*)d_in[19];
    const float* lat_fc2_b  = (const float*)d_in[20];
    const float* klong_q_w  = (const float*)d_in[21];
    const float* klong_k_w  = (const float*)d_in[22];
    const float* klat_q_w   = (const float*)d_in[23];
    const float* klat_k_w   = (const float*)d_in[24];
    const float* pe_long_freq = (const float*)d_in[25];
    const float* pe_long_w    = (const float*)d_in[26];
    const float* pe_lat_freq  = (const float*)d_in[27];
    const float* pe_lat_w     = (const float*)d_in[28];
    const float* gn_g    = (const float*)d_in[29];
    const float* gn_b    = (const float*)d_in[30];
    const float* merge_w = (const float*)d_in[31];
    const float* out_w   = (const float*)d_in[32];
    float* out = (float*)d_out;

    char* base = (char*)d_ws;
    u16*  vA   = (u16*)base;                          // v bf16 (32MB) -> Aout bf16 (32MB)
    char* reg1 = base + 33554432;                     // uu bf16 (16MB) -> tmp1 bf16 (32MB) -> D fp32 (32MB)
    u16*  uu   = (u16*)reg1;
    u16*  tmp1 = (u16*)reg1;
    float* D   = (float*)reg1;
    // small pool (floats from base+64MB); end = 76,940,416 B < 77,856,896 guard
    float* pool    = (float*)(base + 67108864);
    float* modlong = pool;                            // 524288
    float* modlat  = modlong + 524288;                // 131072
    float* Mlong   = modlat + 131072;                 // 65536
    float* Mlat    = Mlong + 65536;                   // 32768
    float* ulong   = Mlat + 32768;                    // 65536
    float* ulat    = ulong + 65536;                   // 32768
    float* qlong   = ulat + 32768;                    // 393216
    float* klongp  = qlong + 393216;                  // 393216
    float* qlat    = klongp + 393216;                 // 196608
    float* klatp   = qlat + 196608;                   // 196608
    float* gnstat  = klatp + 196608;                  // 32
    float* bias2   = gnstat + 32;                     // 256
    u16* KlongA = (u16*)(bias2 + 256);                // 524288 elems (1MB)
    u16* KlatA  = KlongA + 524288;                    // 131072 elems
    u16* Wp     = KlatA + 131072;                     // 131072 elems
    u16* owT    = Wp + 131072;                        // 65536 elems
    // small-path weight aliases (dead at cm time, re-converted per batch)
    u16* w1T = (u16*)qlong;                           // 786,432 B in qlong (1.5MB)
    u16* w2T = (u16*)klongp;                          // 3,145,728 B in klongp+qlat+klatp
    // big-path dedicated regions
    u16* w1Tb   = (u16*)(base + 79691776);            // 786,432 B
    u16* w2Tb   = (u16*)(base + 80478208);            // 3,145,728 B
    u16* hidden = (u16*)(base + 83886080);            // 100,663,296 B (32768x1536 bf16)

    zero_kernel<<<1, 32, 0, stream>>>(gnstat, 32);
    bessel_kernel<<<256, 256, 0, stream>>>(lon, 256, pe_long_freq, 64, pe_long_w, modlong, 1);
    bessel_kernel<<<128, 128, 0, stream>>>(lat, 128, pe_lat_freq, 32, pe_lat_w, modlat, 0);
    conv_owt_kernel<<<256, 256, 0, stream>>>(out_w, owT);
    if (BIG) {
        conv_w1t_kernel<<<1536, 256, 0, stream>>>(cm_w1, w1Tb);
        conv_w2t_kernel<<<6144, 256, 0, stream>>>(cm_w2, w2Tb);
    }

    for (int b = 0; b < 2; ++b) {
        const float* u_b  = u + (size_t)b * 32768 * 256;
        float* uskip_b    = out + (size_t)b * 8388608;
        float* gnstat_b   = gnstat + b * 16;

        if (BIG) {
            // GEMM1: hidden = gelu(u@W1+b1)  [32768 x 1536], K=256  (grid: col fastest)
            gemm128_kernel<256, 0, true><<<dim3(12, 256), 256, 0, stream>>>(
                u_b, w1Tb, cm_b1, nullptr, hidden, nullptr, nullptr);
            // GEMM2: hidden@W2+b2 -> v|uu|uskip  [32768 x 1024], K=1536
            gemm128_kernel<1536, 1, false><<<dim3(8, 256), 256, 0, stream>>>(
                hidden, w2Tb, cm_b2, nullptr, vA, uu, uskip_b);
        } else {
            conv_w1t_kernel<<<1536, 256, 0, stream>>>(cm_w1, w1T);
            conv_w2t_kernel<<<6144, 256, 0, stream>>>(cm_w2, w2T);
            cm_mlp_mfma_kernel<<<2048, 256, 0, stream>>>(u_b, w1T, cm_b1, w2T, cm_b2,
                                                         vA, uu, uskip_b);
        }
        mean_over_lat_kernel<<<256, 256, 0, stream>>>(uu, Mlong);
        mean_over_lon_kernel<<<128, 256, 0, stream>>>(uu, Mlat);
        pool_mlp_kernel<<<256, 256, 0, stream>>>(Mlong, long_in_w, long_ln_g, long_ln_b,
                                                 long_fc1_w, long_fc1_b, long_fc2_w, long_fc2_b,
                                                 nullptr, ulong);
        pool_mlp_kernel<<<128, 256, 0, stream>>>(Mlat, lat_in_w, lat_ln_g, lat_ln_b,
                                                 lat_fc1_w, lat_fc1_b, lat_fc2_w, lat_fc2_b,
                                                 lat, ulat);
        proj_tile_kernel<<<dim3(16, 6), 256, 0, stream>>>(ulong, klong_q_w, qlong);   // clobbers w1T (dead)
        proj_tile_kernel<<<dim3(16, 6), 256, 0, stream>>>(ulong, klong_k_w, klongp);  // clobbers w2T (dead)
        proj_tile_kernel<<<dim3(8, 6), 256, 0, stream>>>(ulat, klat_q_w, qlat);
        proj_tile_kernel<<<dim3(8, 6), 256, 0, stream>>>(ulat, klat_k_w, klatp);
        kmat_long_kernel<<<2048, 256, 0, stream>>>(qlong, klongp, modlong, KlongA);
        kmat_lat_kernel<<<1024, 128, 0, stream>>>(qlat, klatp, modlat, lat, KlatA);
        einsum1_kernel<<<2048, 256, 0, stream>>>(KlatA, vA, tmp1);       // tmp1 over uu (dead)
        einsum2_kernel<<<1024, 256, 0, stream>>>(tmp1, KlongA, vA, gnstat_b); // Aout over v (dead)
        gn_fold_kernel<<<256, 256, 0, stream>>>(gnstat_b, gn_g, gn_b, merge_w, Wp, bias2);
        // merge: D = GN(Aout)@mw + uskip   [32768 x 256], K=512  (D over tmp1, dead)
        gemm128_kernel<512, 2, false><<<dim3(2, 256), 256, 0, stream>>>(
            vA, Wp, bias2, uskip_b, D, nullptr, nullptr);
        // out: out = D@ow                  [32768 x 256], K=256
        gemm128_kernel<256, 3, true><<<dim3(2, 256), 256, 0, stream>>>(
            D, owT, nullptr, nullptr, out + (size_t)b * 8388608, nullptr, nullptr);
    }
}

// Round 3
// 1876.009 us; speedup vs baseline: 1.0456x; 1.0456x over previous
//
#include <hip/hip_runtime.h>
#include <math.h>
#include <stdint.h>

#define NLAT 128
#define NLON 256
#define PI_F 3.14159265358979323846f
#define TWO_PI_F 6.28318530717958647692f

typedef unsigned short u16;
typedef __attribute__((ext_vector_type(8))) short bf16x8;
typedef __attribute__((ext_vector_type(4))) float f32x4;

__device__ __forceinline__ u16 f2b(float f) {
    union { float f; uint32_t u; } v; v.f = f;
    uint32_t r = v.u + 0x7fffu + ((v.u >> 16) & 1u);
    return (u16)(r >> 16);
}
__device__ __forceinline__ float b2f(u16 u) {
    union { uint32_t u; float f; } v; v.u = ((uint32_t)u) << 16;
    return v.f;
}
__device__ __forceinline__ ushort4 pack4(float a, float b, float c, float d) {
    ushort4 r; r.x = f2b(a); r.y = f2b(b); r.z = f2b(c); r.w = f2b(d); return r;
}
__device__ __forceinline__ float gelu_tanh(float x) {
    float x3 = x * x * x;
    return 0.5f * x * (1.0f + tanhf(0.7978845608028654f * (x + 0.044715f * x3)));
}
__device__ __forceinline__ float leaky(float x) { return x >= 0.0f ? x : 0.2f * x; }

__device__ __forceinline__ float lat_weight(const float* __restrict__ lat, int i, int n) {
    float w = cosf(lat[i]);
    if ((i == 0 || i == n - 1) && w < 0.001f) {
        float dlat = lat[1] - lat[0];
        float s = sinf(dlat * 0.25f);
        w = s * s / sinf(dlat * 0.5f);
    }
    return w;
}

// async global->LDS, 16B per lane; LDS dest is wave-uniform base + lane*16
__device__ __forceinline__ void gload16(const void* g, void* l) {
    __builtin_amdgcn_global_load_lds(
        (const __attribute__((address_space(1))) void*)(uintptr_t)g,
        (__attribute__((address_space(3))) void*)(uintptr_t)l,
        16, 0, 0);
}

// ================================================================ generic 128x128 MFMA GEMM
// A: [M][KD] (bf16 K-major, or fp32 if AF32). B: [N][KD] bf16 (n-major rows).
// BK=64, global_load_lds staging, both-sides XOR chunk swizzle (chunk ^= row&7).
// Grid: (M/128, N/128) — ROW fastest (R1-measured lower fetch: consecutive blocks
// share the B col-panel per XCD L2 and stream A rows once).
// EPI: 0 gelu->bf16 O0[row][1536]; 1 split v/uu/uskip; 2 +bias2+uskip -> fp32 O0[row][256];
//      3 plain fp32 O0[row][256].
template<int KD, int EPI, bool AF32>
__global__ __launch_bounds__(256) void gemm128_kernel(
    const void* __restrict__ Aptr, const u16* __restrict__ B,
    const float* __restrict__ bias, const float* __restrict__ uskip,
    void* __restrict__ O0, void* __restrict__ O1, void* __restrict__ O2)
{
    __shared__ __align__(16) u16 sA[128][64];
    __shared__ __align__(16) u16 sB[128][64];
    const int t = threadIdx.x;
    const int lane = t & 63, w = t >> 6;
    const int ln = lane & 15, q = lane >> 4;
    const int wr = w >> 1, wc = w & 1;
    const int row0 = blockIdx.x * 128;
    const int col0 = blockIdx.y * 128;
    // async staging geometry: wave w, issue s covers rows s*32 + w*8 + (lane>>3);
    // each lane loads the 16B chunk (lane&7) XOR-swizzled by row&7 (= (lane>>3))
    const int grow = w * 8 + (lane >> 3);
    const int gcol = ((lane & 7) ^ (lane >> 3)) * 8;
    const int sr = t >> 1, sh = t & 1;

    f32x4 acc[16];
    #pragma unroll
    for (int i = 0; i < 16; ++i) acc[i] = (f32x4){0.f, 0.f, 0.f, 0.f};

    for (int k0 = 0; k0 < KD; k0 += 64) {
        __syncthreads();
        if (AF32) {
            // reg-stage fp32 -> bf16 (can't async): thread t covers row sr, cols sh*32..+31
            const float* Ag = (const float*)Aptr + (size_t)(row0 + sr) * KD + k0 + sh * 32;
            #pragma unroll
            for (int j = 0; j < 8; ++j) {
                float4 f = *(const float4*)(Ag + j * 4);
                int cp = (((4 * sh + (j >> 1)) ^ (sr & 7)) * 8) + (j & 1) * 4;
                *(ushort4*)&sA[sr][cp] = pack4(f.x, f.y, f.z, f.w);
            }
        } else {
            const u16* Ag = (const u16*)Aptr + (size_t)(row0 + grow) * KD + k0 + gcol;
            #pragma unroll
            for (int s = 0; s < 4; ++s)
                gload16(Ag + (size_t)(s * 32) * KD, &sA[s * 32 + w * 8][0]);
        }
        {
            const u16* Bg = B + (size_t)(col0 + grow) * KD + k0 + gcol;
            #pragma unroll
            for (int s = 0; s < 4; ++s)
                gload16(Bg + (size_t)(s * 32) * KD, &sB[s * 32 + w * 8][0]);
        }
        __syncthreads();
        #pragma unroll
        for (int kk = 0; kk < 2; ++kk) {
            bf16x8 af[4], bfr[4];
            #pragma unroll
            for (int x = 0; x < 4; ++x) {
                int ra = wr * 64 + x * 16 + ln;
                af[x] = *(const bf16x8*)&sA[ra][((kk * 4 + q) ^ (ra & 7)) * 8];
            }
            #pragma unroll
            for (int x = 0; x < 4; ++x) {
                int rb = wc * 64 + x * 16 + ln;
                bfr[x] = *(const bf16x8*)&sB[rb][((kk * 4 + q) ^ (rb & 7)) * 8];
            }
            #pragma unroll
            for (int rt = 0; rt < 4; ++rt)
                #pragma unroll
                for (int ct = 0; ct < 4; ++ct)
                    acc[rt * 4 + ct] = __builtin_amdgcn_mfma_f32_16x16x32_bf16(af[rt], bfr[ct], acc[rt * 4 + ct], 0, 0, 0);
        }
    }

    #pragma unroll
    for (int rt = 0; rt < 4; ++rt)
        #pragma unroll
        for (int ct = 0; ct < 4; ++ct) {
            int col = col0 + wc * 64 + ct * 16 + ln;
            float bv = (EPI == 3) ? 0.f : bias[col];
            #pragma unroll
            for (int r = 0; r < 4; ++r) {
                int row = row0 + wr * 64 + rt * 16 + q * 4 + r;
                float x = acc[rt * 4 + ct][r] + bv;
                if (EPI == 0) {
                    ((u16*)O0)[(size_t)row * 1536 + col] = f2b(gelu_tanh(x));
                } else if (EPI == 1) {
                    if (col < 512)      ((u16*)O0)[(size_t)row * 512 + col] = f2b(x);
                    else if (col < 768) ((u16*)O1)[(size_t)row * 256 + col - 512] = f2b(x);
                    else                ((float*)O2)[(size_t)row * 256 + col - 768] = x;
                } else if (EPI == 2) {
                    ((float*)O0)[(size_t)row * 256 + col] = x + uskip[(size_t)row * 256 + col];
                } else {
                    ((float*)O0)[(size_t)row * 256 + col] = x;
                }
            }
        }
}

// ---------------------------------------------------------------- W conversions
__global__ void conv_w1t_kernel(const float* __restrict__ w1, u16* __restrict__ w1t) {
    int idx = blockIdx.x * 256 + threadIdx.x;       // grid 1536: w1t[1536][256]
    int j = idx >> 8, i = idx & 255;
    w1t[idx] = f2b(w1[(size_t)i * 1536 + j]);
}
__global__ void conv_w2t_kernel(const float* __restrict__ w2, u16* __restrict__ w2t) {
    int k = blockIdx.x / 6, s = blockIdx.x % 6;     // grid 6144: w2t[1024][1536]
    int i = s * 256 + threadIdx.x;
    w2t[(size_t)k * 1536 + i] = f2b(w2[(size_t)i * 1024 + k]);
}
__global__ void conv_owt_kernel(const float* __restrict__ ow, u16* __restrict__ owt) {
    int n = blockIdx.x, k = threadIdx.x;            // owt[256][256]
    owt[(size_t)n * 256 + k] = f2b(ow[(size_t)k * 256 + n]);
}
// u fp32 -> bf16, same layout (bit-identical f2b rounding as the old in-GEMM pack)
__global__ void conv_ubf_kernel(const float* __restrict__ u, u16* __restrict__ ub) {
    size_t i = ((size_t)blockIdx.x * 256 + threadIdx.x) * 4;
    float4 f = *(const float4*)(u + i);
    *(ushort4*)(ub + i) = pack4(f.x, f.y, f.z, f.w);
}

// ---------------------------------------------------------------- K1 fallback: fused cm MLP (R4, verified)
__global__ __launch_bounds__(256, 2) void cm_mlp_mfma_kernel(
    const float* __restrict__ u, const u16* __restrict__ w1t, const float* __restrict__ b1,
    const u16* __restrict__ w2t, const float* __restrict__ b2,
    u16* __restrict__ v, u16* __restrict__ uu, float* __restrict__ uskip)
{
    __shared__ __align__(16) u16 sA[16][264];
    __shared__ __align__(16) u16 sH[16][520];
    const int t = threadIdx.x;
    const int lane = t & 63, w = t >> 6;
    const int ln = lane & 15, q = lane >> 4;
    const int row0 = blockIdx.x * 16;

    for (int x = t; x < 1024; x += 256) {
        int r = x >> 6, c0 = (x & 63) * 4;
        float4 xx = *(const float4*)(u + (size_t)(row0 + r) * 256 + c0);
        sA[r][c0 + 0] = f2b(xx.x); sA[r][c0 + 1] = f2b(xx.y);
        sA[r][c0 + 2] = f2b(xx.z); sA[r][c0 + 3] = f2b(xx.w);
    }
    f32x4 c2[16];
    #pragma unroll
    for (int i = 0; i < 16; ++i) c2[i] = (f32x4){0.f, 0.f, 0.f, 0.f};

    for (int jj = 0; jj < 3; ++jj) {
        __syncthreads();
        f32x4 c1[8];
        #pragma unroll
        for (int i = 0; i < 8; ++i) c1[i] = (f32x4){0.f, 0.f, 0.f, 0.f};
        {
            const u16* w1p = w1t + (size_t)(jj * 512 + w * 128 + ln) * 256 + q * 8;
            #pragma unroll
            for (int k0 = 0; k0 < 256; k0 += 32) {
                bf16x8 a = *(const bf16x8*)&sA[ln][k0 + q * 8];
                #pragma unroll
                for (int nt = 0; nt < 8; ++nt) {
                    bf16x8 b = *(const bf16x8*)(w1p + (size_t)nt * 16 * 256 + k0);
                    c1[nt] = __builtin_amdgcn_mfma_f32_16x16x32_bf16(a, b, c1[nt], 0, 0, 0);
                }
            }
        }
        #pragma unroll
        for (int nt = 0; nt < 8; ++nt) {
            int col = w * 128 + nt * 16 + ln;
            float bias = b1[jj * 512 + col];
            #pragma unroll
            for (int r = 0; r < 4; ++r)
                sH[q * 4 + r][col] = f2b(gelu_tanh(c1[nt][r] + bias));
        }
        __syncthreads();
        const u16* w2p = w2t + (size_t)(w * 256 + ln) * 1536 + jj * 512 + q * 8;
        #pragma unroll 2
        for (int k0 = 0; k0 < 512; k0 += 32) {
            bf16x8 a = *(const bf16x8*)&sH[ln][k0 + q * 8];
            #pragma unroll
            for (int nt = 0; nt < 16; ++nt) {
                bf16x8 b = *(const bf16x8*)(w2p + (size_t)nt * 16 * 1536 + k0);
                c2[nt] = __builtin_amdgcn_mfma_f32_16x16x32_bf16(a, b, c2[nt], 0, 0, 0);
            }
        }
    }
    #pragma unroll
    for (int nt = 0; nt < 16; ++nt) {
        int col = w * 256 + nt * 16 + ln;
        float bias = b2[col];
        #pragma unroll
        for (int r = 0; r < 4; ++r) {
            int row = row0 + q * 4 + r;
            float val = c2[nt][r] + bias;
            if (col < 512)      v[(size_t)row * 512 + col] = f2b(val);
            else if (col < 768) uu[(size_t)row * 256 + (col - 512)] = f2b(val);
            else                uskip[(size_t)row * 256 + (col - 768)] = val;
        }
    }
}

// ---------------------------------------------------------------- K2: means of uu
__global__ void mean_over_lat_kernel(const u16* __restrict__ uu, float* __restrict__ Mlong) {
    int l = blockIdx.x, d = threadIdx.x;
    float s = 0.f;
    for (int i = 0; i < NLAT; ++i) s += b2f(uu[((size_t)i * NLON + l) * 256 + d]);
    Mlong[(size_t)l * 256 + d] = s * (1.0f / NLAT);
}
__global__ void mean_over_lon_kernel(const u16* __restrict__ uu, float* __restrict__ Mlat) {
    int i = blockIdx.x, d = threadIdx.x;
    const u16* p = uu + (size_t)i * NLON * 256 + d;
    float s = 0.f;
    for (int l = 0; l < NLON; ++l) s += b2f(p[(size_t)l * 256]);
    Mlat[(size_t)i * 256 + d] = s * (1.0f / NLON);
}

__device__ float block_sum256(float x, float* red) {
    #pragma unroll
    for (int o = 32; o > 0; o >>= 1) x += __shfl_down(x, o, 64);
    int wid = threadIdx.x >> 6, lane = threadIdx.x & 63;
    if (lane == 0) red[wid] = x;
    __syncthreads();
    float s = red[0] + red[1] + red[2] + red[3];
    __syncthreads();
    return s;
}

// ---------------------------------------------------------------- K3: pool MLP
__global__ __launch_bounds__(256) void pool_mlp_kernel(
    const float* __restrict__ xin, const float* __restrict__ in_w,
    const float* __restrict__ ln_g, const float* __restrict__ ln_b,
    const float* __restrict__ fc1_w, const float* __restrict__ fc1_b,
    const float* __restrict__ fc2_w, const float* __restrict__ fc2_b,
    const float* __restrict__ lat, float* __restrict__ out)
{
    __shared__ float sx[256], sy[256], sg[256], red[4];
    int row = blockIdx.x, t = threadIdx.x;
    sx[t] = xin[(size_t)row * 256 + t];
    __syncthreads();
    float acc = 0.f;
    #pragma unroll 4
    for (int i = 0; i < 256; ++i) acc = fmaf(sx[i], in_w[i * 256 + t], acc);
    if (lat) acc *= lat_weight(lat, row, NLAT);
    float m = block_sum256(acc, red) * (1.f / 256.f);
    float var = block_sum256(acc * acc, red) * (1.f / 256.f) - m * m;
    float xn = (acc - m) * rsqrtf(var + 1e-5f) * ln_g[t] + ln_b[t];
    sy[t] = xn;
    __syncthreads();
    float h1 = fc1_b[t], h2 = fc1_b[t + 256];
    #pragma unroll 4
    for (int i = 0; i < 256; ++i) {
        float s = sy[i];
        h1 = fmaf(s, fc1_w[i * 512 + t], h1);
        h2 = fmaf(s, fc1_w[i * 512 + 256 + t], h2);
    }
    float g = h1 * gelu_tanh(h2);
    sg[t] = g;
    __syncthreads();
    float o = fc2_b[t];
    #pragma unroll 4
    for (int i = 0; i < 256; ++i) o = fmaf(sg[i], fc2_w[i * 256 + t], o);
    out[(size_t)row * 256 + t] = o;
}

// ---------------------------------------------------------------- K4: bessel
__global__ void bessel_kernel(const float* __restrict__ coord, int n,
                              const float* __restrict__ freq, int nf,
                              const float* __restrict__ w, float* __restrict__ mod,
                              int periodic)
{
    int i = blockIdx.x, j = threadIdx.x;
    float d = fabsf(coord[j] - coord[i]);
    if (periodic) d = fminf(d, TWO_PI_F - d);
    float acc[8];
    #pragma unroll
    for (int h = 0; h < 8; ++h) acc[h] = 0.f;
    bool big = d > 1e-6f;
    float inv = big ? 1.f / d : 0.f;
    for (int k = 0; k < nf; ++k) {
        float f = freq[k];
        float basis = big ? sinf(f * d) * inv : f;
        #pragma unroll
        for (int h = 0; h < 8; ++h) acc[h] = fmaf(basis, w[k * 8 + h], acc[h]);
    }
    #pragma unroll
    for (int h = 0; h < 8; ++h) mod[((size_t)h * n + i) * n + j] = acc[h];
}

// ---------------------------------------------------------------- K5: projections (tiled, latency-fixed)
__global__ __launch_bounds__(256) void proj_tile_kernel(
    const float* __restrict__ x, const float* __restrict__ w,
    float* __restrict__ c)
{
    const int t = threadIdx.x;
    const int j = blockIdx.y * 256 + t;
    const float* xp = x + (size_t)blockIdx.x * 16 * 256;
    const float* wp = w + j;
    float acc[16];
    #pragma unroll
    for (int r = 0; r < 16; ++r) acc[r] = 0.f;
    for (int i0 = 0; i0 < 256; i0 += 4) {
        float w0 = wp[(size_t)(i0 + 0) * 1536];
        float w1 = wp[(size_t)(i0 + 1) * 1536];
        float w2 = wp[(size_t)(i0 + 2) * 1536];
        float w3 = wp[(size_t)(i0 + 3) * 1536];
        #pragma unroll
        for (int r = 0; r < 16; ++r) {
            float4 xv = *(const float4*)(xp + r * 256 + i0);   // uniform -> s_load_dwordx4
            acc[r] = fmaf(xv.x, w0, acc[r]);
            acc[r] = fmaf(xv.y, w1, acc[r]);
            acc[r] = fmaf(xv.z, w2, acc[r]);
            acc[r] = fmaf(xv.w, w3, acc[r]);
        }
    }
    float* cp = c + (size_t)blockIdx.x * 16 * 1536 + j;
    #pragma unroll
    for (int r = 0; r < 16; ++r) cp[(size_t)r * 1536] = acc[r];
}

// ---------------------------------------------------------------- K6a: k_long -> KlongA[h][l][m] bf16 (K-major)
__global__ __launch_bounds__(256) void kmat_long_kernel(
    const float* __restrict__ q, const float* __restrict__ kp,
    const float* __restrict__ mod, u16* __restrict__ KA)
{
    int blk = blockIdx.x;              // h*256 + l   (grid 2048)
    int l = blk & 255, h = blk >> 8;
    __shared__ float sq[192];
    int t = threadIdx.x;
    if (t < 192) sq[t] = q[(size_t)l * 1536 + h * 192 + t];
    __syncthreads();
    const float* kpp = kp + (size_t)t * 1536 + h * 192;
    float acc = 0.f;
    #pragma unroll 4
    for (int c = 0; c < 192; ++c) acc = fmaf(kpp[c], sq[c], acc);
    float mv = mod[((size_t)h * 256 + l) * 256 + t];
    float val = leaky(acc * mv) * (TWO_PI_F / 256.f);
    KA[((size_t)h * 256 + l) * 256 + t] = f2b(val);
}

// ---------------------------------------------------------------- K6b: k_lat -> KlatA[h][i][j] bf16 (K-major)
__global__ __launch_bounds__(128) void kmat_lat_kernel(
    const float* __restrict__ q, const float* __restrict__ kp,
    const float* __restrict__ mod, const float* __restrict__ lat, u16* __restrict__ KA)
{
    int blk = blockIdx.x;              // h*128 + i   (grid 1024)
    int i = blk & 127, h = blk >> 7;
    __shared__ float sq[192];
    int t = threadIdx.x;
    for (int c = t; c < 192; c += 128) sq[c] = q[(size_t)i * 1536 + h * 192 + c];
    __syncthreads();
    const float* kpp = kp + (size_t)t * 1536 + h * 192;
    float acc = 0.f;
    #pragma unroll 4
    for (int c = 0; c < 192; ++c) acc = fmaf(kpp[c], sq[c], acc);
    float mv = mod[((size_t)h * 128 + i) * 128 + t];
    float wl = lat_weight(lat, t, NLAT);
    float val = leaky(acc * mv) * wl * (PI_F / 128.f);
    KA[((size_t)h * 128 + i) * 128 + t] = f2b(val);
}

// ---------------------------------------------------------------- K7: einsum1 MFMA (per batch)
__global__ __launch_bounds__(256) void einsum1_kernel(
    const u16* __restrict__ KlatA, const u16* __restrict__ v, u16* __restrict__ tmp1)
{
    int blk = blockIdx.x;              // h*256 + m (grid 2048)
    int m = blk & 255, h = blk >> 8;
    __shared__ __align__(16) u16 sV[64][136];   // [c][j], rows 272 B (16-aligned)
    const int t = threadIdx.x;
    const int lane = t & 63, w = t >> 6;
    const int ln = lane & 15, q = lane >> 4;

    {   // transpose-stage v slice [j=128][c=64] -> sV[c][j]
        int j = t >> 1, c0 = (t & 1) * 32;
        const u16* vp = v + ((size_t)j * 256 + m) * 512 + h * 64 + c0;
        union { uint4 q4[4]; u16 s[32]; } buf;
        buf.q4[0] = *(const uint4*)(vp);
        buf.q4[1] = *(const uint4*)(vp + 8);
        buf.q4[2] = *(const uint4*)(vp + 16);
        buf.q4[3] = *(const uint4*)(vp + 24);
        #pragma unroll
        for (int cc = 0; cc < 32; ++cc) sV[c0 + cc][j] = buf.s[cc];
    }
    __syncthreads();

    f32x4 acc[8];
    #pragma unroll
    for (int i = 0; i < 8; ++i) acc[i] = (f32x4){0.f, 0.f, 0.f, 0.f};
    const u16* ka = KlatA + (size_t)h * 128 * 128;
    for (int ch = 0; ch < 4; ++ch) {
        int j0 = ch * 32;
        bf16x8 b = *(const bf16x8*)&sV[w * 16 + ln][j0 + q * 8];
        #pragma unroll
        for (int it = 0; it < 8; ++it) {
            bf16x8 a = *(const bf16x8*)(ka + (size_t)(it * 16 + ln) * 128 + j0 + q * 8);
            acc[it] = __builtin_amdgcn_mfma_f32_16x16x32_bf16(a, b, acc[it], 0, 0, 0);
        }
    }
    int c = w * 16 + ln;
    #pragma unroll
    for (int it = 0; it < 8; ++it)
        #pragma unroll
        for (int r = 0; r < 4; ++r) {
            int i = it * 16 + q * 4 + r;
            tmp1[(((size_t)h * 128 + i) * 256 + m) * 64 + c] = f2b(acc[it][r]);
        }
}

// ---------------------------------------------------------------- K8: einsum2 MFMA + GN stats (per batch)
__global__ __launch_bounds__(256) void einsum2_kernel(
    const u16* __restrict__ tmp1, const u16* __restrict__ KlongA,
    u16* __restrict__ Aout, float* __restrict__ gnstat)
{
    int blk = blockIdx.x;              // h*128 + i (grid 1024)
    int i = blk & 127, h = blk >> 7;
    __shared__ __align__(16) u16 sT[64][264];   // [c][m], rows 528 B (16-aligned)
    __shared__ float red2[8];
    const int t = threadIdx.x;
    const int lane = t & 63, w = t >> 6;
    const int ln = lane & 15, q = lane >> 4;

    {   // transpose-stage tmp1 slice [m=256][c=64] -> sT[c][m]
        const u16* tp = tmp1 + (((size_t)h * 128 + i) * 256 + t) * 64;
        union { uint4 q4[8]; u16 s[64]; } buf;
        #pragma unroll
        for (int x = 0; x < 8; ++x) buf.q4[x] = *(const uint4*)(tp + x * 8);
        #pragma unroll
        for (int cc = 0; cc < 64; ++cc) sT[cc][t] = buf.s[cc];
    }
    __syncthreads();

    f32x4 acc[16];
    #pragma unroll
    for (int x = 0; x < 16; ++x) acc[x] = (f32x4){0.f, 0.f, 0.f, 0.f};
    const u16* ka = KlongA + (size_t)h * 256 * 256;
    for (int ch = 0; ch < 8; ++ch) {
        int m0 = ch * 32;
        bf16x8 bf[4];
        #pragma unroll
        for (int ct = 0; ct < 4; ++ct) bf[ct] = *(const bf16x8*)&sT[ct * 16 + ln][m0 + q * 8];
        #pragma unroll
        for (int lt = 0; lt < 4; ++lt) {
            bf16x8 a = *(const bf16x8*)(ka + (size_t)(w * 64 + lt * 16 + ln) * 256 + m0 + q * 8);
            #pragma unroll
            for (int ct = 0; ct < 4; ++ct)
                acc[lt * 4 + ct] = __builtin_amdgcn_mfma_f32_16x16x32_bf16(a, bf[ct], acc[lt * 4 + ct], 0, 0, 0);
        }
    }
    float lsum = 0.f, lsq = 0.f;
    #pragma unroll
    for (int lt = 0; lt < 4; ++lt)
        #pragma unroll
        for (int ct = 0; ct < 4; ++ct) {
            int c = ct * 16 + ln;
            #pragma unroll
            for (int r = 0; r < 4; ++r) {
                int l = w * 64 + lt * 16 + q * 4 + r;
                float val = acc[lt * 4 + ct][r];
                Aout[((size_t)i * 256 + l) * 512 + h * 64 + c] = f2b(val);
                lsum += val; lsq += val * val;
            }
        }
    #pragma unroll
    for (int o = 32; o > 0; o >>= 1) {
        lsum += __shfl_down(lsum, o, 64);
        lsq  += __shfl_down(lsq, o, 64);
    }
    if ((t & 63) == 0) { red2[w] = lsum; red2[4 + w] = lsq; }
    __syncthreads();
    if (t == 0) {
        atomicAdd(&gnstat[h * 2],     red2[0] + red2[1] + red2[2] + red2[3]);
        atomicAdd(&gnstat[h * 2 + 1], red2[4] + red2[5] + red2[6] + red2[7]);
    }
}

// ---------------------------------------------------------------- K9: fold GN into merge weights (per batch)
__global__ __launch_bounds__(256) void gn_fold_kernel(
    const float* __restrict__ gnstat, const float* __restrict__ gn_g, const float* __restrict__ gn_b,
    const float* __restrict__ mw, u16* __restrict__ Wp, float* __restrict__ bias2)
{
    __shared__ float red[4];
    int j = blockIdx.x, t = threadIdx.x;
    const float Ninv = 1.f / 2097152.f;   // 128*256*64
    float partial = 0.f;
    for (int k = t; k < 512; k += 256) {
        int h = k >> 6;
        float m = gnstat[h * 2] * Ninv;
        float var = gnstat[h * 2 + 1] * Ninv - m * m;
        float siv = rsqrtf(var + 1e-5f);
        float s = siv * gn_g[k];
        float tt = gn_b[k] - m * s;
        float wv = mw[(size_t)k * 256 + j];
        Wp[(size_t)j * 512 + k] = f2b(s * wv);
        partial += tt * wv;
    }
    float tot = block_sum256(partial, red);
    if (t == 0) bias2[j] = tot;
}

__global__ void zero_kernel(float* __restrict__ p, int n) {
    int i = blockIdx.x * blockDim.x + threadIdx.x;
    if (i < n) p[i] = 0.f;
}

// ================================================================ launch
extern "C" void kernel_launch(void* const* d_in, const int* in_sizes, int n_in,
                              void* d_out, int out_size, void* d_ws, size_t ws_size,
                              hipStream_t stream) {
    if (ws_size < 77856896ULL) return;   // known-good minimum from R3/R4
    const bool BIG = (ws_size >= 184549376ULL);  // de-fused cm path needs 96MB hidden

    const float* u        = (const float*)d_in[0];
    const float* lat      = (const float*)d_in[1];
    const float* lon      = (const float*)d_in[2];
    const float* cm_w1    = (const float*)d_in[3];
    const float* cm_b1    = (const float*)d_in[4];
    const float* cm_w2    = (const float*)d_in[5];
    const float* cm_b2    = (const float*)d_in[6];
    const float* long_in_w  = (const float*)d_in[7];
    const float* long_ln_g  = (const float*)d_in[8];
    const float* long_ln_b  = (const float*)d_in[9];
    const float* long_fc1_w = (const float*)d_in[10];
    const float* long_fc1_b = (const float*)d_in[11];
    const float* long_fc2_w = (const float*)d_in[12];
    const float* long_fc2_b = (const float*)d_in[13];
    const float* lat_in_w   = (const float*)d_in[14];
    const float* lat_ln_g   = (const float*)d_in[15];
    const float* lat_ln_b   = (const float*)d_in[16];
    const float* lat_fc1_w  = (const float*)d_in[17];
    const float* lat_fc1_b  = (const float*)d_in[18];
    const float* lat_fc2_w  = (const float*)d_in[19];
    const float* lat_fc2_b  = (const float*)d_in[20];
    const float* klong_q_w  = (const float*)d_in[21];
    const float* klong_k_w  = (const float*)d_in[22];
    const float* klat_q_w   = (const float*)d_in[23];
    const float* klat_k_w   = (const float*)d_in[24];
    const float* pe_long_freq = (const float*)d_in[25];
    const float* pe_long_w    = (const float*)d_in[26];
    const float* pe_lat_freq  = (const float*)d_in[27];
    const float* pe_lat_w     = (const float*)d_in[28];
    const float* gn_g    = (const float*)d_in[29];
    const float* gn_b    = (const float*)d_in[30];
    const float* merge_w = (const float*)d_in[31];
    const float* out_w   = (const float*)d_in[32];
    float* out = (float*)d_out;

    char* base = (char*)d_ws;
    u16*  vA   = (u16*)base;                          // v bf16 (32MB) -> Aout bf16 (32MB)
    char* reg1 = base + 33554432;                     // ubf bf16 (16MB) -> uu bf16 (16MB) -> tmp1 bf16 (32MB) -> D fp32 (32MB)
    u16*  ubf  = (u16*)reg1;
    u16*  uu   = (u16*)reg1;
    u16*  tmp1 = (u16*)reg1;
    float* D   = (float*)reg1;
    // small pool (floats from base+64MB); end = 76,940,416 B < 77,856,896 guard
    float* pool    = (float*)(base + 67108864);
    float* modlong = pool;                            // 524288
    float* modlat  = modlong + 524288;                // 131072
    float* Mlong   = modlat + 131072;                 // 65536
    float* Mlat    = Mlong + 65536;                   // 32768
    float* ulong   = Mlat + 32768;                    // 65536
    float* ulat    = ulong + 65536;                   // 32768
    float* qlong   = ulat + 32768;                    // 393216
    float* klongp  = qlong + 393216;                  // 393216
    float* qlat    = klongp + 393216;                 // 196608
    float* klatp   = qlat + 196608;                   // 196608
    float* gnstat  = klatp + 196608;                  // 32
    float* bias2   = gnstat + 32;                     // 256
    u16* KlongA = (u16*)(bias2 + 256);                // 524288 elems (1MB)
    u16* KlatA  = KlongA + 524288;                    // 131072 elems
    u16* Wp     = KlatA + 131072;                     // 131072 elems
    u16* owT    = Wp + 131072;                        // 65536 elems
    // small-path weight aliases (dead at cm time, re-converted per batch)
    u16* w1T = (u16*)qlong;                           // 786,432 B in qlong (1.5MB)
    u16* w2T = (u16*)klongp;                          // 3,145,728 B in klongp+qlat+klatp
    // big-path dedicated regions
    u16* w1Tb   = (u16*)(base + 79691776);            // 786,432 B
    u16* w2Tb   = (u16*)(base + 80478208);            // 3,145,728 B
    u16* hidden = (u16*)(base + 83886080);            // 100,663,296 B (32768x1536 bf16)

    zero_kernel<<<1, 32, 0, stream>>>(gnstat, 32);
    bessel_kernel<<<256, 256, 0, stream>>>(lon, 256, pe_long_freq, 64, pe_long_w, modlong, 1);
    bessel_kernel<<<128, 128, 0, stream>>>(lat, 128, pe_lat_freq, 32, pe_lat_w, modlat, 0);
    conv_owt_kernel<<<256, 256, 0, stream>>>(out_w, owT);
    if (BIG) {
        conv_w1t_kernel<<<1536, 256, 0, stream>>>(cm_w1, w1Tb);
        conv_w2t_kernel<<<6144, 256, 0, stream>>>(cm_w2, w2Tb);
    }

    for (int b = 0; b < 2; ++b) {
        const float* u_b  = u + (size_t)b * 32768 * 256;
        float* uskip_b    = out + (size_t)b * 8388608;
        float* gnstat_b   = gnstat + b * 16;

        if (BIG) {
            // u -> bf16 once (was packed 12x inside GEMM1's AF32 staging)
            conv_ubf_kernel<<<8192, 256, 0, stream>>>(u_b, ubf);
            // GEMM1: hidden = gelu(u@W1+b1)  [32768 x 1536], K=256  (row fastest)
            gemm128_kernel<256, 0, false><<<dim3(256, 12), 256, 0, stream>>>(
                ubf, w1Tb, cm_b1, nullptr, hidden, nullptr, nullptr);
            // GEMM2: hidden@W2+b2 -> v|uu|uskip  [32768 x 1024], K=1536  (uu overwrites ubf: safe, ubf dead)
            gemm128_kernel<1536, 1, false><<<dim3(256, 8), 256, 0, stream>>>(
                hidden, w2Tb, cm_b2, nullptr, vA, uu, uskip_b);
        } else {
            conv_w1t_kernel<<<1536, 256, 0, stream>>>(cm_w1, w1T);
            conv_w2t_kernel<<<6144, 256, 0, stream>>>(cm_w2, w2T);
            cm_mlp_mfma_kernel<<<2048, 256, 0, stream>>>(u_b, w1T, cm_b1, w2T, cm_b2,
                                                         vA, uu, uskip_b);
        }
        mean_over_lat_kernel<<<256, 256, 0, stream>>>(uu, Mlong);
        mean_over_lon_kernel<<<128, 256, 0, stream>>>(uu, Mlat);
        pool_mlp_kernel<<<256, 256, 0, stream>>>(Mlong, long_in_w, long_ln_g, long_ln_b,
                                                 long_fc1_w, long_fc1_b, long_fc2_w, long_fc2_b,
                                                 nullptr, ulong);
        pool_mlp_kernel<<<128, 256, 0, stream>>>(Mlat, lat_in_w, lat_ln_g, lat_ln_b,
                                                 lat_fc1_w, lat_fc1_b, lat_fc2_w, lat_fc2_b,
                                                 lat, ulat);
        proj_tile_kernel<<<dim3(16, 6), 256, 0, stream>>>(ulong, klong_q_w, qlong);   // clobbers w1T (dead)
        proj_tile_kernel<<<dim3(16, 6), 256, 0, stream>>>(ulong, klong_k_w, klongp);  // clobbers w2T (dead)
        proj_tile_kernel<<<dim3(8, 6), 256, 0, stream>>>(ulat, klat_q_w, qlat);
        proj_tile_kernel<<<dim3(8, 6), 256, 0, stream>>>(ulat, klat_k_w, klatp);
        kmat_long_kernel<<<2048, 256, 0, stream>>>(qlong, klongp, modlong, KlongA);
        kmat_lat_kernel<<<1024, 128, 0, stream>>>(qlat, klatp, modlat, lat, KlatA);
        einsum1_kernel<<<2048, 256, 0, stream>>>(KlatA, vA, tmp1);       // tmp1 over uu (dead)
        einsum2_kernel<<<1024, 256, 0, stream>>>(tmp1, KlongA, vA, gnstat_b); // Aout over v (dead)
        gn_fold_kernel<<<256, 256, 0, stream>>>(gnstat_b, gn_g, gn_b, merge_w, Wp, bias2);
        // merge: D = GN(Aout)@mw + uskip   [32768 x 256], K=512  (D over tmp1, dead)
        gemm128_kernel<512, 2, false><<<dim3(256, 2), 256, 0, stream>>>(
            vA, Wp, bias2, uskip_b, D, nullptr, nullptr);
        // out: out = D@ow                  [32768 x 256], K=256
        gemm128_kernel<256, 3, true><<<dim3(256, 2), 256, 0, stream>>>(
            D, owT, nullptr, nullptr, out + (size_t)b * 8388608, nullptr, nullptr);
    }
}

// Round 5
// 1788.917 us; speedup vs baseline: 1.0965x; 1.0487x over previous
//
#include <hip/hip_runtime.h>
#include <math.h>
#include <stdint.h>

#define NLAT 128
#define NLON 256
#define PI_F 3.14159265358979323846f
#define TWO_PI_F 6.28318530717958647692f

typedef unsigned short u16;
typedef __attribute__((ext_vector_type(8))) short bf16x8;
typedef __attribute__((ext_vector_type(4))) float f32x4;

__device__ __forceinline__ u16 f2b(float f) {
    union { float f; uint32_t u; } v; v.f = f;
    uint32_t r = v.u + 0x7fffu + ((v.u >> 16) & 1u);
    return (u16)(r >> 16);
}
__device__ __forceinline__ float b2f(u16 u) {
    union { uint32_t u; float f; } v; v.u = ((uint32_t)u) << 16;
    return v.f;
}
__device__ __forceinline__ ushort4 pack4(float a, float b, float c, float d) {
    ushort4 r; r.x = f2b(a); r.y = f2b(b); r.z = f2b(c); r.w = f2b(d); return r;
}
// tanh-approx gelu with fast exp: tanh(z) = 1 - 2/(e^{2z}+1).
// |err| ~1e-6 vs tanhf — invisible under bf16 output rounding (quantum ~8e-3).
// Robust at extremes: e->inf => tanh->1; e->0 => tanh->-1.
__device__ __forceinline__ float gelu_tanh(float x) {
    float z = 0.7978845608028654f * (x + 0.044715f * x * x * x);
    float e = __expf(2.0f * z);
    float th = 1.0f - 2.0f / (e + 1.0f);
    return 0.5f * x * (1.0f + th);
}
__device__ __forceinline__ float leaky(float x) { return x >= 0.0f ? x : 0.2f * x; }

__device__ __forceinline__ float lat_weight(const float* __restrict__ lat, int i, int n) {
    float w = cosf(lat[i]);
    if ((i == 0 || i == n - 1) && w < 0.001f) {
        float dlat = lat[1] - lat[0];
        float s = sinf(dlat * 0.25f);
        w = s * s / sinf(dlat * 0.5f);
    }
    return w;
}

// async global->LDS, 16B per lane; LDS dest is wave-uniform base + lane*16
__device__ __forceinline__ void gload16(const void* g, void* l) {
    __builtin_amdgcn_global_load_lds(
        (const __attribute__((address_space(1))) void*)(uintptr_t)g,
        (__attribute__((address_space(3))) void*)(uintptr_t)l,
        16, 0, 0);
}

// ================================================================ generic 128x128 MFMA GEMM
// A: [M][KD] (bf16 K-major, or fp32 if AF32). B: [N][KD] bf16 (n-major rows).
// BK=64, global_load_lds staging, both-sides XOR chunk swizzle (chunk ^= row&7).
// Grid: (M/128, N/128) — ROW fastest (R1/R3-measured lower fetch).
// EPI: 0 gelu->bf16 O0[row][1536]; 1 split v/uu/uskip; 2 +bias2+uskip -> fp32 O0[row][256];
//      3 plain fp32 O0[row][256]; 4 +bias2+uskip -> bf16 O0[row][256].
template<int KD, int EPI, bool AF32>
__global__ __launch_bounds__(256) void gemm128_kernel(
    const void* __restrict__ Aptr, const u16* __restrict__ B,
    const float* __restrict__ bias, const float* __restrict__ uskip,
    void* __restrict__ O0, void* __restrict__ O1, void* __restrict__ O2)
{
    __shared__ __align__(16) u16 sA[128][64];
    __shared__ __align__(16) u16 sB[128][64];
    const int t = threadIdx.x;
    const int lane = t & 63, w = t >> 6;
    const int ln = lane & 15, q = lane >> 4;
    const int wr = w >> 1, wc = w & 1;
    const int row0 = blockIdx.x * 128;
    const int col0 = blockIdx.y * 128;
    // async staging geometry: wave w, issue s covers rows s*32 + w*8 + (lane>>3);
    // each lane loads the 16B chunk (lane&7) XOR-swizzled by row&7 (= (lane>>3))
    const int grow = w * 8 + (lane >> 3);
    const int gcol = ((lane & 7) ^ (lane >> 3)) * 8;
    const int sr = t >> 1, sh = t & 1;

    f32x4 acc[16];
    #pragma unroll
    for (int i = 0; i < 16; ++i) acc[i] = (f32x4){0.f, 0.f, 0.f, 0.f};

    for (int k0 = 0; k0 < KD; k0 += 64) {
        __syncthreads();
        if (AF32) {
            // reg-stage fp32 -> bf16 (can't async): thread t covers row sr, cols sh*32..+31
            const float* Ag = (const float*)Aptr + (size_t)(row0 + sr) * KD + k0 + sh * 32;
            #pragma unroll
            for (int j = 0; j < 8; ++j) {
                float4 f = *(const float4*)(Ag + j * 4);
                int cp = (((4 * sh + (j >> 1)) ^ (sr & 7)) * 8) + (j & 1) * 4;
                *(ushort4*)&sA[sr][cp] = pack4(f.x, f.y, f.z, f.w);
            }
        } else {
            const u16* Ag = (const u16*)Aptr + (size_t)(row0 + grow) * KD + k0 + gcol;
            #pragma unroll
            for (int s = 0; s < 4; ++s)
                gload16(Ag + (size_t)(s * 32) * KD, &sA[s * 32 + w * 8][0]);
        }
        {
            const u16* Bg = B + (size_t)(col0 + grow) * KD + k0 + gcol;
            #pragma unroll
            for (int s = 0; s < 4; ++s)
                gload16(Bg + (size_t)(s * 32) * KD, &sB[s * 32 + w * 8][0]);
        }
        __syncthreads();
        #pragma unroll
        for (int kk = 0; kk < 2; ++kk) {
            bf16x8 af[4], bfr[4];
            #pragma unroll
            for (int x = 0; x < 4; ++x) {
                int ra = wr * 64 + x * 16 + ln;
                af[x] = *(const bf16x8*)&sA[ra][((kk * 4 + q) ^ (ra & 7)) * 8];
            }
            #pragma unroll
            for (int x = 0; x < 4; ++x) {
                int rb = wc * 64 + x * 16 + ln;
                bfr[x] = *(const bf16x8*)&sB[rb][((kk * 4 + q) ^ (rb & 7)) * 8];
            }
            #pragma unroll
            for (int rt = 0; rt < 4; ++rt)
                #pragma unroll
                for (int ct = 0; ct < 4; ++ct)
                    acc[rt * 4 + ct] = __builtin_amdgcn_mfma_f32_16x16x32_bf16(af[rt], bfr[ct], acc[rt * 4 + ct], 0, 0, 0);
        }
    }

    #pragma unroll
    for (int rt = 0; rt < 4; ++rt)
        #pragma unroll
        for (int ct = 0; ct < 4; ++ct) {
            int col = col0 + wc * 64 + ct * 16 + ln;
            float bv = (EPI == 3) ? 0.f : bias[col];
            #pragma unroll
            for (int r = 0; r < 4; ++r) {
                int row = row0 + wr * 64 + rt * 16 + q * 4 + r;
                float x = acc[rt * 4 + ct][r] + bv;
                if (EPI == 0) {
                    ((u16*)O0)[(size_t)row * 1536 + col] = f2b(gelu_tanh(x));
                } else if (EPI == 1) {
                    if (col < 512)      ((u16*)O0)[(size_t)row * 512 + col] = f2b(x);
                    else if (col < 768) ((u16*)O1)[(size_t)row * 256 + col - 512] = f2b(x);
                    else                ((float*)O2)[(size_t)row * 256 + col - 768] = x;
                } else if (EPI == 2) {
                    ((float*)O0)[(size_t)row * 256 + col] = x + uskip[(size_t)row * 256 + col];
                } else if (EPI == 4) {
                    ((u16*)O0)[(size_t)row * 256 + col] = f2b(x + uskip[(size_t)row * 256 + col]);
                } else {
                    ((float*)O0)[(size_t)row * 256 + col] = x;
                }
            }
        }
}

// ---------------------------------------------------------------- W conversions
__global__ void conv_w1t_kernel(const float* __restrict__ w1, u16* __restrict__ w1t) {
    int idx = blockIdx.x * 256 + threadIdx.x;       // grid 1536: w1t[1536][256]
    int j = idx >> 8, i = idx & 255;
    w1t[idx] = f2b(w1[(size_t)i * 1536 + j]);
}
__global__ void conv_w2t_kernel(const float* __restrict__ w2, u16* __restrict__ w2t) {
    int k = blockIdx.x / 6, s = blockIdx.x % 6;     // grid 6144: w2t[1024][1536]
    int i = s * 256 + threadIdx.x;
    w2t[(size_t)k * 1536 + i] = f2b(w2[(size_t)i * 1024 + k]);
}
__global__ void conv_owt_kernel(const float* __restrict__ ow, u16* __restrict__ owt) {
    int n = blockIdx.x, k = threadIdx.x;            // owt[256][256]
    owt[(size_t)n * 256 + k] = f2b(ow[(size_t)k * 256 + n]);
}
// u fp32 -> bf16, same layout (bit-identical f2b rounding as the old in-GEMM pack)
__global__ void conv_ubf_kernel(const float* __restrict__ u, u16* __restrict__ ub) {
    size_t i = ((size_t)blockIdx.x * 256 + threadIdx.x) * 4;
    float4 f = *(const float4*)(u + i);
    *(ushort4*)(ub + i) = pack4(f.x, f.y, f.z, f.w);
}

// ---------------------------------------------------------------- K1 fallback: fused cm MLP (R4, verified)
__global__ __launch_bounds__(256, 2) void cm_mlp_mfma_kernel(
    const float* __restrict__ u, const u16* __restrict__ w1t, const float* __restrict__ b1,
    const u16* __restrict__ w2t, const float* __restrict__ b2,
    u16* __restrict__ v, u16* __restrict__ uu, float* __restrict__ uskip)
{
    __shared__ __align__(16) u16 sA[16][264];
    __shared__ __align__(16) u16 sH[16][520];
    const int t = threadIdx.x;
    const int lane = t & 63, w = t >> 6;
    const int ln = lane & 15, q = lane >> 4;
    const int row0 = blockIdx.x * 16;

    for (int x = t; x < 1024; x += 256) {
        int r = x >> 6, c0 = (x & 63) * 4;
        float4 xx = *(const float4*)(u + (size_t)(row0 + r) * 256 + c0);
        sA[r][c0 + 0] = f2b(xx.x); sA[r][c0 + 1] = f2b(xx.y);
        sA[r][c0 + 2] = f2b(xx.z); sA[r][c0 + 3] = f2b(xx.w);
    }
    f32x4 c2[16];
    #pragma unroll
    for (int i = 0; i < 16; ++i) c2[i] = (f32x4){0.f, 0.f, 0.f, 0.f};

    for (int jj = 0; jj < 3; ++jj) {
        __syncthreads();
        f32x4 c1[8];
        #pragma unroll
        for (int i = 0; i < 8; ++i) c1[i] = (f32x4){0.f, 0.f, 0.f, 0.f};
        {
            const u16* w1p = w1t + (size_t)(jj * 512 + w * 128 + ln) * 256 + q * 8;
            #pragma unroll
            for (int k0 = 0; k0 < 256; k0 += 32) {
                bf16x8 a = *(const bf16x8*)&sA[ln][k0 + q * 8];
                #pragma unroll
                for (int nt = 0; nt < 8; ++nt) {
                    bf16x8 b = *(const bf16x8*)(w1p + (size_t)nt * 16 * 256 + k0);
                    c1[nt] = __builtin_amdgcn_mfma_f32_16x16x32_bf16(a, b, c1[nt], 0, 0, 0);
                }
            }
        }
        #pragma unroll
        for (int nt = 0; nt < 8; ++nt) {
            int col = w * 128 + nt * 16 + ln;
            float bias = b1[jj * 512 + col];
            #pragma unroll
            for (int r = 0; r < 4; ++r)
                sH[q * 4 + r][col] = f2b(gelu_tanh(c1[nt][r] + bias));
        }
        __syncthreads();
        const u16* w2p = w2t + (size_t)(w * 256 + ln) * 1536 + jj * 512 + q * 8;
        #pragma unroll 2
        for (int k0 = 0; k0 < 512; k0 += 32) {
            bf16x8 a = *(const bf16x8*)&sH[ln][k0 + q * 8];
            #pragma unroll
            for (int nt = 0; nt < 16; ++nt) {
                bf16x8 b = *(const bf16x8*)(w2p + (size_t)nt * 16 * 1536 + k0);
                c2[nt] = __builtin_amdgcn_mfma_f32_16x16x32_bf16(a, b, c2[nt], 0, 0, 0);
            }
        }
    }
    #pragma unroll
    for (int nt = 0; nt < 16; ++nt) {
        int col = w * 256 + nt * 16 + ln;
        float bias = b2[col];
        #pragma unroll
        for (int r = 0; r < 4; ++r) {
            int row = row0 + q * 4 + r;
            float val = c2[nt][r] + bias;
            if (col < 512)      v[(size_t)row * 512 + col] = f2b(val);
            else if (col < 768) uu[(size_t)row * 256 + (col - 512)] = f2b(val);
            else                uskip[(size_t)row * 256 + (col - 768)] = val;
        }
    }
}

// ---------------------------------------------------------------- K2: means of uu
__global__ void mean_over_lat_kernel(const u16* __restrict__ uu, float* __restrict__ Mlong) {
    int l = blockIdx.x, d = threadIdx.x;
    float s = 0.f;
    for (int i = 0; i < NLAT; ++i) s += b2f(uu[((size_t)i * NLON + l) * 256 + d]);
    Mlong[(size_t)l * 256 + d] = s * (1.0f / NLAT);
}
__global__ void mean_over_lon_kernel(const u16* __restrict__ uu, float* __restrict__ Mlat) {
    int i = blockIdx.x, d = threadIdx.x;
    const u16* p = uu + (size_t)i * NLON * 256 + d;
    float s = 0.f;
    for (int l = 0; l < NLON; ++l) s += b2f(p[(size_t)l * 256]);
    Mlat[(size_t)i * 256 + d] = s * (1.0f / NLON);
}

__device__ float block_sum256(float x, float* red) {
    #pragma unroll
    for (int o = 32; o > 0; o >>= 1) x += __shfl_down(x, o, 64);
    int wid = threadIdx.x >> 6, lane = threadIdx.x & 63;
    if (lane == 0) red[wid] = x;
    __syncthreads();
    float s = red[0] + red[1] + red[2] + red[3];
    __syncthreads();
    return s;
}

// ---------------------------------------------------------------- K3: pool MLP
__global__ __launch_bounds__(256) void pool_mlp_kernel(
    const float* __restrict__ xin, const float* __restrict__ in_w,
    const float* __restrict__ ln_g, const float* __restrict__ ln_b,
    const float* __restrict__ fc1_w, const float* __restrict__ fc1_b,
    const float* __restrict__ fc2_w, const float* __restrict__ fc2_b,
    const float* __restrict__ lat, float* __restrict__ out)
{
    __shared__ float sx[256], sy[256], sg[256], red[4];
    int row = blockIdx.x, t = threadIdx.x;
    sx[t] = xin[(size_t)row * 256 + t];
    __syncthreads();
    float acc = 0.f;
    #pragma unroll 4
    for (int i = 0; i < 256; ++i) acc = fmaf(sx[i], in_w[i * 256 + t], acc);
    if (lat) acc *= lat_weight(lat, row, NLAT);
    float m = block_sum256(acc, red) * (1.f / 256.f);
    float var = block_sum256(acc * acc, red) * (1.f / 256.f) - m * m;
    float xn = (acc - m) * rsqrtf(var + 1e-5f) * ln_g[t] + ln_b[t];
    sy[t] = xn;
    __syncthreads();
    float h1 = fc1_b[t], h2 = fc1_b[t + 256];
    #pragma unroll 4
    for (int i = 0; i < 256; ++i) {
        float s = sy[i];
        h1 = fmaf(s, fc1_w[i * 512 + t], h1);
        h2 = fmaf(s, fc1_w[i * 512 + 256 + t], h2);
    }
    float g = h1 * gelu_tanh(h2);
    sg[t] = g;
    __syncthreads();
    float o = fc2_b[t];
    #pragma unroll 4
    for (int i = 0; i < 256; ++i) o = fmaf(sg[i], fc2_w[i * 256 + t], o);
    out[(size_t)row * 256 + t] = o;
}

// ---------------------------------------------------------------- K4: bessel
__global__ void bessel_kernel(const float* __restrict__ coord, int n,
                              const float* __restrict__ freq, int nf,
                              const float* __restrict__ w, float* __restrict__ mod,
                              int periodic)
{
    int i = blockIdx.x, j = threadIdx.x;
    float d = fabsf(coord[j] - coord[i]);
    if (periodic) d = fminf(d, TWO_PI_F - d);
    float acc[8];
    #pragma unroll
    for (int h = 0; h < 8; ++h) acc[h] = 0.f;
    bool big = d > 1e-6f;
    float inv = big ? 1.f / d : 0.f;
    for (int k = 0; k < nf; ++k) {
        float f = freq[k];
        float basis = big ? sinf(f * d) * inv : f;
        #pragma unroll
        for (int h = 0; h < 8; ++h) acc[h] = fmaf(basis, w[k * 8 + h], acc[h]);
    }
    #pragma unroll
    for (int h = 0; h < 8; ++h) mod[((size_t)h * n + i) * n + j] = acc[h];
}

// ---------------------------------------------------------------- K5: projections (tiled, latency-fixed)
__global__ __launch_bounds__(256) void proj_tile_kernel(
    const float* __restrict__ x, const float* __restrict__ w,
    float* __restrict__ c)
{
    const int t = threadIdx.x;
    const int j = blockIdx.y * 256 + t;
    const float* xp = x + (size_t)blockIdx.x * 16 * 256;
    const float* wp = w + j;
    float acc[16];
    #pragma unroll
    for (int r = 0; r < 16; ++r) acc[r] = 0.f;
    for (int i0 = 0; i0 < 256; i0 += 4) {
        float w0 = wp[(size_t)(i0 + 0) * 1536];
        float w1 = wp[(size_t)(i0 + 1) * 1536];
        float w2 = wp[(size_t)(i0 + 2) * 1536];
        float w3 = wp[(size_t)(i0 + 3) * 1536];
        #pragma unroll
        for (int r = 0; r < 16; ++r) {
            float4 xv = *(const float4*)(xp + r * 256 + i0);   // uniform -> s_load_dwordx4
            acc[r] = fmaf(xv.x, w0, acc[r]);
            acc[r] = fmaf(xv.y, w1, acc[r]);
            acc[r] = fmaf(xv.z, w2, acc[r]);
            acc[r] = fmaf(xv.w, w3, acc[r]);
        }
    }
    float* cp = c + (size_t)blockIdx.x * 16 * 1536 + j;
    #pragma unroll
    for (int r = 0; r < 16; ++r) cp[(size_t)r * 1536] = acc[r];
}

// ---------------------------------------------------------------- K6a: k_long -> KlongA[h][l][m] bf16 (K-major)
__global__ __launch_bounds__(256) void kmat_long_kernel(
    const float* __restrict__ q, const float* __restrict__ kp,
    const float* __restrict__ mod, u16* __restrict__ KA)
{
    int blk = blockIdx.x;              // h*256 + l   (grid 2048)
    int l = blk & 255, h = blk >> 8;
    __shared__ float sq[192];
    int t = threadIdx.x;
    if (t < 192) sq[t] = q[(size_t)l * 1536 + h * 192 + t];
    __syncthreads();
    const float* kpp = kp + (size_t)t * 1536 + h * 192;
    float acc = 0.f;
    #pragma unroll 4
    for (int c = 0; c < 192; ++c) acc = fmaf(kpp[c], sq[c], acc);
    float mv = mod[((size_t)h * 256 + l) * 256 + t];
    float val = leaky(acc * mv) * (TWO_PI_F / 256.f);
    KA[((size_t)h * 256 + l) * 256 + t] = f2b(val);
}

// ---------------------------------------------------------------- K6b: k_lat -> KlatA[h][i][j] bf16 (K-major)
__global__ __launch_bounds__(128) void kmat_lat_kernel(
    const float* __restrict__ q, const float* __restrict__ kp,
    const float* __restrict__ mod, const float* __restrict__ lat, u16* __restrict__ KA)
{
    int blk = blockIdx.x;              // h*128 + i   (grid 1024)
    int i = blk & 127, h = blk >> 7;
    __shared__ float sq[192];
    int t = threadIdx.x;
    for (int c = t; c < 192; c += 128) sq[c] = q[(size_t)i * 1536 + h * 192 + c];
    __syncthreads();
    const float* kpp = kp + (size_t)t * 1536 + h * 192;
    float acc = 0.f;
    #pragma unroll 4
    for (int c = 0; c < 192; ++c) acc = fmaf(kpp[c], sq[c], acc);
    float mv = mod[((size_t)h * 128 + i) * 128 + t];
    float wl = lat_weight(lat, t, NLAT);
    float val = leaky(acc * mv) * wl * (PI_F / 128.f);
    KA[((size_t)h * 128 + i) * 128 + t] = f2b(val);
}

// ---------------------------------------------------------------- K7: einsum1 MFMA (per batch)
__global__ __launch_bounds__(256) void einsum1_kernel(
    const u16* __restrict__ KlatA, const u16* __restrict__ v, u16* __restrict__ tmp1)
{
    int blk = blockIdx.x;              // h*256 + m (grid 2048)
    int m = blk & 255, h = blk >> 8;
    __shared__ __align__(16) u16 sV[64][136];   // [c][j], rows 272 B (16-aligned)
    const int t = threadIdx.x;
    const int lane = t & 63, w = t >> 6;
    const int ln = lane & 15, q = lane >> 4;

    {   // transpose-stage v slice [j=128][c=64] -> sV[c][j]
        int j = t >> 1, c0 = (t & 1) * 32;
        const u16* vp = v + ((size_t)j * 256 + m) * 512 + h * 64 + c0;
        union { uint4 q4[4]; u16 s[32]; } buf;
        buf.q4[0] = *(const uint4*)(vp);
        buf.q4[1] = *(const uint4*)(vp + 8);
        buf.q4[2] = *(const uint4*)(vp + 16);
        buf.q4[3] = *(const uint4*)(vp + 24);
        #pragma unroll
        for (int cc = 0; cc < 32; ++cc) sV[c0 + cc][j] = buf.s[cc];
    }
    __syncthreads();

    f32x4 acc[8];
    #pragma unroll
    for (int i = 0; i < 8; ++i) acc[i] = (f32x4){0.f, 0.f, 0.f, 0.f};
    const u16* ka = KlatA + (size_t)h * 128 * 128;
    for (int ch = 0; ch < 4; ++ch) {
        int j0 = ch * 32;
        bf16x8 b = *(const bf16x8*)&sV[w * 16 + ln][j0 + q * 8];
        #pragma unroll
        for (int it = 0; it < 8; ++it) {
            bf16x8 a = *(const bf16x8*)(ka + (size_t)(it * 16 + ln) * 128 + j0 + q * 8);
            acc[it] = __builtin_amdgcn_mfma_f32_16x16x32_bf16(a, b, acc[it], 0, 0, 0);
        }
    }
    int c = w * 16 + ln;
    #pragma unroll
    for (int it = 0; it < 8; ++it)
        #pragma unroll
        for (int r = 0; r < 4; ++r) {
            int i = it * 16 + q * 4 + r;
            tmp1[(((size_t)h * 128 + i) * 256 + m) * 64 + c] = f2b(acc[it][r]);
        }
}

// ---------------------------------------------------------------- K8: einsum2 MFMA + GN stats (per batch)
__global__ __launch_bounds__(256) void einsum2_kernel(
    const u16* __restrict__ tmp1, const u16* __restrict__ KlongA,
    u16* __restrict__ Aout, float* __restrict__ gnstat)
{
    int blk = blockIdx.x;              // h*128 + i (grid 1024)
    int i = blk & 127, h = blk >> 7;
    __shared__ __align__(16) u16 sT[64][264];   // [c][m], rows 528 B (16-aligned)
    __shared__ float red2[8];
    const int t = threadIdx.x;
    const int lane = t & 63, w = t >> 6;
    const int ln = lane & 15, q = lane >> 4;

    {   // transpose-stage tmp1 slice [m=256][c=64] -> sT[c][m]
        const u16* tp = tmp1 + (((size_t)h * 128 + i) * 256 + t) * 64;
        union { uint4 q4[8]; u16 s[64]; } buf;
        #pragma unroll
        for (int x = 0; x < 8; ++x) buf.q4[x] = *(const uint4*)(tp + x * 8);
        #pragma unroll
        for (int cc = 0; cc < 64; ++cc) sT[cc][t] = buf.s[cc];
    }
    __syncthreads();

    f32x4 acc[16];
    #pragma unroll
    for (int x = 0; x < 16; ++x) acc[x] = (f32x4){0.f, 0.f, 0.f, 0.f};
    const u16* ka = KlongA + (size_t)h * 256 * 256;
    for (int ch = 0; ch < 8; ++ch) {
        int m0 = ch * 32;
        bf16x8 bf[4];
        #pragma unroll
        for (int ct = 0; ct < 4; ++ct) bf[ct] = *(const bf16x8*)&sT[ct * 16 + ln][m0 + q * 8];
        #pragma unroll
        for (int lt = 0; lt < 4; ++lt) {
            bf16x8 a = *(const bf16x8*)(ka + (size_t)(w * 64 + lt * 16 + ln) * 256 + m0 + q * 8);
            #pragma unroll
            for (int ct = 0; ct < 4; ++ct)
                acc[lt * 4 + ct] = __builtin_amdgcn_mfma_f32_16x16x32_bf16(a, bf[ct], acc[lt * 4 + ct], 0, 0, 0);
        }
    }
    float lsum = 0.f, lsq = 0.f;
    #pragma unroll
    for (int lt = 0; lt < 4; ++lt)
        #pragma unroll
        for (int ct = 0; ct < 4; ++ct) {
            int c = ct * 16 + ln;
            #pragma unroll
            for (int r = 0; r < 4; ++r) {
                int l = w * 64 + lt * 16 + q * 4 + r;
                float val = acc[lt * 4 + ct][r];
                Aout[((size_t)i * 256 + l) * 512 + h * 64 + c] = f2b(val);
                lsum += val; lsq += val * val;
            }
        }
    #pragma unroll
    for (int o = 32; o > 0; o >>= 1) {
        lsum += __shfl_down(lsum, o, 64);
        lsq  += __shfl_down(lsq, o, 64);
    }
    if ((t & 63) == 0) { red2[w] = lsum; red2[4 + w] = lsq; }
    __syncthreads();
    if (t == 0) {
        atomicAdd(&gnstat[h * 2],     red2[0] + red2[1] + red2[2] + red2[3]);
        atomicAdd(&gnstat[h * 2 + 1], red2[4] + red2[5] + red2[6] + red2[7]);
    }
}

// ---------------------------------------------------------------- K9: fold GN into merge weights (per batch)
__global__ __launch_bounds__(256) void gn_fold_kernel(
    const float* __restrict__ gnstat, const float* __restrict__ gn_g, const float* __restrict__ gn_b,
    const float* __restrict__ mw, u16* __restrict__ Wp, float* __restrict__ bias2)
{
    __shared__ float red[4];
    int j = blockIdx.x, t = threadIdx.x;
    const float Ninv = 1.f / 2097152.f;   // 128*256*64
    float partial = 0.f;
    for (int k = t; k < 512; k += 256) {
        int h = k >> 6;
        float m = gnstat[h * 2] * Ninv;
        float var = gnstat[h * 2 + 1] * Ninv - m * m;
        float siv = rsqrtf(var + 1e-5f);
        float s = siv * gn_g[k];
        float tt = gn_b[k] - m * s;
        float wv = mw[(size_t)k * 256 + j];
        Wp[(size_t)j * 512 + k] = f2b(s * wv);
        partial += tt * wv;
    }
    float tot = block_sum256(partial, red);
    if (t == 0) bias2[j] = tot;
}

__global__ void zero_kernel(float* __restrict__ p, int n) {
    int i = blockIdx.x * blockDim.x + threadIdx.x;
    if (i < n) p[i] = 0.f;
}

// ================================================================ launch
extern "C" void kernel_launch(void* const* d_in, const int* in_sizes, int n_in,
                              void* d_out, int out_size, void* d_ws, size_t ws_size,
                              hipStream_t stream) {
    if (ws_size < 77856896ULL) return;   // known-good minimum from R3/R4
    const bool BIG = (ws_size >= 184549376ULL);  // de-fused cm path needs 96MB hidden

    const float* u        = (const float*)d_in[0];
    const float* lat      = (const float*)d_in[1];
    const float* lon      = (const float*)d_in[2];
    const float* cm_w1    = (const float*)d_in[3];
    const float* cm_b1    = (const float*)d_in[4];
    const float* cm_w2    = (const float*)d_in[5];
    const float* cm_b2    = (const float*)d_in[6];
    const float* long_in_w  = (const float*)d_in[7];
    const float* long_ln_g  = (const float*)d_in[8];
    const float* long_ln_b  = (const float*)d_in[9];
    const float* long_fc1_w = (const float*)d_in[10];
    const float* long_fc1_b = (const float*)d_in[11];
    const float* long_fc2_w = (const float*)d_in[12];
    const float* long_fc2_b = (const float*)d_in[13];
    const float* lat_in_w   = (const float*)d_in[14];
    const float* lat_ln_g   = (const float*)d_in[15];
    const float* lat_ln_b   = (const float*)d_in[16];
    const float* lat_fc1_w  = (const float*)d_in[17];
    const float* lat_fc1_b  = (const float*)d_in[18];
    const float* lat_fc2_w  = (const float*)d_in[19];
    const float* lat_fc2_b  = (const float*)d_in[20];
    const float* klong_q_w  = (const float*)d_in[21];
    const float* klong_k_w  = (const float*)d_in[22];
    const float* klat_q_w   = (const float*)d_in[23];
    const float* klat_k_w   = (const float*)d_in[24];
    const float* pe_long_freq = (const float*)d_in[25];
    const float* pe_long_w    = (const float*)d_in[26];
    const float* pe_lat_freq  = (const float*)d_in[27];
    const float* pe_lat_w     = (const float*)d_in[28];
    const float* gn_g    = (const float*)d_in[29];
    const float* gn_b    = (const float*)d_in[30];
    const float* merge_w = (const float*)d_in[31];
    const float* out_w   = (const float*)d_in[32];
    float* out = (float*)d_out;

    char* base = (char*)d_ws;
    u16*  vA   = (u16*)base;                          // v bf16 (32MB) -> Aout bf16 (32MB)
    char* reg1 = base + 33554432;                     // ubf bf16 (16MB) -> uu bf16 (16MB) -> tmp1 bf16 (32MB) -> Dbf bf16 (16MB)
    u16*  ubf  = (u16*)reg1;
    u16*  uu   = (u16*)reg1;
    u16*  tmp1 = (u16*)reg1;
    u16*  Dbf  = (u16*)reg1;
    // small pool (floats from base+64MB); end = 76,940,416 B < 77,856,896 guard
    float* pool    = (float*)(base + 67108864);
    float* modlong = pool;                            // 524288
    float* modlat  = modlong + 524288;                // 131072
    float* Mlong   = modlat + 131072;                 // 65536
    float* Mlat    = Mlong + 65536;                   // 32768
    float* ulong   = Mlat + 32768;                    // 65536
    float* ulat    = ulong + 65536;                   // 32768
    float* qlong   = ulat + 32768;                    // 393216
    float* klongp  = qlong + 393216;                  // 393216
    float* qlat    = klongp + 393216;                 // 196608
    float* klatp   = qlat + 196608;                   // 196608
    float* gnstat  = klatp + 196608;                  // 32
    float* bias2   = gnstat + 32;                     // 256
    u16* KlongA = (u16*)(bias2 + 256);                // 524288 elems (1MB)
    u16* KlatA  = KlongA + 524288;                    // 131072 elems
    u16* Wp     = KlatA + 131072;                     // 131072 elems
    u16* owT    = Wp + 131072;                        // 65536 elems
    // small-path weight aliases (dead at cm time, re-converted per batch)
    u16* w1T = (u16*)qlong;                           // 786,432 B in qlong (1.5MB)
    u16* w2T = (u16*)klongp;                          // 3,145,728 B in klongp+qlat+klatp
    // big-path dedicated regions
    u16* w1Tb   = (u16*)(base + 79691776);            // 786,432 B
    u16* w2Tb   = (u16*)(base + 80478208);            // 3,145,728 B
    u16* hidden = (u16*)(base + 83886080);            // 100,663,296 B (32768x1536 bf16)

    zero_kernel<<<1, 32, 0, stream>>>(gnstat, 32);
    bessel_kernel<<<256, 256, 0, stream>>>(lon, 256, pe_long_freq, 64, pe_long_w, modlong, 1);
    bessel_kernel<<<128, 128, 0, stream>>>(lat, 128, pe_lat_freq, 32, pe_lat_w, modlat, 0);
    conv_owt_kernel<<<256, 256, 0, stream>>>(out_w, owT);
    if (BIG) {
        conv_w1t_kernel<<<1536, 256, 0, stream>>>(cm_w1, w1Tb);
        conv_w2t_kernel<<<6144, 256, 0, stream>>>(cm_w2, w2Tb);
    }

    for (int b = 0; b < 2; ++b) {
        const float* u_b  = u + (size_t)b * 32768 * 256;
        float* uskip_b    = out + (size_t)b * 8388608;
        float* gnstat_b   = gnstat + b * 16;

        if (BIG) {
            // u -> bf16 once (bit-identical to the old in-GEMM pack)
            conv_ubf_kernel<<<8192, 256, 0, stream>>>(u_b, ubf);
            // GEMM1: hidden = gelu(u@W1+b1)  [32768 x 1536], K=256  (row fastest)
            gemm128_kernel<256, 0, false><<<dim3(256, 12), 256, 0, stream>>>(
                ubf, w1Tb, cm_b1, nullptr, hidden, nullptr, nullptr);
            // GEMM2: hidden@W2+b2 -> v|uu|uskip  [32768 x 1024], K=1536  (uu overwrites ubf: safe, ubf dead)
            gemm128_kernel<1536, 1, false><<<dim3(256, 8), 256, 0, stream>>>(
                hidden, w2Tb, cm_b2, nullptr, vA, uu, uskip_b);
        } else {
            conv_w1t_kernel<<<1536, 256, 0, stream>>>(cm_w1, w1T);
            conv_w2t_kernel<<<6144, 256, 0, stream>>>(cm_w2, w2T);
            cm_mlp_mfma_kernel<<<2048, 256, 0, stream>>>(u_b, w1T, cm_b1, w2T, cm_b2,
                                                         vA, uu, uskip_b);
        }
        mean_over_lat_kernel<<<256, 256, 0, stream>>>(uu, Mlong);
        mean_over_lon_kernel<<<128, 256, 0, stream>>>(uu, Mlat);
        pool_mlp_kernel<<<256, 256, 0, stream>>>(Mlong, long_in_w, long_ln_g, long_ln_b,
                                                 long_fc1_w, long_fc1_b, long_fc2_w, long_fc2_b,
                                                 nullptr, ulong);
        pool_mlp_kernel<<<128, 256, 0, stream>>>(Mlat, lat_in_w, lat_ln_g, lat_ln_b,
                                                 lat_fc1_w, lat_fc1_b, lat_fc2_w, lat_fc2_b,
                                                 lat, ulat);
        proj_tile_kernel<<<dim3(16, 6), 256, 0, stream>>>(ulong, klong_q_w, qlong);   // clobbers w1T (dead)
        proj_tile_kernel<<<dim3(16, 6), 256, 0, stream>>>(ulong, klong_k_w, klongp);  // clobbers w2T (dead)
        proj_tile_kernel<<<dim3(8, 6), 256, 0, stream>>>(ulat, klat_q_w, qlat);
        proj_tile_kernel<<<dim3(8, 6), 256, 0, stream>>>(ulat, klat_k_w, klatp);
        kmat_long_kernel<<<2048, 256, 0, stream>>>(qlong, klongp, modlong, KlongA);
        kmat_lat_kernel<<<1024, 128, 0, stream>>>(qlat, klatp, modlat, lat, KlatA);
        einsum1_kernel<<<2048, 256, 0, stream>>>(KlatA, vA, tmp1);       // tmp1 over uu (dead)
        einsum2_kernel<<<1024, 256, 0, stream>>>(tmp1, KlongA, vA, gnstat_b); // Aout over v (dead)
        gn_fold_kernel<<<256, 256, 0, stream>>>(gnstat_b, gn_g, gn_b, merge_w, Wp, bias2);
        // merge: Dbf = bf16(GN(Aout)@mw + uskip)   [32768 x 256], K=512  (Dbf over tmp1, dead)
        // bf16 write is bit-identical to the out-GEMM's former AF32 in-kernel pack.
        gemm128_kernel<512, 4, false><<<dim3(256, 2), 256, 0, stream>>>(
            vA, Wp, bias2, uskip_b, Dbf, nullptr, nullptr);
        // out: out = Dbf@ow                [32768 x 256], K=256  (bf16 async-staged A)
        gemm128_kernel<256, 3, false><<<dim3(256, 2), 256, 0, stream>>>(
            Dbf, owT, nullptr, nullptr, out + (size_t)b * 8388608, nullptr, nullptr);
    }
}

// Round 6
// 1614.827 us; speedup vs baseline: 1.2147x; 1.1078x over previous
//
#include <hip/hip_runtime.h>
#include <math.h>
#include <stdint.h>

#define NLAT 128
#define NLON 256
#define PI_F 3.14159265358979323846f
#define TWO_PI_F 6.28318530717958647692f

typedef unsigned short u16;
typedef __attribute__((ext_vector_type(8))) short bf16x8;
typedef __attribute__((ext_vector_type(4))) float f32x4;

__device__ __forceinline__ u16 f2b(float f) {
    union { float f; uint32_t u; } v; v.f = f;
    uint32_t r = v.u + 0x7fffu + ((v.u >> 16) & 1u);
    return (u16)(r >> 16);
}
__device__ __forceinline__ float b2f(u16 u) {
    union { uint32_t u; float f; } v; v.u = ((uint32_t)u) << 16;
    return v.f;
}
__device__ __forceinline__ ushort4 pack4(float a, float b, float c, float d) {
    ushort4 r; r.x = f2b(a); r.y = f2b(b); r.z = f2b(c); r.w = f2b(d); return r;
}
// tanh-approx gelu with fast exp: tanh(z) = 1 - 2/(e^{2z}+1).
// |err| ~1e-6 vs tanhf — invisible under bf16 output rounding (quantum ~8e-3).
__device__ __forceinline__ float gelu_tanh(float x) {
    float z = 0.7978845608028654f * (x + 0.044715f * x * x * x);
    float e = __expf(2.0f * z);
    float th = 1.0f - 2.0f / (e + 1.0f);
    return 0.5f * x * (1.0f + th);
}
__device__ __forceinline__ float leaky(float x) { return x >= 0.0f ? x : 0.2f * x; }

__device__ __forceinline__ float lat_weight(const float* __restrict__ lat, int i, int n) {
    float w = cosf(lat[i]);
    if ((i == 0 || i == n - 1) && w < 0.001f) {
        float dlat = lat[1] - lat[0];
        float s = sinf(dlat * 0.25f);
        w = s * s / sinf(dlat * 0.5f);
    }
    return w;
}

// async global->LDS, 16B per lane; LDS dest is wave-uniform base + lane*16
__device__ __forceinline__ void gload16(const void* g, void* l) {
    __builtin_amdgcn_global_load_lds(
        (const __attribute__((address_space(1))) void*)(uintptr_t)g,
        (__attribute__((address_space(3))) void*)(uintptr_t)l,
        16, 0, 0);
}

// ================================================================ generic 128x128 MFMA GEMM
// A: [M][KD] (bf16 K-major, or fp32 if AF32). B: [N][KD] bf16 (n-major rows).
// BK=64, global_load_lds staging, both-sides XOR chunk swizzle (chunk ^= row&7).
// Grid: (M/128, N/128) — ROW fastest (R1/R3-measured lower fetch).
// EPI: 0 gelu->bf16 O0[row][1536]; 1 split v/uu/uskip; 2 +bias2+uskip -> fp32 O0[row][256];
//      3 plain fp32 O0[row][256]; 4 +bias2+uskip -> bf16 O0[row][256].
template<int KD, int EPI, bool AF32>
__global__ __launch_bounds__(256) void gemm128_kernel(
    const void* __restrict__ Aptr, const u16* __restrict__ B,
    const float* __restrict__ bias, const float* __restrict__ uskip,
    void* __restrict__ O0, void* __restrict__ O1, void* __restrict__ O2)
{
    __shared__ __align__(16) u16 sA[128][64];
    __shared__ __align__(16) u16 sB[128][64];
    const int t = threadIdx.x;
    const int lane = t & 63, w = t >> 6;
    const int ln = lane & 15, q = lane >> 4;
    const int wr = w >> 1, wc = w & 1;
    const int row0 = blockIdx.x * 128;
    const int col0 = blockIdx.y * 128;
    // async staging geometry: wave w, issue s covers rows s*32 + w*8 + (lane>>3);
    // each lane loads the 16B chunk (lane&7) XOR-swizzled by row&7 (= (lane>>3))
    const int grow = w * 8 + (lane >> 3);
    const int gcol = ((lane & 7) ^ (lane >> 3)) * 8;
    const int sr = t >> 1, sh = t & 1;

    f32x4 acc[16];
    #pragma unroll
    for (int i = 0; i < 16; ++i) acc[i] = (f32x4){0.f, 0.f, 0.f, 0.f};

    for (int k0 = 0; k0 < KD; k0 += 64) {
        __syncthreads();
        if (AF32) {
            // reg-stage fp32 -> bf16 (can't async): thread t covers row sr, cols sh*32..+31
            const float* Ag = (const float*)Aptr + (size_t)(row0 + sr) * KD + k0 + sh * 32;
            #pragma unroll
            for (int j = 0; j < 8; ++j) {
                float4 f = *(const float4*)(Ag + j * 4);
                int cp = (((4 * sh + (j >> 1)) ^ (sr & 7)) * 8) + (j & 1) * 4;
                *(ushort4*)&sA[sr][cp] = pack4(f.x, f.y, f.z, f.w);
            }
        } else {
            const u16* Ag = (const u16*)Aptr + (size_t)(row0 + grow) * KD + k0 + gcol;
            #pragma unroll
            for (int s = 0; s < 4; ++s)
                gload16(Ag + (size_t)(s * 32) * KD, &sA[s * 32 + w * 8][0]);
        }
        {
            const u16* Bg = B + (size_t)(col0 + grow) * KD + k0 + gcol;
            #pragma unroll
            for (int s = 0; s < 4; ++s)
                gload16(Bg + (size_t)(s * 32) * KD, &sB[s * 32 + w * 8][0]);
        }
        __syncthreads();
        #pragma unroll
        for (int kk = 0; kk < 2; ++kk) {
            bf16x8 af[4], bfr[4];
            #pragma unroll
            for (int x = 0; x < 4; ++x) {
                int ra = wr * 64 + x * 16 + ln;
                af[x] = *(const bf16x8*)&sA[ra][((kk * 4 + q) ^ (ra & 7)) * 8];
            }
            #pragma unroll
            for (int x = 0; x < 4; ++x) {
                int rb = wc * 64 + x * 16 + ln;
                bfr[x] = *(const bf16x8*)&sB[rb][((kk * 4 + q) ^ (rb & 7)) * 8];
            }
            #pragma unroll
            for (int rt = 0; rt < 4; ++rt)
                #pragma unroll
                for (int ct = 0; ct < 4; ++ct)
                    acc[rt * 4 + ct] = __builtin_amdgcn_mfma_f32_16x16x32_bf16(af[rt], bfr[ct], acc[rt * 4 + ct], 0, 0, 0);
        }
    }

    #pragma unroll
    for (int rt = 0; rt < 4; ++rt)
        #pragma unroll
        for (int ct = 0; ct < 4; ++ct) {
            int col = col0 + wc * 64 + ct * 16 + ln;
            float bv = (EPI == 3) ? 0.f : bias[col];
            #pragma unroll
            for (int r = 0; r < 4; ++r) {
                int row = row0 + wr * 64 + rt * 16 + q * 4 + r;
                float x = acc[rt * 4 + ct][r] + bv;
                if (EPI == 0) {
                    ((u16*)O0)[(size_t)row * 1536 + col] = f2b(gelu_tanh(x));
                } else if (EPI == 1) {
                    if (col < 512)      ((u16*)O0)[(size_t)row * 512 + col] = f2b(x);
                    else if (col < 768) ((u16*)O1)[(size_t)row * 256 + col - 512] = f2b(x);
                    else                ((float*)O2)[(size_t)row * 256 + col - 768] = x;
                } else if (EPI == 2) {
                    ((float*)O0)[(size_t)row * 256 + col] = x + uskip[(size_t)row * 256 + col];
                } else if (EPI == 4) {
                    ((u16*)O0)[(size_t)row * 256 + col] = f2b(x + uskip[(size_t)row * 256 + col]);
                } else {
                    ((float*)O0)[(size_t)row * 256 + col] = x;
                }
            }
        }
}

// ---------------------------------------------------------------- coalesced fp32->bf16 transpose
// out[c][r] = f2b(in[r][c]); R,C multiples of 32. Grid (C/32, R/32), 256 threads.
// Both global read and write are lane-contiguous; LDS [32][33] is conflict-free.
__global__ __launch_bounds__(256) void transpose_f32_bf16_kernel(
    const float* __restrict__ in, u16* __restrict__ out, int R, int C)
{
    __shared__ float tile[32][33];
    const int tx = threadIdx.x & 31, ty = threadIdx.x >> 5;   // ty 0..7
    const int c0 = blockIdx.x * 32, r0 = blockIdx.y * 32;
    #pragma unroll
    for (int p = 0; p < 4; ++p)
        tile[ty + p * 8][tx] = in[(size_t)(r0 + ty + p * 8) * C + c0 + tx];
    __syncthreads();
    #pragma unroll
    for (int p = 0; p < 4; ++p)
        out[(size_t)(c0 + ty + p * 8) * R + r0 + tx] = f2b(tile[tx][ty + p * 8]);
}

// u fp32 -> bf16, same layout (bit-identical f2b rounding as the old in-GEMM pack)
__global__ void conv_ubf_kernel(const float* __restrict__ u, u16* __restrict__ ub) {
    size_t i = ((size_t)blockIdx.x * 256 + threadIdx.x) * 4;
    float4 f = *(const float4*)(u + i);
    *(ushort4*)(ub + i) = pack4(f.x, f.y, f.z, f.w);
}

// ---------------------------------------------------------------- K1 fallback: fused cm MLP (R4, verified)
__global__ __launch_bounds__(256, 2) void cm_mlp_mfma_kernel(
    const float* __restrict__ u, const u16* __restrict__ w1t, const float* __restrict__ b1,
    const u16* __restrict__ w2t, const float* __restrict__ b2,
    u16* __restrict__ v, u16* __restrict__ uu, float* __restrict__ uskip)
{
    __shared__ __align__(16) u16 sA[16][264];
    __shared__ __align__(16) u16 sH[16][520];
    const int t = threadIdx.x;
    const int lane = t & 63, w = t >> 6;
    const int ln = lane & 15, q = lane >> 4;
    const int row0 = blockIdx.x * 16;

    for (int x = t; x < 1024; x += 256) {
        int r = x >> 6, c0 = (x & 63) * 4;
        float4 xx = *(const float4*)(u + (size_t)(row0 + r) * 256 + c0);
        sA[r][c0 + 0] = f2b(xx.x); sA[r][c0 + 1] = f2b(xx.y);
        sA[r][c0 + 2] = f2b(xx.z); sA[r][c0 + 3] = f2b(xx.w);
    }
    f32x4 c2[16];
    #pragma unroll
    for (int i = 0; i < 16; ++i) c2[i] = (f32x4){0.f, 0.f, 0.f, 0.f};

    for (int jj = 0; jj < 3; ++jj) {
        __syncthreads();
        f32x4 c1[8];
        #pragma unroll
        for (int i = 0; i < 8; ++i) c1[i] = (f32x4){0.f, 0.f, 0.f, 0.f};
        {
            const u16* w1p = w1t + (size_t)(jj * 512 + w * 128 + ln) * 256 + q * 8;
            #pragma unroll
            for (int k0 = 0; k0 < 256; k0 += 32) {
                bf16x8 a = *(const bf16x8*)&sA[ln][k0 + q * 8];
                #pragma unroll
                for (int nt = 0; nt < 8; ++nt) {
                    bf16x8 b = *(const bf16x8*)(w1p + (size_t)nt * 16 * 256 + k0);
                    c1[nt] = __builtin_amdgcn_mfma_f32_16x16x32_bf16(a, b, c1[nt], 0, 0, 0);
                }
            }
        }
        #pragma unroll
        for (int nt = 0; nt < 8; ++nt) {
            int col = w * 128 + nt * 16 + ln;
            float bias = b1[jj * 512 + col];
            #pragma unroll
            for (int r = 0; r < 4; ++r)
                sH[q * 4 + r][col] = f2b(gelu_tanh(c1[nt][r] + bias));
        }
        __syncthreads();
        const u16* w2p = w2t + (size_t)(w * 256 + ln) * 1536 + jj * 512 + q * 8;
        #pragma unroll 2
        for (int k0 = 0; k0 < 512; k0 += 32) {
            bf16x8 a = *(const bf16x8*)&sH[ln][k0 + q * 8];
            #pragma unroll
            for (int nt = 0; nt < 16; ++nt) {
                bf16x8 b = *(const bf16x8*)(w2p + (size_t)nt * 16 * 1536 + k0);
                c2[nt] = __builtin_amdgcn_mfma_f32_16x16x32_bf16(a, b, c2[nt], 0, 0, 0);
            }
        }
    }
    #pragma unroll
    for (int nt = 0; nt < 16; ++nt) {
        int col = w * 256 + nt * 16 + ln;
        float bias = b2[col];
        #pragma unroll
        for (int r = 0; r < 4; ++r) {
            int row = row0 + q * 4 + r;
            float val = c2[nt][r] + bias;
            if (col < 512)      v[(size_t)row * 512 + col] = f2b(val);
            else if (col < 768) uu[(size_t)row * 256 + (col - 512)] = f2b(val);
            else                uskip[(size_t)row * 256 + (col - 768)] = val;
        }
    }
}

// ---------------------------------------------------------------- K2: means of uu (4-way ILP chains)
__global__ void mean_over_lat_kernel(const u16* __restrict__ uu, float* __restrict__ Mlong) {
    int l = blockIdx.x, d = threadIdx.x;
    const u16* p = uu + (size_t)l * 256 + d;
    float s0 = 0.f, s1 = 0.f, s2 = 0.f, s3 = 0.f;
    for (int i = 0; i < 32; ++i) {
        s0 += b2f(p[(size_t)(i      ) * NLON * 256]);
        s1 += b2f(p[(size_t)(i +  32) * NLON * 256]);
        s2 += b2f(p[(size_t)(i +  64) * NLON * 256]);
        s3 += b2f(p[(size_t)(i +  96) * NLON * 256]);
    }
    Mlong[(size_t)l * 256 + d] = (s0 + s1 + s2 + s3) * (1.0f / NLAT);
}
__global__ void mean_over_lon_kernel(const u16* __restrict__ uu, float* __restrict__ Mlat) {
    int i = blockIdx.x, d = threadIdx.x;
    const u16* p = uu + (size_t)i * NLON * 256 + d;
    float s0 = 0.f, s1 = 0.f, s2 = 0.f, s3 = 0.f;
    for (int l = 0; l < 64; ++l) {
        s0 += b2f(p[(size_t)(l      ) * 256]);
        s1 += b2f(p[(size_t)(l +  64) * 256]);
        s2 += b2f(p[(size_t)(l + 128) * 256]);
        s3 += b2f(p[(size_t)(l + 192) * 256]);
    }
    Mlat[(size_t)i * 256 + d] = (s0 + s1 + s2 + s3) * (1.0f / NLON);
}

__device__ float block_sum256(float x, float* red) {
    #pragma unroll
    for (int o = 32; o > 0; o >>= 1) x += __shfl_down(x, o, 64);
    int wid = threadIdx.x >> 6, lane = threadIdx.x & 63;
    if (lane == 0) red[wid] = x;
    __syncthreads();
    float s = red[0] + red[1] + red[2] + red[3];
    __syncthreads();
    return s;
}

// ---------------------------------------------------------------- K3: pool MLP (split chains for ILP)
__global__ __launch_bounds__(256) void pool_mlp_kernel(
    const float* __restrict__ xin, const float* __restrict__ in_w,
    const float* __restrict__ ln_g, const float* __restrict__ ln_b,
    const float* __restrict__ fc1_w, const float* __restrict__ fc1_b,
    const float* __restrict__ fc2_w, const float* __restrict__ fc2_b,
    const float* __restrict__ lat, float* __restrict__ out)
{
    __shared__ float sx[256], sy[256], sg[256], red[4];
    int row = blockIdx.x, t = threadIdx.x;
    sx[t] = xin[(size_t)row * 256 + t];
    __syncthreads();
    float a0 = 0.f, a1 = 0.f;
    #pragma unroll 4
    for (int i = 0; i < 128; ++i) {
        a0 = fmaf(sx[i],       in_w[i * 256 + t],         a0);
        a1 = fmaf(sx[i + 128], in_w[(i + 128) * 256 + t], a1);
    }
    float acc = a0 + a1;
    if (lat) acc *= lat_weight(lat, row, NLAT);
    float m = block_sum256(acc, red) * (1.f / 256.f);
    float var = block_sum256(acc * acc, red) * (1.f / 256.f) - m * m;
    float xn = (acc - m) * rsqrtf(var + 1e-5f) * ln_g[t] + ln_b[t];
    sy[t] = xn;
    __syncthreads();
    float h1a = 0.f, h1b = 0.f, h2a = 0.f, h2b = 0.f;
    #pragma unroll 4
    for (int i = 0; i < 128; ++i) {
        float s0 = sy[i], s1 = sy[i + 128];
        h1a = fmaf(s0, fc1_w[i * 512 + t], h1a);
        h1b = fmaf(s1, fc1_w[(i + 128) * 512 + t], h1b);
        h2a = fmaf(s0, fc1_w[i * 512 + 256 + t], h2a);
        h2b = fmaf(s1, fc1_w[(i + 128) * 512 + 256 + t], h2b);
    }
    float h1 = fc1_b[t] + h1a + h1b;
    float h2 = fc1_b[t + 256] + h2a + h2b;
    float g = h1 * gelu_tanh(h2);
    sg[t] = g;
    __syncthreads();
    float o0 = 0.f, o1 = 0.f;
    #pragma unroll 4
    for (int i = 0; i < 128; ++i) {
        o0 = fmaf(sg[i],       fc2_w[i * 256 + t],         o0);
        o1 = fmaf(sg[i + 128], fc2_w[(i + 128) * 256 + t], o1);
    }
    out[(size_t)row * 256 + t] = fc2_b[t] + o0 + o1;
}

// ---------------------------------------------------------------- K4: bessel
__global__ void bessel_kernel(const float* __restrict__ coord, int n,
                              const float* __restrict__ freq, int nf,
                              const float* __restrict__ w, float* __restrict__ mod,
                              int periodic)
{
    int i = blockIdx.x, j = threadIdx.x;
    float d = fabsf(coord[j] - coord[i]);
    if (periodic) d = fminf(d, TWO_PI_F - d);
    float acc[8];
    #pragma unroll
    for (int h = 0; h < 8; ++h) acc[h] = 0.f;
    bool big = d > 1e-6f;
    float inv = big ? 1.f / d : 0.f;
    for (int k = 0; k < nf; ++k) {
        float f = freq[k];
        float basis = big ? sinf(f * d) * inv : f;
        #pragma unroll
        for (int h = 0; h < 8; ++h) acc[h] = fmaf(basis, w[k * 8 + h], acc[h]);
    }
    #pragma unroll
    for (int h = 0; h < 8; ++h) mod[((size_t)h * n + i) * n + j] = acc[h];
}

// ---------------------------------------------------------------- K5: projections (tiled, latency-fixed)
__global__ __launch_bounds__(256) void proj_tile_kernel(
    const float* __restrict__ x, const float* __restrict__ w,
    float* __restrict__ c)
{
    const int t = threadIdx.x;
    const int j = blockIdx.y * 256 + t;
    const float* xp = x + (size_t)blockIdx.x * 16 * 256;
    const float* wp = w + j;
    float acc[16];
    #pragma unroll
    for (int r = 0; r < 16; ++r) acc[r] = 0.f;
    for (int i0 = 0; i0 < 256; i0 += 4) {
        float w0 = wp[(size_t)(i0 + 0) * 1536];
        float w1 = wp[(size_t)(i0 + 1) * 1536];
        float w2 = wp[(size_t)(i0 + 2) * 1536];
        float w3 = wp[(size_t)(i0 + 3) * 1536];
        #pragma unroll
        for (int r = 0; r < 16; ++r) {
            float4 xv = *(const float4*)(xp + r * 256 + i0);   // uniform -> s_load_dwordx4
            acc[r] = fmaf(xv.x, w0, acc[r]);
            acc[r] = fmaf(xv.y, w1, acc[r]);
            acc[r] = fmaf(xv.z, w2, acc[r]);
            acc[r] = fmaf(xv.w, w3, acc[r]);
        }
    }
    float* cp = c + (size_t)blockIdx.x * 16 * 1536 + j;
    #pragma unroll
    for (int r = 0; r < 16; ++r) cp[(size_t)r * 1536] = acc[r];
}

// ---------------------------------------------------------------- K6a: k_long -> KlongA[h][l][m] bf16 (K-major)
__global__ __launch_bounds__(256) void kmat_long_kernel(
    const float* __restrict__ q, const float* __restrict__ kp,
    const float* __restrict__ mod, u16* __restrict__ KA)
{
    int blk = blockIdx.x;              // h*256 + l   (grid 2048)
    int l = blk & 255, h = blk >> 8;
    __shared__ float sq[192];
    int t = threadIdx.x;
    if (t < 192) sq[t] = q[(size_t)l * 1536 + h * 192 + t];
    __syncthreads();
    const float* kpp = kp + (size_t)t * 1536 + h * 192;
    float acc = 0.f;
    #pragma unroll 4
    for (int c = 0; c < 192; ++c) acc = fmaf(kpp[c], sq[c], acc);
    float mv = mod[((size_t)h * 256 + l) * 256 + t];
    float val = leaky(acc * mv) * (TWO_PI_F / 256.f);
    KA[((size_t)h * 256 + l) * 256 + t] = f2b(val);
}

// ---------------------------------------------------------------- K6b: k_lat -> KlatA[h][i][j] bf16 (K-major)
__global__ __launch_bounds__(128) void kmat_lat_kernel(
    const float* __restrict__ q, const float* __restrict__ kp,
    const float* __restrict__ mod, const float* __restrict__ lat, u16* __restrict__ KA)
{
    int blk = blockIdx.x;              // h*128 + i   (grid 1024)
    int i = blk & 127, h = blk >> 7;
    __shared__ float sq[192];
    int t = threadIdx.x;
    for (int c = t; c < 192; c += 128) sq[c] = q[(size_t)i * 1536 + h * 192 + c];
    __syncthreads();
    const float* kpp = kp + (size_t)t * 1536 + h * 192;
    float acc = 0.f;
    #pragma unroll 4
    for (int c = 0; c < 192; ++c) acc = fmaf(kpp[c], sq[c], acc);
    float mv = mod[((size_t)h * 128 + i) * 128 + t];
    float wl = lat_weight(lat, t, NLAT);
    float val = leaky(acc * mv) * wl * (PI_F / 128.f);
    KA[((size_t)h * 128 + i) * 128 + t] = f2b(val);
}

// ---------------------------------------------------------------- K7: einsum1 MFMA (per batch)
__global__ __launch_bounds__(256) void einsum1_kernel(
    const u16* __restrict__ KlatA, const u16* __restrict__ v, u16* __restrict__ tmp1)
{
    int blk = blockIdx.x;              // h*256 + m (grid 2048)
    int m = blk & 255, h = blk >> 8;
    __shared__ __align__(16) u16 sV[64][136];   // [c][j], rows 272 B (16-aligned)
    const int t = threadIdx.x;
    const int lane = t & 63, w = t >> 6;
    const int ln = lane & 15, q = lane >> 4;

    {   // transpose-stage v slice [j=128][c=64] -> sV[c][j]
        int j = t >> 1, c0 = (t & 1) * 32;
        const u16* vp = v + ((size_t)j * 256 + m) * 512 + h * 64 + c0;
        union { uint4 q4[4]; u16 s[32]; } buf;
        buf.q4[0] = *(const uint4*)(vp);
        buf.q4[1] = *(const uint4*)(vp + 8);
        buf.q4[2] = *(const uint4*)(vp + 16);
        buf.q4[3] = *(const uint4*)(vp + 24);
        #pragma unroll
        for (int cc = 0; cc < 32; ++cc) sV[c0 + cc][j] = buf.s[cc];
    }
    __syncthreads();

    f32x4 acc[8];
    #pragma unroll
    for (int i = 0; i < 8; ++i) acc[i] = (f32x4){0.f, 0.f, 0.f, 0.f};
    const u16* ka = KlatA + (size_t)h * 128 * 128;
    for (int ch = 0; ch < 4; ++ch) {
        int j0 = ch * 32;
        bf16x8 b = *(const bf16x8*)&sV[w * 16 + ln][j0 + q * 8];
        #pragma unroll
        for (int it = 0; it < 8; ++it) {
            bf16x8 a = *(const bf16x8*)(ka + (size_t)(it * 16 + ln) * 128 + j0 + q * 8);
            acc[it] = __builtin_amdgcn_mfma_f32_16x16x32_bf16(a, b, acc[it], 0, 0, 0);
        }
    }
    int c = w * 16 + ln;
    #pragma unroll
    for (int it = 0; it < 8; ++it)
        #pragma unroll
        for (int r = 0; r < 4; ++r) {
            int i = it * 16 + q * 4 + r;
            tmp1[(((size_t)h * 128 + i) * 256 + m) * 64 + c] = f2b(acc[it][r]);
        }
}

// ---------------------------------------------------------------- K8: einsum2 MFMA + GN stats (per batch)
__global__ __launch_bounds__(256) void einsum2_kernel(
    const u16* __restrict__ tmp1, const u16* __restrict__ KlongA,
    u16* __restrict__ Aout, float* __restrict__ gnstat)
{
    int blk = blockIdx.x;              // h*128 + i (grid 1024)
    int i = blk & 127, h = blk >> 7;
    __shared__ __align__(16) u16 sT[64][264];   // [c][m], rows 528 B (16-aligned)
    __shared__ float red2[8];
    const int t = threadIdx.x;
    const int lane = t & 63, w = t >> 6;
    const int ln = lane & 15, q = lane >> 4;

    {   // transpose-stage tmp1 slice [m=256][c=64] -> sT[c][m]
        const u16* tp = tmp1 + (((size_t)h * 128 + i) * 256 + t) * 64;
        union { uint4 q4[8]; u16 s[64]; } buf;
        #pragma unroll
        for (int x = 0; x < 8; ++x) buf.q4[x] = *(const uint4*)(tp + x * 8);
        #pragma unroll
        for (int cc = 0; cc < 64; ++cc) sT[cc][t] = buf.s[cc];
    }
    __syncthreads();

    f32x4 acc[16];
    #pragma unroll
    for (int x = 0; x < 16; ++x) acc[x] = (f32x4){0.f, 0.f, 0.f, 0.f};
    const u16* ka = KlongA + (size_t)h * 256 * 256;
    for (int ch = 0; ch < 8; ++ch) {
        int m0 = ch * 32;
        bf16x8 bf[4];
        #pragma unroll
        for (int ct = 0; ct < 4; ++ct) bf[ct] = *(const bf16x8*)&sT[ct * 16 + ln][m0 + q * 8];
        #pragma unroll
        for (int lt = 0; lt < 4; ++lt) {
            bf16x8 a = *(const bf16x8*)(ka + (size_t)(w * 64 + lt * 16 + ln) * 256 + m0 + q * 8);
            #pragma unroll
            for (int ct = 0; ct < 4; ++ct)
                acc[lt * 4 + ct] = __builtin_amdgcn_mfma_f32_16x16x32_bf16(a, bf[ct], acc[lt * 4 + ct], 0, 0, 0);
        }
    }
    float lsum = 0.f, lsq = 0.f;
    #pragma unroll
    for (int lt = 0; lt < 4; ++lt)
        #pragma unroll
        for (int ct = 0; ct < 4; ++ct) {
            int c = ct * 16 + ln;
            #pragma unroll
            for (int r = 0; r < 4; ++r) {
                int l = w * 64 + lt * 16 + q * 4 + r;
                float val = acc[lt * 4 + ct][r];
                Aout[((size_t)i * 256 + l) * 512 + h * 64 + c] = f2b(val);
                lsum += val; lsq += val * val;
            }
        }
    #pragma unroll
    for (int o = 32; o > 0; o >>= 1) {
        lsum += __shfl_down(lsum, o, 64);
        lsq  += __shfl_down(lsq, o, 64);
    }
    if ((t & 63) == 0) { red2[w] = lsum; red2[4 + w] = lsq; }
    __syncthreads();
    if (t == 0) {
        atomicAdd(&gnstat[h * 2],     red2[0] + red2[1] + red2[2] + red2[3]);
        atomicAdd(&gnstat[h * 2 + 1], red2[4] + red2[5] + red2[6] + red2[7]);
    }
}

// ---------------------------------------------------------------- K9: fold GN into merge weights (per batch)
__global__ __launch_bounds__(256) void gn_fold_kernel(
    const float* __restrict__ gnstat, const float* __restrict__ gn_g, const float* __restrict__ gn_b,
    const float* __restrict__ mw, u16* __restrict__ Wp, float* __restrict__ bias2)
{
    __shared__ float red[4];
    int j = blockIdx.x, t = threadIdx.x;
    const float Ninv = 1.f / 2097152.f;   // 128*256*64
    float partial = 0.f;
    for (int k = t; k < 512; k += 256) {
        int h = k >> 6;
        float m = gnstat[h * 2] * Ninv;
        float var = gnstat[h * 2 + 1] * Ninv - m * m;
        float siv = rsqrtf(var + 1e-5f);
        float s = siv * gn_g[k];
        float tt = gn_b[k] - m * s;
        float wv = mw[(size_t)k * 256 + j];
        Wp[(size_t)j * 512 + k] = f2b(s * wv);
        partial += tt * wv;
    }
    float tot = block_sum256(partial, red);
    if (t == 0) bias2[j] = tot;
}

__global__ void zero_kernel(float* __restrict__ p, int n) {
    int i = blockIdx.x * blockDim.x + threadIdx.x;
    if (i < n) p[i] = 0.f;
}

// ================================================================ launch
extern "C" void kernel_launch(void* const* d_in, const int* in_sizes, int n_in,
                              void* d_out, int out_size, void* d_ws, size_t ws_size,
                              hipStream_t stream) {
    if (ws_size < 77856896ULL) return;   // known-good minimum from R3/R4
    const bool BIG = (ws_size >= 184549376ULL);  // de-fused cm path needs 96MB hidden

    const float* u        = (const float*)d_in[0];
    const float* lat      = (const float*)d_in[1];
    const float* lon      = (const float*)d_in[2];
    const float* cm_w1    = (const float*)d_in[3];
    const float* cm_b1    = (const float*)d_in[4];
    const float* cm_w2    = (const float*)d_in[5];
    const float* cm_b2    = (const float*)d_in[6];
    const float* long_in_w  = (const float*)d_in[7];
    const float* long_ln_g  = (const float*)d_in[8];
    const float* long_ln_b  = (const float*)d_in[9];
    const float* long_fc1_w = (const float*)d_in[10];
    const float* long_fc1_b = (const float*)d_in[11];
    const float* long_fc2_w = (const float*)d_in[12];
    const float* long_fc2_b = (const float*)d_in[13];
    const float* lat_in_w   = (const float*)d_in[14];
    const float* lat_ln_g   = (const float*)d_in[15];
    const float* lat_ln_b   = (const float*)d_in[16];
    const float* lat_fc1_w  = (const float*)d_in[17];
    const float* lat_fc1_b  = (const float*)d_in[18];
    const float* lat_fc2_w  = (const float*)d_in[19];
    const float* lat_fc2_b  = (const float*)d_in[20];
    const float* klong_q_w  = (const float*)d_in[21];
    const float* klong_k_w  = (const float*)d_in[22];
    const float* klat_q_w   = (const float*)d_in[23];
    const float* klat_k_w   = (const float*)d_in[24];
    const float* pe_long_freq = (const float*)d_in[25];
    const float* pe_long_w    = (const float*)d_in[26];
    const float* pe_lat_freq  = (const float*)d_in[27];
    const float* pe_lat_w     = (const float*)d_in[28];
    const float* gn_g    = (const float*)d_in[29];
    const float* gn_b    = (const float*)d_in[30];
    const float* merge_w = (const float*)d_in[31];
    const float* out_w   = (const float*)d_in[32];
    float* out = (float*)d_out;

    char* base = (char*)d_ws;
    u16*  vA   = (u16*)base;                          // v bf16 (32MB) -> Aout bf16 (32MB)
    char* reg1 = base + 33554432;                     // ubf bf16 (16MB) -> uu bf16 (16MB) -> tmp1 bf16 (32MB) -> Dbf bf16 (16MB)
    u16*  ubf  = (u16*)reg1;
    u16*  uu   = (u16*)reg1;
    u16*  tmp1 = (u16*)reg1;
    u16*  Dbf  = (u16*)reg1;
    // small pool (floats from base+64MB); end = 76,940,416 B < 77,856,896 guard
    float* pool    = (float*)(base + 67108864);
    float* modlong = pool;                            // 524288
    float* modlat  = modlong + 524288;                // 131072
    float* Mlong   = modlat + 131072;                 // 65536
    float* Mlat    = Mlong + 65536;                   // 32768
    float* ulong   = Mlat + 32768;                    // 65536
    float* ulat    = ulong + 65536;                   // 32768
    float* qlong   = ulat + 32768;                    // 393216
    float* klongp  = qlong + 393216;                  // 393216
    float* qlat    = klongp + 393216;                 // 196608
    float* klatp   = qlat + 196608;                   // 196608
    float* gnstat  = klatp + 196608;                  // 32
    float* bias2   = gnstat + 32;                     // 256
    u16* KlongA = (u16*)(bias2 + 256);                // 524288 elems (1MB)
    u16* KlatA  = KlongA + 524288;                    // 131072 elems
    u16* Wp     = KlatA + 131072;                     // 131072 elems
    u16* owT    = Wp + 131072;                        // 65536 elems
    // small-path weight aliases (dead at cm time, re-converted per batch)
    u16* w1T = (u16*)qlong;                           // 786,432 B in qlong (1.5MB)
    u16* w2T = (u16*)klongp;                          // 3,145,728 B in klongp+qlat+klatp
    // big-path dedicated regions
    u16* w1Tb   = (u16*)(base + 79691776);            // 786,432 B
    u16* w2Tb   = (u16*)(base + 80478208);            // 3,145,728 B
    u16* hidden = (u16*)(base + 83886080);            // 100,663,296 B (32768x1536 bf16)

    zero_kernel<<<1, 32, 0, stream>>>(gnstat, 32);
    bessel_kernel<<<256, 256, 0, stream>>>(lon, 256, pe_long_freq, 64, pe_long_w, modlong, 1);
    bessel_kernel<<<128, 128, 0, stream>>>(lat, 128, pe_lat_freq, 32, pe_lat_w, modlat, 0);
    // owT[256][256] <- out_w^T (coalesced)
    transpose_f32_bf16_kernel<<<dim3(8, 8), 256, 0, stream>>>(out_w, owT, 256, 256);
    if (BIG) {
        // w1Tb[1536][256] <- cm_w1^T; w2Tb[1024][1536] <- cm_w2^T (coalesced)
        transpose_f32_bf16_kernel<<<dim3(48, 8), 256, 0, stream>>>(cm_w1, w1Tb, 256, 1536);
        transpose_f32_bf16_kernel<<<dim3(32, 48), 256, 0, stream>>>(cm_w2, w2Tb, 1536, 1024);
    }

    for (int b = 0; b < 2; ++b) {
        const float* u_b  = u + (size_t)b * 32768 * 256;
        float* uskip_b    = out + (size_t)b * 8388608;
        float* gnstat_b   = gnstat + b * 16;

        if (BIG) {
            // u -> bf16 once (bit-identical to the old in-GEMM pack)
            conv_ubf_kernel<<<8192, 256, 0, stream>>>(u_b, ubf);
            // GEMM1: hidden = gelu(u@W1+b1)  [32768 x 1536], K=256  (row fastest)
            gemm128_kernel<256, 0, false><<<dim3(256, 12), 256, 0, stream>>>(
                ubf, w1Tb, cm_b1, nullptr, hidden, nullptr, nullptr);
            // GEMM2: hidden@W2+b2 -> v|uu|uskip  [32768 x 1024], K=1536  (uu overwrites ubf: safe, ubf dead)
            gemm128_kernel<1536, 1, false><<<dim3(256, 8), 256, 0, stream>>>(
                hidden, w2Tb, cm_b2, nullptr, vA, uu, uskip_b);
        } else {
            transpose_f32_bf16_kernel<<<dim3(48, 8), 256, 0, stream>>>(cm_w1, w1T, 256, 1536);
            transpose_f32_bf16_kernel<<<dim3(32, 48), 256, 0, stream>>>(cm_w2, w2T, 1536, 1024);
            cm_mlp_mfma_kernel<<<2048, 256, 0, stream>>>(u_b, w1T, cm_b1, w2T, cm_b2,
                                                         vA, uu, uskip_b);
        }
        mean_over_lat_kernel<<<256, 256, 0, stream>>>(uu, Mlong);
        mean_over_lon_kernel<<<128, 256, 0, stream>>>(uu, Mlat);
        pool_mlp_kernel<<<256, 256, 0, stream>>>(Mlong, long_in_w, long_ln_g, long_ln_b,
                                                 long_fc1_w, long_fc1_b, long_fc2_w, long_fc2_b,
                                                 nullptr, ulong);
        pool_mlp_kernel<<<128, 256, 0, stream>>>(Mlat, lat_in_w, lat_ln_g, lat_ln_b,
                                                 lat_fc1_w, lat_fc1_b, lat_fc2_w, lat_fc2_b,
                                                 lat, ulat);
        proj_tile_kernel<<<dim3(16, 6), 256, 0, stream>>>(ulong, klong_q_w, qlong);   // clobbers w1T (dead)
        proj_tile_kernel<<<dim3(16, 6), 256, 0, stream>>>(ulong, klong_k_w, klongp);  // clobbers w2T (dead)
        proj_tile_kernel<<<dim3(8, 6), 256, 0, stream>>>(ulat, klat_q_w, qlat);
        proj_tile_kernel<<<dim3(8, 6), 256, 0, stream>>>(ulat, klat_k_w, klatp);
        kmat_long_kernel<<<2048, 256, 0, stream>>>(qlong, klongp, modlong, KlongA);
        kmat_lat_kernel<<<1024, 128, 0, stream>>>(qlat, klatp, modlat, lat, KlatA);
        einsum1_kernel<<<2048, 256, 0, stream>>>(KlatA, vA, tmp1);       // tmp1 over uu (dead)
        einsum2_kernel<<<1024, 256, 0, stream>>>(tmp1, KlongA, vA, gnstat_b); // Aout over v (dead)
        gn_fold_kernel<<<256, 256, 0, stream>>>(gnstat_b, gn_g, gn_b, merge_w, Wp, bias2);
        // merge: Dbf = bf16(GN(Aout)@mw + uskip)   [32768 x 256], K=512  (Dbf over tmp1, dead)
        gemm128_kernel<512, 4, false><<<dim3(256, 2), 256, 0, stream>>>(
            vA, Wp, bias2, uskip_b, Dbf, nullptr, nullptr);
        // out: out = Dbf@ow                [32768 x 256], K=256  (bf16 async-staged A)
        gemm128_kernel<256, 3, false><<<dim3(256, 2), 256, 0, stream>>>(
            Dbf, owT, nullptr, nullptr, out + (size_t)b * 8388608, nullptr, nullptr);
    }
}

// Round 7
// 1602.283 us; speedup vs baseline: 1.2242x; 1.0078x over previous
//
#include <hip/hip_runtime.h>
#include <math.h>
#include <stdint.h>

#define NLAT 128
#define NLON 256
#define PI_F 3.14159265358979323846f
#define TWO_PI_F 6.28318530717958647692f

typedef unsigned short u16;
typedef __attribute__((ext_vector_type(8))) short bf16x8;
typedef __attribute__((ext_vector_type(4))) float f32x4;

__device__ __forceinline__ u16 f2b(float f) {
    union { float f; uint32_t u; } v; v.f = f;
    uint32_t r = v.u + 0x7fffu + ((v.u >> 16) & 1u);
    return (u16)(r >> 16);
}
__device__ __forceinline__ float b2f(u16 u) {
    union { uint32_t u; float f; } v; v.u = ((uint32_t)u) << 16;
    return v.f;
}
__device__ __forceinline__ ushort4 pack4(float a, float b, float c, float d) {
    ushort4 r; r.x = f2b(a); r.y = f2b(b); r.z = f2b(c); r.w = f2b(d); return r;
}
// tanh-approx gelu with fast exp: tanh(z) = 1 - 2/(e^{2z}+1).
// |err| ~1e-6 vs tanhf — invisible under bf16 output rounding (quantum ~8e-3).
__device__ __forceinline__ float gelu_tanh(float x) {
    float z = 0.7978845608028654f * (x + 0.044715f * x * x * x);
    float e = __expf(2.0f * z);
    float th = 1.0f - 2.0f / (e + 1.0f);
    return 0.5f * x * (1.0f + th);
}
__device__ __forceinline__ float leaky(float x) { return x >= 0.0f ? x : 0.2f * x; }

__device__ __forceinline__ float lat_weight(const float* __restrict__ lat, int i, int n) {
    float w = cosf(lat[i]);
    if ((i == 0 || i == n - 1) && w < 0.001f) {
        float dlat = lat[1] - lat[0];
        float s = sinf(dlat * 0.25f);
        w = s * s / sinf(dlat * 0.5f);
    }
    return w;
}

// async global->LDS, 16B per lane; LDS dest is wave-uniform base + lane*16
__device__ __forceinline__ void gload16(const void* g, void* l) {
    __builtin_amdgcn_global_load_lds(
        (const __attribute__((address_space(1))) void*)(uintptr_t)g,
        (__attribute__((address_space(3))) void*)(uintptr_t)l,
        16, 0, 0);
}

// ================================================================ generic 128x128 MFMA GEMM
// A: [M][KD] (bf16 K-major, or fp32 if AF32). B: [N][KD] bf16 (n-major rows).
// BK=64, global_load_lds staging, both-sides XOR chunk swizzle (chunk ^= row&7).
// Grid: 1D nwg = (M/128)*NCOL, XCD-aware decode: bid%8 selects XCD (HW round-robin),
// each XCD owns a contiguous row band and iterates cols fastest -> A row-panel is
// fetched by exactly ONE XCD's L2 and reused across its NCOL col-blocks; B stays
// L2-resident. (R2 measured the anti-pattern: col-fastest global order -> +90% FETCH.)
// EPI: 0 gelu->bf16 O0[row][1536]; 1 split v/uu/uskip; 2 +bias2+uskip -> fp32 O0[row][256];
//      3 plain fp32 O0[row][256]; 4 +bias2+uskip -> bf16 O0[row][256].
template<int KD, int EPI, bool AF32, int NCOL>
__global__ __launch_bounds__(256) void gemm128_kernel(
    const void* __restrict__ Aptr, const u16* __restrict__ B,
    const float* __restrict__ bias, const float* __restrict__ uskip,
    void* __restrict__ O0, void* __restrict__ O1, void* __restrict__ O2)
{
    __shared__ __align__(16) u16 sA[128][64];
    __shared__ __align__(16) u16 sB[128][64];
    const int t = threadIdx.x;
    const int lane = t & 63, w = t >> 6;
    const int ln = lane & 15, q = lane >> 4;
    const int wr = w >> 1, wc = w & 1;
    // XCD-aware bijective remap (nwg % 8 == 0 for all instantiations)
    const int bid = blockIdx.x;
    const int xcd = bid & 7, idx = bid >> 3;
    const int rowsPerXcd = ((int)gridDim.x >> 3) / NCOL;
    const int row0 = (xcd * rowsPerXcd + idx / NCOL) * 128;
    const int col0 = (idx % NCOL) * 128;
    // async staging geometry: wave w, issue s covers rows s*32 + w*8 + (lane>>3);
    // each lane loads the 16B chunk (lane&7) XOR-swizzled by row&7 (= (lane>>3))
    const int grow = w * 8 + (lane >> 3);
    const int gcol = ((lane & 7) ^ (lane >> 3)) * 8;
    const int sr = t >> 1, sh = t & 1;

    f32x4 acc[16];
    #pragma unroll
    for (int i = 0; i < 16; ++i) acc[i] = (f32x4){0.f, 0.f, 0.f, 0.f};

    for (int k0 = 0; k0 < KD; k0 += 64) {
        __syncthreads();
        if (AF32) {
            // reg-stage fp32 -> bf16 (can't async): thread t covers row sr, cols sh*32..+31
            const float* Ag = (const float*)Aptr + (size_t)(row0 + sr) * KD + k0 + sh * 32;
            #pragma unroll
            for (int j = 0; j < 8; ++j) {
                float4 f = *(const float4*)(Ag + j * 4);
                int cp = (((4 * sh + (j >> 1)) ^ (sr & 7)) * 8) + (j & 1) * 4;
                *(ushort4*)&sA[sr][cp] = pack4(f.x, f.y, f.z, f.w);
            }
        } else {
            const u16* Ag = (const u16*)Aptr + (size_t)(row0 + grow) * KD + k0 + gcol;
            #pragma unroll
            for (int s = 0; s < 4; ++s)
                gload16(Ag + (size_t)(s * 32) * KD, &sA[s * 32 + w * 8][0]);
        }
        {
            const u16* Bg = B + (size_t)(col0 + grow) * KD + k0 + gcol;
            #pragma unroll
            for (int s = 0; s < 4; ++s)
                gload16(Bg + (size_t)(s * 32) * KD, &sB[s * 32 + w * 8][0]);
        }
        __syncthreads();
        #pragma unroll
        for (int kk = 0; kk < 2; ++kk) {
            bf16x8 af[4], bfr[4];
            #pragma unroll
            for (int x = 0; x < 4; ++x) {
                int ra = wr * 64 + x * 16 + ln;
                af[x] = *(const bf16x8*)&sA[ra][((kk * 4 + q) ^ (ra & 7)) * 8];
            }
            #pragma unroll
            for (int x = 0; x < 4; ++x) {
                int rb = wc * 64 + x * 16 + ln;
                bfr[x] = *(const bf16x8*)&sB[rb][((kk * 4 + q) ^ (rb & 7)) * 8];
            }
            #pragma unroll
            for (int rt = 0; rt < 4; ++rt)
                #pragma unroll
                for (int ct = 0; ct < 4; ++ct)
                    acc[rt * 4 + ct] = __builtin_amdgcn_mfma_f32_16x16x32_bf16(af[rt], bfr[ct], acc[rt * 4 + ct], 0, 0, 0);
        }
    }

    #pragma unroll
    for (int rt = 0; rt < 4; ++rt)
        #pragma unroll
        for (int ct = 0; ct < 4; ++ct) {
            int col = col0 + wc * 64 + ct * 16 + ln;
            float bv = (EPI == 3) ? 0.f : bias[col];
            #pragma unroll
            for (int r = 0; r < 4; ++r) {
                int row = row0 + wr * 64 + rt * 16 + q * 4 + r;
                float x = acc[rt * 4 + ct][r] + bv;
                if (EPI == 0) {
                    ((u16*)O0)[(size_t)row * 1536 + col] = f2b(gelu_tanh(x));
                } else if (EPI == 1) {
                    if (col < 512)      ((u16*)O0)[(size_t)row * 512 + col] = f2b(x);
                    else if (col < 768) ((u16*)O1)[(size_t)row * 256 + col - 512] = f2b(x);
                    else                ((float*)O2)[(size_t)row * 256 + col - 768] = x;
                } else if (EPI == 2) {
                    ((float*)O0)[(size_t)row * 256 + col] = x + uskip[(size_t)row * 256 + col];
                } else if (EPI == 4) {
                    ((u16*)O0)[(size_t)row * 256 + col] = f2b(x + uskip[(size_t)row * 256 + col]);
                } else {
                    ((float*)O0)[(size_t)row * 256 + col] = x;
                }
            }
        }
}

// ---------------------------------------------------------------- coalesced fp32->bf16 transpose
// out[c][r] = f2b(in[r][c]); R,C multiples of 32. Grid (C/32, R/32), 256 threads.
__global__ __launch_bounds__(256) void transpose_f32_bf16_kernel(
    const float* __restrict__ in, u16* __restrict__ out, int R, int C)
{
    __shared__ float tile[32][33];
    const int tx = threadIdx.x & 31, ty = threadIdx.x >> 5;   // ty 0..7
    const int c0 = blockIdx.x * 32, r0 = blockIdx.y * 32;
    #pragma unroll
    for (int p = 0; p < 4; ++p)
        tile[ty + p * 8][tx] = in[(size_t)(r0 + ty + p * 8) * C + c0 + tx];
    __syncthreads();
    #pragma unroll
    for (int p = 0; p < 4; ++p)
        out[(size_t)(c0 + ty + p * 8) * R + r0 + tx] = f2b(tile[tx][ty + p * 8]);
}

// u fp32 -> bf16, same layout (bit-identical f2b rounding as the old in-GEMM pack)
__global__ void conv_ubf_kernel(const float* __restrict__ u, u16* __restrict__ ub) {
    size_t i = ((size_t)blockIdx.x * 256 + threadIdx.x) * 4;
    float4 f = *(const float4*)(u + i);
    *(ushort4*)(ub + i) = pack4(f.x, f.y, f.z, f.w);
}

// ---------------------------------------------------------------- K1 fallback: fused cm MLP (R4, verified)
__global__ __launch_bounds__(256, 2) void cm_mlp_mfma_kernel(
    const float* __restrict__ u, const u16* __restrict__ w1t, const float* __restrict__ b1,
    const u16* __restrict__ w2t, const float* __restrict__ b2,
    u16* __restrict__ v, u16* __restrict__ uu, float* __restrict__ uskip)
{
    __shared__ __align__(16) u16 sA[16][264];
    __shared__ __align__(16) u16 sH[16][520];
    const int t = threadIdx.x;
    const int lane = t & 63, w = t >> 6;
    const int ln = lane & 15, q = lane >> 4;
    const int row0 = blockIdx.x * 16;

    for (int x = t; x < 1024; x += 256) {
        int r = x >> 6, c0 = (x & 63) * 4;
        float4 xx = *(const float4*)(u + (size_t)(row0 + r) * 256 + c0);
        sA[r][c0 + 0] = f2b(xx.x); sA[r][c0 + 1] = f2b(xx.y);
        sA[r][c0 + 2] = f2b(xx.z); sA[r][c0 + 3] = f2b(xx.w);
    }
    f32x4 c2[16];
    #pragma unroll
    for (int i = 0; i < 16; ++i) c2[i] = (f32x4){0.f, 0.f, 0.f, 0.f};

    for (int jj = 0; jj < 3; ++jj) {
        __syncthreads();
        f32x4 c1[8];
        #pragma unroll
        for (int i = 0; i < 8; ++i) c1[i] = (f32x4){0.f, 0.f, 0.f, 0.f};
        {
            const u16* w1p = w1t + (size_t)(jj * 512 + w * 128 + ln) * 256 + q * 8;
            #pragma unroll
            for (int k0 = 0; k0 < 256; k0 += 32) {
                bf16x8 a = *(const bf16x8*)&sA[ln][k0 + q * 8];
                #pragma unroll
                for (int nt = 0; nt < 8; ++nt) {
                    bf16x8 b = *(const bf16x8*)(w1p + (size_t)nt * 16 * 256 + k0);
                    c1[nt] = __builtin_amdgcn_mfma_f32_16x16x32_bf16(a, b, c1[nt], 0, 0, 0);
                }
            }
        }
        #pragma unroll
        for (int nt = 0; nt < 8; ++nt) {
            int col = w * 128 + nt * 16 + ln;
            float bias = b1[jj * 512 + col];
            #pragma unroll
            for (int r = 0; r < 4; ++r)
                sH[q * 4 + r][col] = f2b(gelu_tanh(c1[nt][r] + bias));
        }
        __syncthreads();
        const u16* w2p = w2t + (size_t)(w * 256 + ln) * 1536 + jj * 512 + q * 8;
        #pragma unroll 2
        for (int k0 = 0; k0 < 512; k0 += 32) {
            bf16x8 a = *(const bf16x8*)&sH[ln][k0 + q * 8];
            #pragma unroll
            for (int nt = 0; nt < 16; ++nt) {
                bf16x8 b = *(const bf16x8*)(w2p + (size_t)nt * 16 * 1536 + k0);
                c2[nt] = __builtin_amdgcn_mfma_f32_16x16x32_bf16(a, b, c2[nt], 0, 0, 0);
            }
        }
    }
    #pragma unroll
    for (int nt = 0; nt < 16; ++nt) {
        int col = w * 256 + nt * 16 + ln;
        float bias = b2[col];
        #pragma unroll
        for (int r = 0; r < 4; ++r) {
            int row = row0 + q * 4 + r;
            float val = c2[nt][r] + bias;
            if (col < 512)      v[(size_t)row * 512 + col] = f2b(val);
            else if (col < 768) uu[(size_t)row * 256 + (col - 512)] = f2b(val);
            else                uskip[(size_t)row * 256 + (col - 768)] = val;
        }
    }
}

// ---------------------------------------------------------------- K2: means of uu (4-way ILP chains)
__global__ void mean_over_lat_kernel(const u16* __restrict__ uu, float* __restrict__ Mlong) {
    int l = blockIdx.x, d = threadIdx.x;
    const u16* p = uu + (size_t)l * 256 + d;
    float s0 = 0.f, s1 = 0.f, s2 = 0.f, s3 = 0.f;
    for (int i = 0; i < 32; ++i) {
        s0 += b2f(p[(size_t)(i      ) * NLON * 256]);
        s1 += b2f(p[(size_t)(i +  32) * NLON * 256]);
        s2 += b2f(p[(size_t)(i +  64) * NLON * 256]);
        s3 += b2f(p[(size_t)(i +  96) * NLON * 256]);
    }
    Mlong[(size_t)l * 256 + d] = (s0 + s1 + s2 + s3) * (1.0f / NLAT);
}
__global__ void mean_over_lon_kernel(const u16* __restrict__ uu, float* __restrict__ Mlat) {
    int i = blockIdx.x, d = threadIdx.x;
    const u16* p = uu + (size_t)i * NLON * 256 + d;
    float s0 = 0.f, s1 = 0.f, s2 = 0.f, s3 = 0.f;
    for (int l = 0; l < 64; ++l) {
        s0 += b2f(p[(size_t)(l      ) * 256]);
        s1 += b2f(p[(size_t)(l +  64) * 256]);
        s2 += b2f(p[(size_t)(l + 128) * 256]);
        s3 += b2f(p[(size_t)(l + 192) * 256]);
    }
    Mlat[(size_t)i * 256 + d] = (s0 + s1 + s2 + s3) * (1.0f / NLON);
}

__device__ float block_sum256(float x, float* red) {
    #pragma unroll
    for (int o = 32; o > 0; o >>= 1) x += __shfl_down(x, o, 64);
    int wid = threadIdx.x >> 6, lane = threadIdx.x & 63;
    if (lane == 0) red[wid] = x;
    __syncthreads();
    float s = red[0] + red[1] + red[2] + red[3];
    __syncthreads();
    return s;
}

// ---------------------------------------------------------------- K3: pool MLP (split chains for ILP)
__global__ __launch_bounds__(256) void pool_mlp_kernel(
    const float* __restrict__ xin, const float* __restrict__ in_w,
    const float* __restrict__ ln_g, const float* __restrict__ ln_b,
    const float* __restrict__ fc1_w, const float* __restrict__ fc1_b,
    const float* __restrict__ fc2_w, const float* __restrict__ fc2_b,
    const float* __restrict__ lat, float* __restrict__ out)
{
    __shared__ float sx[256], sy[256], sg[256], red[4];
    int row = blockIdx.x, t = threadIdx.x;
    sx[t] = xin[(size_t)row * 256 + t];
    __syncthreads();
    float a0 = 0.f, a1 = 0.f;
    #pragma unroll 4
    for (int i = 0; i < 128; ++i) {
        a0 = fmaf(sx[i],       in_w[i * 256 + t],         a0);
        a1 = fmaf(sx[i + 128], in_w[(i + 128) * 256 + t], a1);
    }
    float acc = a0 + a1;
    if (lat) acc *= lat_weight(lat, row, NLAT);
    float m = block_sum256(acc, red) * (1.f / 256.f);
    float var = block_sum256(acc * acc, red) * (1.f / 256.f) - m * m;
    float xn = (acc - m) * rsqrtf(var + 1e-5f) * ln_g[t] + ln_b[t];
    sy[t] = xn;
    __syncthreads();
    float h1a = 0.f, h1b = 0.f, h2a = 0.f, h2b = 0.f;
    #pragma unroll 4
    for (int i = 0; i < 128; ++i) {
        float s0 = sy[i], s1 = sy[i + 128];
        h1a = fmaf(s0, fc1_w[i * 512 + t], h1a);
        h1b = fmaf(s1, fc1_w[(i + 128) * 512 + t], h1b);
        h2a = fmaf(s0, fc1_w[i * 512 + 256 + t], h2a);
        h2b = fmaf(s1, fc1_w[(i + 128) * 512 + 256 + t], h2b);
    }
    float h1 = fc1_b[t] + h1a + h1b;
    float h2 = fc1_b[t + 256] + h2a + h2b;
    float g = h1 * gelu_tanh(h2);
    sg[t] = g;
    __syncthreads();
    float o0 = 0.f, o1 = 0.f;
    #pragma unroll 4
    for (int i = 0; i < 128; ++i) {
        o0 = fmaf(sg[i],       fc2_w[i * 256 + t],         o0);
        o1 = fmaf(sg[i + 128], fc2_w[(i + 128) * 256 + t], o1);
    }
    out[(size_t)row * 256 + t] = fc2_b[t] + o0 + o1;
}

// ---------------------------------------------------------------- K4: bessel
__global__ void bessel_kernel(const float* __restrict__ coord, int n,
                              const float* __restrict__ freq, int nf,
                              const float* __restrict__ w, float* __restrict__ mod,
                              int periodic)
{
    int i = blockIdx.x, j = threadIdx.x;
    float d = fabsf(coord[j] - coord[i]);
    if (periodic) d = fminf(d, TWO_PI_F - d);
    float acc[8];
    #pragma unroll
    for (int h = 0; h < 8; ++h) acc[h] = 0.f;
    bool big = d > 1e-6f;
    float inv = big ? 1.f / d : 0.f;
    for (int k = 0; k < nf; ++k) {
        float f = freq[k];
        float basis = big ? sinf(f * d) * inv : f;
        #pragma unroll
        for (int h = 0; h < 8; ++h) acc[h] = fmaf(basis, w[k * 8 + h], acc[h]);
    }
    #pragma unroll
    for (int h = 0; h < 8; ++h) mod[((size_t)h * n + i) * n + j] = acc[h];
}

// ---------------------------------------------------------------- K5: projections (tiled, latency-fixed)
__global__ __launch_bounds__(256) void proj_tile_kernel(
    const float* __restrict__ x, const float* __restrict__ w,
    float* __restrict__ c)
{
    const int t = threadIdx.x;
    const int j = blockIdx.y * 256 + t;
    const float* xp = x + (size_t)blockIdx.x * 16 * 256;
    const float* wp = w + j;
    float acc[16];
    #pragma unroll
    for (int r = 0; r < 16; ++r) acc[r] = 0.f;
    for (int i0 = 0; i0 < 256; i0 += 4) {
        float w0 = wp[(size_t)(i0 + 0) * 1536];
        float w1 = wp[(size_t)(i0 + 1) * 1536];
        float w2 = wp[(size_t)(i0 + 2) * 1536];
        float w3 = wp[(size_t)(i0 + 3) * 1536];
        #pragma unroll
        for (int r = 0; r < 16; ++r) {
            float4 xv = *(const float4*)(xp + r * 256 + i0);   // uniform -> s_load_dwordx4
            acc[r] = fmaf(xv.x, w0, acc[r]);
            acc[r] = fmaf(xv.y, w1, acc[r]);
            acc[r] = fmaf(xv.z, w2, acc[r]);
            acc[r] = fmaf(xv.w, w3, acc[r]);
        }
    }
    float* cp = c + (size_t)blockIdx.x * 16 * 1536 + j;
    #pragma unroll
    for (int r = 0; r < 16; ++r) cp[(size_t)r * 1536] = acc[r];
}

// ---------------------------------------------------------------- K6a: k_long -> KlongA[h][l][m] bf16 (K-major)
__global__ __launch_bounds__(256) void kmat_long_kernel(
    const float* __restrict__ q, const float* __restrict__ kp,
    const float* __restrict__ mod, u16* __restrict__ KA)
{
    int blk = blockIdx.x;              // h*256 + l   (grid 2048)
    int l = blk & 255, h = blk >> 8;
    __shared__ float sq[192];
    int t = threadIdx.x;
    if (t < 192) sq[t] = q[(size_t)l * 1536 + h * 192 + t];
    __syncthreads();
    const float* kpp = kp + (size_t)t * 1536 + h * 192;
    float acc = 0.f;
    #pragma unroll 4
    for (int c = 0; c < 192; ++c) acc = fmaf(kpp[c], sq[c], acc);
    float mv = mod[((size_t)h * 256 + l) * 256 + t];
    float val = leaky(acc * mv) * (TWO_PI_F / 256.f);
    KA[((size_t)h * 256 + l) * 256 + t] = f2b(val);
}

// ---------------------------------------------------------------- K6b: k_lat -> KlatA[h][i][j] bf16 (K-major)
__global__ __launch_bounds__(128) void kmat_lat_kernel(
    const float* __restrict__ q, const float* __restrict__ kp,
    const float* __restrict__ mod, const float* __restrict__ lat, u16* __restrict__ KA)
{
    int blk = blockIdx.x;              // h*128 + i   (grid 1024)
    int i = blk & 127, h = blk >> 7;
    __shared__ float sq[192];
    int t = threadIdx.x;
    for (int c = t; c < 192; c += 128) sq[c] = q[(size_t)i * 1536 + h * 192 + c];
    __syncthreads();
    const float* kpp = kp + (size_t)t * 1536 + h * 192;
    float acc = 0.f;
    #pragma unroll 4
    for (int c = 0; c < 192; ++c) acc = fmaf(kpp[c], sq[c], acc);
    float mv = mod[((size_t)h * 128 + i) * 128 + t];
    float wl = lat_weight(lat, t, NLAT);
    float val = leaky(acc * mv) * wl * (PI_F / 128.f);
    KA[((size_t)h * 128 + i) * 128 + t] = f2b(val);
}

// ---------------------------------------------------------------- K7: einsum1 MFMA (per batch)
__global__ __launch_bounds__(256) void einsum1_kernel(
    const u16* __restrict__ KlatA, const u16* __restrict__ v, u16* __restrict__ tmp1)
{
    int blk = blockIdx.x;              // h*256 + m (grid 2048)
    int m = blk & 255, h = blk >> 8;
    __shared__ __align__(16) u16 sV[64][136];   // [c][j], rows 272 B (16-aligned)
    const int t = threadIdx.x;
    const int lane = t & 63, w = t >> 6;
    const int ln = lane & 15, q = lane >> 4;

    {   // transpose-stage v slice [j=128][c=64] -> sV[c][j]
        int j = t >> 1, c0 = (t & 1) * 32;
        const u16* vp = v + ((size_t)j * 256 + m) * 512 + h * 64 + c0;
        union { uint4 q4[4]; u16 s[32]; } buf;
        buf.q4[0] = *(const uint4*)(vp);
        buf.q4[1] = *(const uint4*)(vp + 8);
        buf.q4[2] = *(const uint4*)(vp + 16);
        buf.q4[3] = *(const uint4*)(vp + 24);
        #pragma unroll
        for (int cc = 0; cc < 32; ++cc) sV[c0 + cc][j] = buf.s[cc];
    }
    __syncthreads();

    f32x4 acc[8];
    #pragma unroll
    for (int i = 0; i < 8; ++i) acc[i] = (f32x4){0.f, 0.f, 0.f, 0.f};
    const u16* ka = KlatA + (size_t)h * 128 * 128;
    for (int ch = 0; ch < 4; ++ch) {
        int j0 = ch * 32;
        bf16x8 b = *(const bf16x8*)&sV[w * 16 + ln][j0 + q * 8];
        #pragma unroll
        for (int it = 0; it < 8; ++it) {
            bf16x8 a = *(const bf16x8*)(ka + (size_t)(it * 16 + ln) * 128 + j0 + q * 8);
            acc[it] = __builtin_amdgcn_mfma_f32_16x16x32_bf16(a, b, acc[it], 0, 0, 0);
        }
    }
    int c = w * 16 + ln;
    #pragma unroll
    for (int it = 0; it < 8; ++it)
        #pragma unroll
        for (int r = 0; r < 4; ++r) {
            int i = it * 16 + q * 4 + r;
            tmp1[(((size_t)h * 128 + i) * 256 + m) * 64 + c] = f2b(acc[it][r]);
        }
}

// ---------------------------------------------------------------- K8: einsum2 MFMA + GN stats (per batch)
__global__ __launch_bounds__(256) void einsum2_kernel(
    const u16* __restrict__ tmp1, const u16* __restrict__ KlongA,
    u16* __restrict__ Aout, float* __restrict__ gnstat)
{
    int blk = blockIdx.x;              // h*128 + i (grid 1024)
    int i = blk & 127, h = blk >> 7;
    __shared__ __align__(16) u16 sT[64][264];   // [c][m], rows 528 B (16-aligned)
    __shared__ float red2[8];
    const int t = threadIdx.x;
    const int lane = t & 63, w = t >> 6;
    const int ln = lane & 15, q = lane >> 4;

    {   // transpose-stage tmp1 slice [m=256][c=64] -> sT[c][m]
        const u16* tp = tmp1 + (((size_t)h * 128 + i) * 256 + t) * 64;
        union { uint4 q4[8]; u16 s[64]; } buf;
        #pragma unroll
        for (int x = 0; x < 8; ++x) buf.q4[x] = *(const uint4*)(tp + x * 8);
        #pragma unroll
        for (int cc = 0; cc < 64; ++cc) sT[cc][t] = buf.s[cc];
    }
    __syncthreads();

    f32x4 acc[16];
    #pragma unroll
    for (int x = 0; x < 16; ++x) acc[x] = (f32x4){0.f, 0.f, 0.f, 0.f};
    const u16* ka = KlongA + (size_t)h * 256 * 256;
    for (int ch = 0; ch < 8; ++ch) {
        int m0 = ch * 32;
        bf16x8 bf[4];
        #pragma unroll
        for (int ct = 0; ct < 4; ++ct) bf[ct] = *(const bf16x8*)&sT[ct * 16 + ln][m0 + q * 8];
        #pragma unroll
        for (int lt = 0; lt < 4; ++lt) {
            bf16x8 a = *(const bf16x8*)(ka + (size_t)(w * 64 + lt * 16 + ln) * 256 + m0 + q * 8);
            #pragma unroll
            for (int ct = 0; ct < 4; ++ct)
                acc[lt * 4 + ct] = __builtin_amdgcn_mfma_f32_16x16x32_bf16(a, bf[ct], acc[lt * 4 + ct], 0, 0, 0);
        }
    }
    float lsum = 0.f, lsq = 0.f;
    #pragma unroll
    for (int lt = 0; lt < 4; ++lt)
        #pragma unroll
        for (int ct = 0; ct < 4; ++ct) {
            int c = ct * 16 + ln;
            #pragma unroll
            for (int r = 0; r < 4; ++r) {
                int l = w * 64 + lt * 16 + q * 4 + r;
                float val = acc[lt * 4 + ct][r];
                Aout[((size_t)i * 256 + l) * 512 + h * 64 + c] = f2b(val);
                lsum += val; lsq += val * val;
            }
        }
    #pragma unroll
    for (int o = 32; o > 0; o >>= 1) {
        lsum += __shfl_down(lsum, o, 64);
        lsq  += __shfl_down(lsq, o, 64);
    }
    if ((t & 63) == 0) { red2[w] = lsum; red2[4 + w] = lsq; }
    __syncthreads();
    if (t == 0) {
        atomicAdd(&gnstat[h * 2],     red2[0] + red2[1] + red2[2] + red2[3]);
        atomicAdd(&gnstat[h * 2 + 1], red2[4] + red2[5] + red2[6] + red2[7]);
    }
}

// ---------------------------------------------------------------- K9: fold GN into merge weights (per batch)
__global__ __launch_bounds__(256) void gn_fold_kernel(
    const float* __restrict__ gnstat, const float* __restrict__ gn_g, const float* __restrict__ gn_b,
    const float* __restrict__ mw, u16* __restrict__ Wp, float* __restrict__ bias2)
{
    __shared__ float red[4];
    int j = blockIdx.x, t = threadIdx.x;
    const float Ninv = 1.f / 2097152.f;   // 128*256*64
    float partial = 0.f;
    for (int k = t; k < 512; k += 256) {
        int h = k >> 6;
        float m = gnstat[h * 2] * Ninv;
        float var = gnstat[h * 2 + 1] * Ninv - m * m;
        float siv = rsqrtf(var + 1e-5f);
        float s = siv * gn_g[k];
        float tt = gn_b[k] - m * s;
        float wv = mw[(size_t)k * 256 + j];
        Wp[(size_t)j * 512 + k] = f2b(s * wv);
        partial += tt * wv;
    }
    float tot = block_sum256(partial, red);
    if (t == 0) bias2[j] = tot;
}

__global__ void zero_kernel(float* __restrict__ p, int n) {
    int i = blockIdx.x * blockDim.x + threadIdx.x;
    if (i < n) p[i] = 0.f;
}

// ================================================================ launch
extern "C" void kernel_launch(void* const* d_in, const int* in_sizes, int n_in,
                              void* d_out, int out_size, void* d_ws, size_t ws_size,
                              hipStream_t stream) {
    if (ws_size < 77856896ULL) return;   // known-good minimum from R3/R4
    const bool BIG = (ws_size >= 184549376ULL);  // de-fused cm path needs 96MB hidden

    const float* u        = (const float*)d_in[0];
    const float* lat      = (const float*)d_in[1];
    const float* lon      = (const float*)d_in[2];
    const float* cm_w1    = (const float*)d_in[3];
    const float* cm_b1    = (const float*)d_in[4];
    const float* cm_w2    = (const float*)d_in[5];
    const float* cm_b2    = (const float*)d_in[6];
    const float* long_in_w  = (const float*)d_in[7];
    const float* long_ln_g  = (const float*)d_in[8];
    const float* long_ln_b  = (const float*)d_in[9];
    const float* long_fc1_w = (const float*)d_in[10];
    const float* long_fc1_b = (const float*)d_in[11];
    const float* long_fc2_w = (const float*)d_in[12];
    const float* long_fc2_b = (const float*)d_in[13];
    const float* lat_in_w   = (const float*)d_in[14];
    const float* lat_ln_g   = (const float*)d_in[15];
    const float* lat_ln_b   = (const float*)d_in[16];
    const float* lat_fc1_w  = (const float*)d_in[17];
    const float* lat_fc1_b  = (const float*)d_in[18];
    const float* lat_fc2_w  = (const float*)d_in[19];
    const float* lat_fc2_b  = (const float*)d_in[20];
    const float* klong_q_w  = (const float*)d_in[21];
    const float* klong_k_w  = (const float*)d_in[22];
    const float* klat_q_w   = (const float*)d_in[23];
    const float* klat_k_w   = (const float*)d_in[24];
    const float* pe_long_freq = (const float*)d_in[25];
    const float* pe_long_w    = (const float*)d_in[26];
    const float* pe_lat_freq  = (const float*)d_in[27];
    const float* pe_lat_w     = (const float*)d_in[28];
    const float* gn_g    = (const float*)d_in[29];
    const float* gn_b    = (const float*)d_in[30];
    const float* merge_w = (const float*)d_in[31];
    const float* out_w   = (const float*)d_in[32];
    float* out = (float*)d_out;

    char* base = (char*)d_ws;
    u16*  vA   = (u16*)base;                          // v bf16 (32MB) -> Aout bf16 (32MB)
    char* reg1 = base + 33554432;                     // ubf bf16 (16MB) -> uu bf16 (16MB) -> tmp1 bf16 (32MB) -> Dbf bf16 (16MB)
    u16*  ubf  = (u16*)reg1;
    u16*  uu   = (u16*)reg1;
    u16*  tmp1 = (u16*)reg1;
    u16*  Dbf  = (u16*)reg1;
    // small pool (floats from base+64MB); end = 76,940,416 B < 77,856,896 guard
    float* pool    = (float*)(base + 67108864);
    float* modlong = pool;                            // 524288
    float* modlat  = modlong + 524288;                // 131072
    float* Mlong   = modlat + 131072;                 // 65536
    float* Mlat    = Mlong + 65536;                   // 32768
    float* ulong   = Mlat + 32768;                    // 65536
    float* ulat    = ulong + 65536;                   // 32768
    float* qlong   = ulat + 32768;                    // 393216
    float* klongp  = qlong + 393216;                  // 393216
    float* qlat    = klongp + 393216;                 // 196608
    float* klatp   = qlat + 196608;                   // 196608
    float* gnstat  = klatp + 196608;                  // 32
    float* bias2   = gnstat + 32;                     // 256
    u16* KlongA = (u16*)(bias2 + 256);                // 524288 elems (1MB)
    u16* KlatA  = KlongA + 524288;                    // 131072 elems
    u16* Wp     = KlatA + 131072;                     // 131072 elems
    u16* owT    = Wp + 131072;                        // 65536 elems
    // small-path weight aliases (dead at cm time, re-converted per batch)
    u16* w1T = (u16*)qlong;                           // 786,432 B in qlong (1.5MB)
    u16* w2T = (u16*)klongp;                          // 3,145,728 B in klongp+qlat+klatp
    // big-path dedicated regions
    u16* w1Tb   = (u16*)(base + 79691776);            // 786,432 B
    u16* w2Tb   = (u16*)(base + 80478208);            // 3,145,728 B
    u16* hidden = (u16*)(base + 83886080);            // 100,663,296 B (32768x1536 bf16)

    zero_kernel<<<1, 32, 0, stream>>>(gnstat, 32);
    bessel_kernel<<<256, 256, 0, stream>>>(lon, 256, pe_long_freq, 64, pe_long_w, modlong, 1);
    bessel_kernel<<<128, 128, 0, stream>>>(lat, 128, pe_lat_freq, 32, pe_lat_w, modlat, 0);
    // owT[256][256] <- out_w^T (coalesced)
    transpose_f32_bf16_kernel<<<dim3(8, 8), 256, 0, stream>>>(out_w, owT, 256, 256);
    if (BIG) {
        // w1Tb[1536][256] <- cm_w1^T; w2Tb[1024][1536] <- cm_w2^T (coalesced)
        transpose_f32_bf16_kernel<<<dim3(48, 8), 256, 0, stream>>>(cm_w1, w1Tb, 256, 1536);
        transpose_f32_bf16_kernel<<<dim3(32, 48), 256, 0, stream>>>(cm_w2, w2Tb, 1536, 1024);
    }

    for (int b = 0; b < 2; ++b) {
        const float* u_b  = u + (size_t)b * 32768 * 256;
        float* uskip_b    = out + (size_t)b * 8388608;
        float* gnstat_b   = gnstat + b * 16;

        if (BIG) {
            // u -> bf16 once (bit-identical to the old in-GEMM pack)
            conv_ubf_kernel<<<8192, 256, 0, stream>>>(u_b, ubf);
            // GEMM1: hidden = gelu(u@W1+b1)  [32768 x 1536], K=256, NCOL=12
            gemm128_kernel<256, 0, false, 12><<<3072, 256, 0, stream>>>(
                ubf, w1Tb, cm_b1, nullptr, hidden, nullptr, nullptr);
            // GEMM2: hidden@W2+b2 -> v|uu|uskip  [32768 x 1024], K=1536, NCOL=8
            gemm128_kernel<1536, 1, false, 8><<<2048, 256, 0, stream>>>(
                hidden, w2Tb, cm_b2, nullptr, vA, uu, uskip_b);
        } else {
            transpose_f32_bf16_kernel<<<dim3(48, 8), 256, 0, stream>>>(cm_w1, w1T, 256, 1536);
            transpose_f32_bf16_kernel<<<dim3(32, 48), 256, 0, stream>>>(cm_w2, w2T, 1536, 1024);
            cm_mlp_mfma_kernel<<<2048, 256, 0, stream>>>(u_b, w1T, cm_b1, w2T, cm_b2,
                                                         vA, uu, uskip_b);
        }
        mean_over_lat_kernel<<<256, 256, 0, stream>>>(uu, Mlong);
        mean_over_lon_kernel<<<128, 256, 0, stream>>>(uu, Mlat);
        pool_mlp_kernel<<<256, 256, 0, stream>>>(Mlong, long_in_w, long_ln_g, long_ln_b,
                                                 long_fc1_w, long_fc1_b, long_fc2_w, long_fc2_b,
                                                 nullptr, ulong);
        pool_mlp_kernel<<<128, 256, 0, stream>>>(Mlat, lat_in_w, lat_ln_g, lat_ln_b,
                                                 lat_fc1_w, lat_fc1_b, lat_fc2_w, lat_fc2_b,
                                                 lat, ulat);
        proj_tile_kernel<<<dim3(16, 6), 256, 0, stream>>>(ulong, klong_q_w, qlong);   // clobbers w1T (dead)
        proj_tile_kernel<<<dim3(16, 6), 256, 0, stream>>>(ulong, klong_k_w, klongp);  // clobbers w2T (dead)
        proj_tile_kernel<<<dim3(8, 6), 256, 0, stream>>>(ulat, klat_q_w, qlat);
        proj_tile_kernel<<<dim3(8, 6), 256, 0, stream>>>(ulat, klat_k_w, klatp);
        kmat_long_kernel<<<2048, 256, 0, stream>>>(qlong, klongp, modlong, KlongA);
        kmat_lat_kernel<<<1024, 128, 0, stream>>>(qlat, klatp, modlat, lat, KlatA);
        einsum1_kernel<<<2048, 256, 0, stream>>>(KlatA, vA, tmp1);       // tmp1 over uu (dead)
        einsum2_kernel<<<1024, 256, 0, stream>>>(tmp1, KlongA, vA, gnstat_b); // Aout over v (dead)
        gn_fold_kernel<<<256, 256, 0, stream>>>(gnstat_b, gn_g, gn_b, merge_w, Wp, bias2);
        // merge: Dbf = bf16(GN(Aout)@mw + uskip)   [32768 x 256], K=512, NCOL=2
        gemm128_kernel<512, 4, false, 2><<<512, 256, 0, stream>>>(
            vA, Wp, bias2, uskip_b, Dbf, nullptr, nullptr);
        // out: out = Dbf@ow                [32768 x 256], K=256, NCOL=2
        gemm128_kernel<256, 3, false, 2><<<512, 256, 0, stream>>>(
            Dbf, owT, nullptr, nullptr, out + (size_t)b * 8388608, nullptr, nullptr);
    }
}

// Round 8
// 1331.419 us; speedup vs baseline: 1.4732x; 1.2034x over previous
//
#include <hip/hip_runtime.h>
#include <math.h>
#include <stdint.h>

#define NLAT 128
#define NLON 256
#define PI_F 3.14159265358979323846f
#define TWO_PI_F 6.28318530717958647692f

typedef unsigned short u16;
typedef __attribute__((ext_vector_type(8))) short bf16x8;
typedef __attribute__((ext_vector_type(4))) float f32x4;

__device__ __forceinline__ u16 f2b(float f) {
    union { float f; uint32_t u; } v; v.f = f;
    uint32_t r = v.u + 0x7fffu + ((v.u >> 16) & 1u);
    return (u16)(r >> 16);
}
__device__ __forceinline__ float b2f(u16 u) {
    union { uint32_t u; float f; } v; v.u = ((uint32_t)u) << 16;
    return v.f;
}
__device__ __forceinline__ ushort4 pack4(float a, float b, float c, float d) {
    ushort4 r; r.x = f2b(a); r.y = f2b(b); r.z = f2b(c); r.w = f2b(d); return r;
}
// tanh-approx gelu with fast exp: tanh(z) = 1 - 2/(e^{2z}+1).
// |err| ~1e-6 vs tanhf — invisible under bf16 output rounding (quantum ~8e-3).
__device__ __forceinline__ float gelu_tanh(float x) {
    float z = 0.7978845608028654f * (x + 0.044715f * x * x * x);
    float e = __expf(2.0f * z);
    float th = 1.0f - 2.0f / (e + 1.0f);
    return 0.5f * x * (1.0f + th);
}
__device__ __forceinline__ float leaky(float x) { return x >= 0.0f ? x : 0.2f * x; }

__device__ __forceinline__ float lat_weight(const float* __restrict__ lat, int i, int n) {
    float w = cosf(lat[i]);
    if ((i == 0 || i == n - 1) && w < 0.001f) {
        float dlat = lat[1] - lat[0];
        float s = sinf(dlat * 0.25f);
        w = s * s / sinf(dlat * 0.5f);
    }
    return w;
}

// async global->LDS, 16B per lane; LDS dest is wave-uniform base + lane*16
__device__ __forceinline__ void gload16(const void* g, void* l) {
    __builtin_amdgcn_global_load_lds(
        (const __attribute__((address_space(1))) void*)(uintptr_t)g,
        (__attribute__((address_space(3))) void*)(uintptr_t)l,
        16, 0, 0);
}

// ================================================================ generic 128x128 MFMA GEMM
// A: [M][KD] (bf16 K-major, or fp32 if AF32). B: [N][KD] bf16 (n-major rows).
// BK=64, global_load_lds staging, both-sides XOR chunk swizzle (chunk ^= row&7).
// Grid: 1D nwg = (M/128)*NCOL, XCD-aware decode: bid%8 selects XCD (HW round-robin),
// each XCD owns a contiguous row band and iterates cols fastest -> A row-panel is
// fetched by exactly ONE XCD's L2 and reused across its NCOL col-blocks; B stays
// L2-resident. (R7 measured: GEMM2 FETCH 209->98.5 MB = optimal single pass.)
// EPI: 0 gelu->bf16 O0[row][1536]; 1 split v/uu/uskip; 2 +bias2+uskip -> fp32 O0[row][256];
//      3 plain fp32 O0[row][256]; 4 +bias2+uskip -> bf16 O0[row][256].
template<int KD, int EPI, bool AF32, int NCOL>
__global__ __launch_bounds__(256) void gemm128_kernel(
    const void* __restrict__ Aptr, const u16* __restrict__ B,
    const float* __restrict__ bias, const float* __restrict__ uskip,
    void* __restrict__ O0, void* __restrict__ O1, void* __restrict__ O2)
{
    __shared__ __align__(16) u16 sA[128][64];
    __shared__ __align__(16) u16 sB[128][64];
    const int t = threadIdx.x;
    const int lane = t & 63, w = t >> 6;
    const int ln = lane & 15, q = lane >> 4;
    const int wr = w >> 1, wc = w & 1;
    // XCD-aware bijective remap (nwg % 8 == 0 for all instantiations)
    const int bid = blockIdx.x;
    const int xcd = bid & 7, idx = bid >> 3;
    const int rowsPerXcd = ((int)gridDim.x >> 3) / NCOL;
    const int row0 = (xcd * rowsPerXcd + idx / NCOL) * 128;
    const int col0 = (idx % NCOL) * 128;
    // async staging geometry: wave w, issue s covers rows s*32 + w*8 + (lane>>3);
    // each lane loads the 16B chunk (lane&7) XOR-swizzled by row&7 (= (lane>>3))
    const int grow = w * 8 + (lane >> 3);
    const int gcol = ((lane & 7) ^ (lane >> 3)) * 8;
    const int sr = t >> 1, sh = t & 1;

    f32x4 acc[16];
    #pragma unroll
    for (int i = 0; i < 16; ++i) acc[i] = (f32x4){0.f, 0.f, 0.f, 0.f};

    for (int k0 = 0; k0 < KD; k0 += 64) {
        __syncthreads();
        if (AF32) {
            // reg-stage fp32 -> bf16 (can't async): thread t covers row sr, cols sh*32..+31
            const float* Ag = (const float*)Aptr + (size_t)(row0 + sr) * KD + k0 + sh * 32;
            #pragma unroll
            for (int j = 0; j < 8; ++j) {
                float4 f = *(const float4*)(Ag + j * 4);
                int cp = (((4 * sh + (j >> 1)) ^ (sr & 7)) * 8) + (j & 1) * 4;
                *(ushort4*)&sA[sr][cp] = pack4(f.x, f.y, f.z, f.w);
            }
        } else {
            const u16* Ag = (const u16*)Aptr + (size_t)(row0 + grow) * KD + k0 + gcol;
            #pragma unroll
            for (int s = 0; s < 4; ++s)
                gload16(Ag + (size_t)(s * 32) * KD, &sA[s * 32 + w * 8][0]);
        }
        {
            const u16* Bg = B + (size_t)(col0 + grow) * KD + k0 + gcol;
            #pragma unroll
            for (int s = 0; s < 4; ++s)
                gload16(Bg + (size_t)(s * 32) * KD, &sB[s * 32 + w * 8][0]);
        }
        __syncthreads();
        #pragma unroll
        for (int kk = 0; kk < 2; ++kk) {
            bf16x8 af[4], bfr[4];
            #pragma unroll
            for (int x = 0; x < 4; ++x) {
                int ra = wr * 64 + x * 16 + ln;
                af[x] = *(const bf16x8*)&sA[ra][((kk * 4 + q) ^ (ra & 7)) * 8];
            }
            #pragma unroll
            for (int x = 0; x < 4; ++x) {
                int rb = wc * 64 + x * 16 + ln;
                bfr[x] = *(const bf16x8*)&sB[rb][((kk * 4 + q) ^ (rb & 7)) * 8];
            }
            #pragma unroll
            for (int rt = 0; rt < 4; ++rt)
                #pragma unroll
                for (int ct = 0; ct < 4; ++ct)
                    acc[rt * 4 + ct] = __builtin_amdgcn_mfma_f32_16x16x32_bf16(af[rt], bfr[ct], acc[rt * 4 + ct], 0, 0, 0);
        }
    }

    #pragma unroll
    for (int rt = 0; rt < 4; ++rt)
        #pragma unroll
        for (int ct = 0; ct < 4; ++ct) {
            int col = col0 + wc * 64 + ct * 16 + ln;
            float bv = (EPI == 3) ? 0.f : bias[col];
            #pragma unroll
            for (int r = 0; r < 4; ++r) {
                int row = row0 + wr * 64 + rt * 16 + q * 4 + r;
                float x = acc[rt * 4 + ct][r] + bv;
                if (EPI == 0) {
                    ((u16*)O0)[(size_t)row * 1536 + col] = f2b(gelu_tanh(x));
                } else if (EPI == 1) {
                    if (col < 512)      ((u16*)O0)[(size_t)row * 512 + col] = f2b(x);
                    else if (col < 768) ((u16*)O1)[(size_t)row * 256 + col - 512] = f2b(x);
                    else                ((float*)O2)[(size_t)row * 256 + col - 768] = x;
                } else if (EPI == 2) {
                    ((float*)O0)[(size_t)row * 256 + col] = x + uskip[(size_t)row * 256 + col];
                } else if (EPI == 4) {
                    ((u16*)O0)[(size_t)row * 256 + col] = f2b(x + uskip[(size_t)row * 256 + col]);
                } else {
                    ((float*)O0)[(size_t)row * 256 + col] = x;
                }
            }
        }
}

// ---------------------------------------------------------------- coalesced fp32->bf16 transpose
// out[c][r] = f2b(in[r][c]); R,C multiples of 32. Grid (C/32, R/32), 256 threads.
__global__ __launch_bounds__(256) void transpose_f32_bf16_kernel(
    const float* __restrict__ in, u16* __restrict__ out, int R, int C)
{
    __shared__ float tile[32][33];
    const int tx = threadIdx.x & 31, ty = threadIdx.x >> 5;   // ty 0..7
    const int c0 = blockIdx.x * 32, r0 = blockIdx.y * 32;
    #pragma unroll
    for (int p = 0; p < 4; ++p)
        tile[ty + p * 8][tx] = in[(size_t)(r0 + ty + p * 8) * C + c0 + tx];
    __syncthreads();
    #pragma unroll
    for (int p = 0; p < 4; ++p)
        out[(size_t)(c0 + ty + p * 8) * R + r0 + tx] = f2b(tile[tx][ty + p * 8]);
}

// u fp32 -> bf16, same layout (bit-identical f2b rounding as the old in-GEMM pack)
__global__ void conv_ubf_kernel(const float* __restrict__ u, u16* __restrict__ ub) {
    size_t i = ((size_t)blockIdx.x * 256 + threadIdx.x) * 4;
    float4 f = *(const float4*)(u + i);
    *(ushort4*)(ub + i) = pack4(f.x, f.y, f.z, f.w);
}

// ---------------------------------------------------------------- K1 fallback: fused cm MLP (R4, verified)
__global__ __launch_bounds__(256, 2) void cm_mlp_mfma_kernel(
    const float* __restrict__ u, const u16* __restrict__ w1t, const float* __restrict__ b1,
    const u16* __restrict__ w2t, const float* __restrict__ b2,
    u16* __restrict__ v, u16* __restrict__ uu, float* __restrict__ uskip)
{
    __shared__ __align__(16) u16 sA[16][264];
    __shared__ __align__(16) u16 sH[16][520];
    const int t = threadIdx.x;
    const int lane = t & 63, w = t >> 6;
    const int ln = lane & 15, q = lane >> 4;
    const int row0 = blockIdx.x * 16;

    for (int x = t; x < 1024; x += 256) {
        int r = x >> 6, c0 = (x & 63) * 4;
        float4 xx = *(const float4*)(u + (size_t)(row0 + r) * 256 + c0);
        sA[r][c0 + 0] = f2b(xx.x); sA[r][c0 + 1] = f2b(xx.y);
        sA[r][c0 + 2] = f2b(xx.z); sA[r][c0 + 3] = f2b(xx.w);
    }
    f32x4 c2[16];
    #pragma unroll
    for (int i = 0; i < 16; ++i) c2[i] = (f32x4){0.f, 0.f, 0.f, 0.f};

    for (int jj = 0; jj < 3; ++jj) {
        __syncthreads();
        f32x4 c1[8];
        #pragma unroll
        for (int i = 0; i < 8; ++i) c1[i] = (f32x4){0.f, 0.f, 0.f, 0.f};
        {
            const u16* w1p = w1t + (size_t)(jj * 512 + w * 128 + ln) * 256 + q * 8;
            #pragma unroll
            for (int k0 = 0; k0 < 256; k0 += 32) {
                bf16x8 a = *(const bf16x8*)&sA[ln][k0 + q * 8];
                #pragma unroll
                for (int nt = 0; nt < 8; ++nt) {
                    bf16x8 b = *(const bf16x8*)(w1p + (size_t)nt * 16 * 256 + k0);
                    c1[nt] = __builtin_amdgcn_mfma_f32_16x16x32_bf16(a, b, c1[nt], 0, 0, 0);
                }
            }
        }
        #pragma unroll
        for (int nt = 0; nt < 8; ++nt) {
            int col = w * 128 + nt * 16 + ln;
            float bias = b1[jj * 512 + col];
            #pragma unroll
            for (int r = 0; r < 4; ++r)
                sH[q * 4 + r][col] = f2b(gelu_tanh(c1[nt][r] + bias));
        }
        __syncthreads();
        const u16* w2p = w2t + (size_t)(w * 256 + ln) * 1536 + jj * 512 + q * 8;
        #pragma unroll 2
        for (int k0 = 0; k0 < 512; k0 += 32) {
            bf16x8 a = *(const bf16x8*)&sH[ln][k0 + q * 8];
            #pragma unroll
            for (int nt = 0; nt < 16; ++nt) {
                bf16x8 b = *(const bf16x8*)(w2p + (size_t)nt * 16 * 1536 + k0);
                c2[nt] = __builtin_amdgcn_mfma_f32_16x16x32_bf16(a, b, c2[nt], 0, 0, 0);
            }
        }
    }
    #pragma unroll
    for (int nt = 0; nt < 16; ++nt) {
        int col = w * 256 + nt * 16 + ln;
        float bias = b2[col];
        #pragma unroll
        for (int r = 0; r < 4; ++r) {
            int row = row0 + q * 4 + r;
            float val = c2[nt][r] + bias;
            if (col < 512)      v[(size_t)row * 512 + col] = f2b(val);
            else if (col < 768) uu[(size_t)row * 256 + (col - 512)] = f2b(val);
            else                uskip[(size_t)row * 256 + (col - 768)] = val;
        }
    }
}

// ---------------------------------------------------------------- K2: means of uu (4-way ILP chains)
__global__ void mean_over_lat_kernel(const u16* __restrict__ uu, float* __restrict__ Mlong) {
    int l = blockIdx.x, d = threadIdx.x;
    const u16* p = uu + (size_t)l * 256 + d;
    float s0 = 0.f, s1 = 0.f, s2 = 0.f, s3 = 0.f;
    for (int i = 0; i < 32; ++i) {
        s0 += b2f(p[(size_t)(i      ) * NLON * 256]);
        s1 += b2f(p[(size_t)(i +  32) * NLON * 256]);
        s2 += b2f(p[(size_t)(i +  64) * NLON * 256]);
        s3 += b2f(p[(size_t)(i +  96) * NLON * 256]);
    }
    Mlong[(size_t)l * 256 + d] = (s0 + s1 + s2 + s3) * (1.0f / NLAT);
}
__global__ void mean_over_lon_kernel(const u16* __restrict__ uu, float* __restrict__ Mlat) {
    int i = blockIdx.x, d = threadIdx.x;
    const u16* p = uu + (size_t)i * NLON * 256 + d;
    float s0 = 0.f, s1 = 0.f, s2 = 0.f, s3 = 0.f;
    for (int l = 0; l < 64; ++l) {
        s0 += b2f(p[(size_t)(l      ) * 256]);
        s1 += b2f(p[(size_t)(l +  64) * 256]);
        s2 += b2f(p[(size_t)(l + 128) * 256]);
        s3 += b2f(p[(size_t)(l + 192) * 256]);
    }
    Mlat[(size_t)i * 256 + d] = (s0 + s1 + s2 + s3) * (1.0f / NLON);
}

__device__ float block_sum256(float x, float* red) {
    #pragma unroll
    for (int o = 32; o > 0; o >>= 1) x += __shfl_down(x, o, 64);
    int wid = threadIdx.x >> 6, lane = threadIdx.x & 63;
    if (lane == 0) red[wid] = x;
    __syncthreads();
    float s = red[0] + red[1] + red[2] + red[3];
    __syncthreads();
    return s;
}

// ---------------------------------------------------------------- K3: pool MLP (split chains for ILP)
__global__ __launch_bounds__(256) void pool_mlp_kernel(
    const float* __restrict__ xin, const float* __restrict__ in_w,
    const float* __restrict__ ln_g, const float* __restrict__ ln_b,
    const float* __restrict__ fc1_w, const float* __restrict__ fc1_b,
    const float* __restrict__ fc2_w, const float* __restrict__ fc2_b,
    const float* __restrict__ lat, float* __restrict__ out)
{
    __shared__ float sx[256], sy[256], sg[256], red[4];
    int row = blockIdx.x, t = threadIdx.x;
    sx[t] = xin[(size_t)row * 256 + t];
    __syncthreads();
    float a0 = 0.f, a1 = 0.f;
    #pragma unroll 4
    for (int i = 0; i < 128; ++i) {
        a0 = fmaf(sx[i],       in_w[i * 256 + t],         a0);
        a1 = fmaf(sx[i + 128], in_w[(i + 128) * 256 + t], a1);
    }
    float acc = a0 + a1;
    if (lat) acc *= lat_weight(lat, row, NLAT);
    float m = block_sum256(acc, red) * (1.f / 256.f);
    float var = block_sum256(acc * acc, red) * (1.f / 256.f) - m * m;
    float xn = (acc - m) * rsqrtf(var + 1e-5f) * ln_g[t] + ln_b[t];
    sy[t] = xn;
    __syncthreads();
    float h1a = 0.f, h1b = 0.f, h2a = 0.f, h2b = 0.f;
    #pragma unroll 4
    for (int i = 0; i < 128; ++i) {
        float s0 = sy[i], s1 = sy[i + 128];
        h1a = fmaf(s0, fc1_w[i * 512 + t], h1a);
        h1b = fmaf(s1, fc1_w[(i + 128) * 512 + t], h1b);
        h2a = fmaf(s0, fc1_w[i * 512 + 256 + t], h2a);
        h2b = fmaf(s1, fc1_w[(i + 128) * 512 + 256 + t], h2b);
    }
    float h1 = fc1_b[t] + h1a + h1b;
    float h2 = fc1_b[t + 256] + h2a + h2b;
    float g = h1 * gelu_tanh(h2);
    sg[t] = g;
    __syncthreads();
    float o0 = 0.f, o1 = 0.f;
    #pragma unroll 4
    for (int i = 0; i < 128; ++i) {
        o0 = fmaf(sg[i],       fc2_w[i * 256 + t],         o0);
        o1 = fmaf(sg[i + 128], fc2_w[(i + 128) * 256 + t], o1);
    }
    out[(size_t)row * 256 + t] = fc2_b[t] + o0 + o1;
}

// ---------------------------------------------------------------- K4: bessel
__global__ void bessel_kernel(const float* __restrict__ coord, int n,
                              const float* __restrict__ freq, int nf,
                              const float* __restrict__ w, float* __restrict__ mod,
                              int periodic)
{
    int i = blockIdx.x, j = threadIdx.x;
    float d = fabsf(coord[j] - coord[i]);
    if (periodic) d = fminf(d, TWO_PI_F - d);
    float acc[8];
    #pragma unroll
    for (int h = 0; h < 8; ++h) acc[h] = 0.f;
    bool big = d > 1e-6f;
    float inv = big ? 1.f / d : 0.f;
    for (int k = 0; k < nf; ++k) {
        float f = freq[k];
        float basis = big ? sinf(f * d) * inv : f;
        #pragma unroll
        for (int h = 0; h < 8; ++h) acc[h] = fmaf(basis, w[k * 8 + h], acc[h]);
    }
    #pragma unroll
    for (int h = 0; h < 8; ++h) mod[((size_t)h * n + i) * n + j] = acc[h];
}

// ---------------------------------------------------------------- K5: all 4 projections in ONE launch
// z selects {long_q, long_k, lat_q, lat_k}; 8 rows/block -> 576 useful blocks total
// (vs 4 separate 96/48-block launches at 0.2-0.4 blocks/CU). Same fmaf order per
// element as proj_tile_kernel -> bit-identical outputs.
__global__ __launch_bounds__(256) void proj_tile4_kernel(
    const float* __restrict__ xlong, const float* __restrict__ xlat,
    const float* __restrict__ wlq, const float* __restrict__ wlk,
    const float* __restrict__ waq, const float* __restrict__ wak,
    float* __restrict__ clq, float* __restrict__ clk,
    float* __restrict__ caq, float* __restrict__ cak)
{
    const int z = blockIdx.z;
    const int nblk = (z < 2) ? 32 : 16;            // 256/8 or 128/8 row-blocks
    if ((int)blockIdx.x >= nblk) return;
    const float* x = (z < 2) ? xlong : xlat;
    const float* w = (z == 0) ? wlq : (z == 1) ? wlk : (z == 2) ? waq : wak;
    float* c       = (z == 0) ? clq : (z == 1) ? clk : (z == 2) ? caq : cak;
    const int t = threadIdx.x;
    const int j = blockIdx.y * 256 + t;
    const float* xp = x + (size_t)blockIdx.x * 8 * 256;
    const float* wp = w + j;
    float acc[8];
    #pragma unroll
    for (int r = 0; r < 8; ++r) acc[r] = 0.f;
    for (int i0 = 0; i0 < 256; i0 += 4) {
        float w0 = wp[(size_t)(i0 + 0) * 1536];
        float w1 = wp[(size_t)(i0 + 1) * 1536];
        float w2 = wp[(size_t)(i0 + 2) * 1536];
        float w3 = wp[(size_t)(i0 + 3) * 1536];
        #pragma unroll
        for (int r = 0; r < 8; ++r) {
            float4 xv = *(const float4*)(xp + r * 256 + i0);   // uniform -> s_load_dwordx4
            acc[r] = fmaf(xv.x, w0, acc[r]);
            acc[r] = fmaf(xv.y, w1, acc[r]);
            acc[r] = fmaf(xv.z, w2, acc[r]);
            acc[r] = fmaf(xv.w, w3, acc[r]);
        }
    }
    float* cp = c + (size_t)blockIdx.x * 8 * 1536 + j;
    #pragma unroll
    for (int r = 0; r < 8; ++r) cp[(size_t)r * 1536] = acc[r];
}

// ---------------------------------------------------------------- K6a: k_long -> KlongA[h][l][m] bf16 (K-major)
__global__ __launch_bounds__(256) void kmat_long_kernel(
    const float* __restrict__ q, const float* __restrict__ kp,
    const float* __restrict__ mod, u16* __restrict__ KA)
{
    int blk = blockIdx.x;              // h*256 + l   (grid 2048)
    int l = blk & 255, h = blk >> 8;
    __shared__ float sq[192];
    int t = threadIdx.x;
    if (t < 192) sq[t] = q[(size_t)l * 1536 + h * 192 + t];
    __syncthreads();
    const float* kpp = kp + (size_t)t * 1536 + h * 192;
    float acc = 0.f;
    #pragma unroll 4
    for (int c = 0; c < 192; ++c) acc = fmaf(kpp[c], sq[c], acc);
    float mv = mod[((size_t)h * 256 + l) * 256 + t];
    float val = leaky(acc * mv) * (TWO_PI_F / 256.f);
    KA[((size_t)h * 256 + l) * 256 + t] = f2b(val);
}

// ---------------------------------------------------------------- K6b: k_lat -> KlatA[h][i][j] bf16 (K-major)
__global__ __launch_bounds__(128) void kmat_lat_kernel(
    const float* __restrict__ q, const float* __restrict__ kp,
    const float* __restrict__ mod, const float* __restrict__ lat, u16* __restrict__ KA)
{
    int blk = blockIdx.x;              // h*128 + i   (grid 1024)
    int i = blk & 127, h = blk >> 7;
    __shared__ float sq[192];
    int t = threadIdx.x;
    for (int c = t; c < 192; c += 128) sq[c] = q[(size_t)i * 1536 + h * 192 + c];
    __syncthreads();
    const float* kpp = kp + (size_t)t * 1536 + h * 192;
    float acc = 0.f;
    #pragma unroll 4
    for (int c = 0; c < 192; ++c) acc = fmaf(kpp[c], sq[c], acc);
    float mv = mod[((size_t)h * 128 + i) * 128 + t];
    float wl = lat_weight(lat, t, NLAT);
    float val = leaky(acc * mv) * wl * (PI_F / 128.f);
    KA[((size_t)h * 128 + i) * 128 + t] = f2b(val);
}

// ---------------------------------------------------------------- K7: einsum1 MFMA (per batch)
__global__ __launch_bounds__(256) void einsum1_kernel(
    const u16* __restrict__ KlatA, const u16* __restrict__ v, u16* __restrict__ tmp1)
{
    int blk = blockIdx.x;              // h*256 + m (grid 2048)
    int m = blk & 255, h = blk >> 8;
    __shared__ __align__(16) u16 sV[64][136];   // [c][j], rows 272 B (16-aligned)
    const int t = threadIdx.x;
    const int lane = t & 63, w = t >> 6;
    const int ln = lane & 15, q = lane >> 4;

    {   // transpose-stage v slice [j=128][c=64] -> sV[c][j]
        int j = t >> 1, c0 = (t & 1) * 32;
        const u16* vp = v + ((size_t)j * 256 + m) * 512 + h * 64 + c0;
        union { uint4 q4[4]; u16 s[32]; } buf;
        buf.q4[0] = *(const uint4*)(vp);
        buf.q4[1] = *(const uint4*)(vp + 8);
        buf.q4[2] = *(const uint4*)(vp + 16);
        buf.q4[3] = *(const uint4*)(vp + 24);
        #pragma unroll
        for (int cc = 0; cc < 32; ++cc) sV[c0 + cc][j] = buf.s[cc];
    }
    __syncthreads();

    f32x4 acc[8];
    #pragma unroll
    for (int i = 0; i < 8; ++i) acc[i] = (f32x4){0.f, 0.f, 0.f, 0.f};
    const u16* ka = KlatA + (size_t)h * 128 * 128;
    for (int ch = 0; ch < 4; ++ch) {
        int j0 = ch * 32;
        bf16x8 b = *(const bf16x8*)&sV[w * 16 + ln][j0 + q * 8];
        #pragma unroll
        for (int it = 0; it < 8; ++it) {
            bf16x8 a = *(const bf16x8*)(ka + (size_t)(it * 16 + ln) * 128 + j0 + q * 8);
            acc[it] = __builtin_amdgcn_mfma_f32_16x16x32_bf16(a, b, acc[it], 0, 0, 0);
        }
    }
    int c = w * 16 + ln;
    #pragma unroll
    for (int it = 0; it < 8; ++it)
        #pragma unroll
        for (int r = 0; r < 4; ++r) {
            int i = it * 16 + q * 4 + r;
            tmp1[(((size_t)h * 128 + i) * 256 + m) * 64 + c] = f2b(acc[it][r]);
        }
}

// ---------------------------------------------------------------- K8: einsum2 MFMA + GN stats (per batch)
__global__ __launch_bounds__(256) void einsum2_kernel(
    const u16* __restrict__ tmp1, const u16* __restrict__ KlongA,
    u16* __restrict__ Aout, float* __restrict__ gnstat)
{
    int blk = blockIdx.x;              // h*128 + i (grid 1024)
    int i = blk & 127, h = blk >> 7;
    __shared__ __align__(16) u16 sT[64][264];   // [c][m], rows 528 B (16-aligned)
    __shared__ float red2[8];
    const int t = threadIdx.x;
    const int lane = t & 63, w = t >> 6;
    const int ln = lane & 15, q = lane >> 4;

    {   // transpose-stage tmp1 slice [m=256][c=64] -> sT[c][m]
        const u16* tp = tmp1 + (((size_t)h * 128 + i) * 256 + t) * 64;
        union { uint4 q4[8]; u16 s[64]; } buf;
        #pragma unroll
        for (int x = 0; x < 8; ++x) buf.q4[x] = *(const uint4*)(tp + x * 8);
        #pragma unroll
        for (int cc = 0; cc < 64; ++cc) sT[cc][t] = buf.s[cc];
    }
    __syncthreads();

    f32x4 acc[16];
    #pragma unroll
    for (int x = 0; x < 16; ++x) acc[x] = (f32x4){0.f, 0.f, 0.f, 0.f};
    const u16* ka = KlongA + (size_t)h * 256 * 256;
    for (int ch = 0; ch < 8; ++ch) {
        int m0 = ch * 32;
        bf16x8 bf[4];
        #pragma unroll
        for (int ct = 0; ct < 4; ++ct) bf[ct] = *(const bf16x8*)&sT[ct * 16 + ln][m0 + q * 8];
        #pragma unroll
        for (int lt = 0; lt < 4; ++lt) {
            bf16x8 a = *(const bf16x8*)(ka + (size_t)(w * 64 + lt * 16 + ln) * 256 + m0 + q * 8);
            #pragma unroll
            for (int ct = 0; ct < 4; ++ct)
                acc[lt * 4 + ct] = __builtin_amdgcn_mfma_f32_16x16x32_bf16(a, bf[ct], acc[lt * 4 + ct], 0, 0, 0);
        }
    }
    float lsum = 0.f, lsq = 0.f;
    #pragma unroll
    for (int lt = 0; lt < 4; ++lt)
        #pragma unroll
        for (int ct = 0; ct < 4; ++ct) {
            int c = ct * 16 + ln;
            #pragma unroll
            for (int r = 0; r < 4; ++r) {
                int l = w * 64 + lt * 16 + q * 4 + r;
                float val = acc[lt * 4 + ct][r];
                Aout[((size_t)i * 256 + l) * 512 + h * 64 + c] = f2b(val);
                lsum += val; lsq += val * val;
            }
        }
    #pragma unroll
    for (int o = 32; o > 0; o >>= 1) {
        lsum += __shfl_down(lsum, o, 64);
        lsq  += __shfl_down(lsq, o, 64);
    }
    if ((t & 63) == 0) { red2[w] = lsum; red2[4 + w] = lsq; }
    __syncthreads();
    if (t == 0) {
        atomicAdd(&gnstat[h * 2],     red2[0] + red2[1] + red2[2] + red2[3]);
        atomicAdd(&gnstat[h * 2 + 1], red2[4] + red2[5] + red2[6] + red2[7]);
    }
}

// ---------------------------------------------------------------- K9: fold GN into merge weights (per batch)
__global__ __launch_bounds__(256) void gn_fold_kernel(
    const float* __restrict__ gnstat, const float* __restrict__ gn_g, const float* __restrict__ gn_b,
    const float* __restrict__ mw, u16* __restrict__ Wp, float* __restrict__ bias2)
{
    __shared__ float red[4];
    int j = blockIdx.x, t = threadIdx.x;
    const float Ninv = 1.f / 2097152.f;   // 128*256*64
    float partial = 0.f;
    for (int k = t; k < 512; k += 256) {
        int h = k >> 6;
        float m = gnstat[h * 2] * Ninv;
        float var = gnstat[h * 2 + 1] * Ninv - m * m;
        float siv = rsqrtf(var + 1e-5f);
        float s = siv * gn_g[k];
        float tt = gn_b[k] - m * s;
        float wv = mw[(size_t)k * 256 + j];
        Wp[(size_t)j * 512 + k] = f2b(s * wv);
        partial += tt * wv;
    }
    float tot = block_sum256(partial, red);
    if (t == 0) bias2[j] = tot;
}

__global__ void zero_kernel(float* __restrict__ p, int n) {
    int i = blockIdx.x * blockDim.x + threadIdx.x;
    if (i < n) p[i] = 0.f;
}

// ================================================================ launch
extern "C" void kernel_launch(void* const* d_in, const int* in_sizes, int n_in,
                              void* d_out, int out_size, void* d_ws, size_t ws_size,
                              hipStream_t stream) {
    if (ws_size < 77856896ULL) return;   // known-good minimum from R3/R4
    const bool BIG = (ws_size >= 184549376ULL);  // de-fused cm path needs 96MB hidden

    const float* u        = (const float*)d_in[0];
    const float* lat      = (const float*)d_in[1];
    const float* lon      = (const float*)d_in[2];
    const float* cm_w1    = (const float*)d_in[3];
    const float* cm_b1    = (const float*)d_in[4];
    const float* cm_w2    = (const float*)d_in[5];
    const float* cm_b2    = (const float*)d_in[6];
    const float* long_in_w  = (const float*)d_in[7];
    const float* long_ln_g  = (const float*)d_in[8];
    const float* long_ln_b  = (const float*)d_in[9];
    const float* long_fc1_w = (const float*)d_in[10];
    const float* long_fc1_b = (const float*)d_in[11];
    const float* long_fc2_w = (const float*)d_in[12];
    const float* long_fc2_b = (const float*)d_in[13];
    const float* lat_in_w   = (const float*)d_in[14];
    const float* lat_ln_g   = (const float*)d_in[15];
    const float* lat_ln_b   = (const float*)d_in[16];
    const float* lat_fc1_w  = (const float*)d_in[17];
    const float* lat_fc1_b  = (const float*)d_in[18];
    const float* lat_fc2_w  = (const float*)d_in[19];
    const float* lat_fc2_b  = (const float*)d_in[20];
    const float* klong_q_w  = (const float*)d_in[21];
    const float* klong_k_w  = (const float*)d_in[22];
    const float* klat_q_w   = (const float*)d_in[23];
    const float* klat_k_w   = (const float*)d_in[24];
    const float* pe_long_freq = (const float*)d_in[25];
    const float* pe_long_w    = (const float*)d_in[26];
    const float* pe_lat_freq  = (const float*)d_in[27];
    const float* pe_lat_w     = (const float*)d_in[28];
    const float* gn_g    = (const float*)d_in[29];
    const float* gn_b    = (const float*)d_in[30];
    const float* merge_w = (const float*)d_in[31];
    const float* out_w   = (const float*)d_in[32];
    float* out = (float*)d_out;

    char* base = (char*)d_ws;
    u16*  vA   = (u16*)base;                          // v bf16 (32MB) -> Aout bf16 (32MB)
    char* reg1 = base + 33554432;                     // ubf bf16 (16MB) -> uu bf16 (16MB) -> tmp1 bf16 (32MB) -> Dbf bf16 (16MB)
    u16*  ubf  = (u16*)reg1;
    u16*  uu   = (u16*)reg1;
    u16*  tmp1 = (u16*)reg1;
    u16*  Dbf  = (u16*)reg1;
    // small pool (floats from base+64MB); end = 76,940,416 B < 77,856,896 guard
    float* pool    = (float*)(base + 67108864);
    float* modlong = pool;                            // 524288
    float* modlat  = modlong + 524288;                // 131072
    float* Mlong   = modlat + 131072;                 // 65536
    float* Mlat    = Mlong + 65536;                   // 32768
    float* ulong   = Mlat + 32768;                    // 65536
    float* ulat    = ulong + 65536;                   // 32768
    float* qlong   = ulat + 32768;                    // 393216
    float* klongp  = qlong + 393216;                  // 393216
    float* qlat    = klongp + 393216;                 // 196608
    float* klatp   = qlat + 196608;                   // 196608
    float* gnstat  = klatp + 196608;                  // 32
    float* bias2   = gnstat + 32;                     // 256
    u16* KlongA = (u16*)(bias2 + 256);                // 524288 elems (1MB)
    u16* KlatA  = KlongA + 524288;                    // 131072 elems
    u16* Wp     = KlatA + 131072;                     // 131072 elems
    u16* owT    = Wp + 131072;                        // 65536 elems
    // small-path weight aliases (dead at cm time, re-converted per batch)
    u16* w1T = (u16*)qlong;                           // 786,432 B in qlong (1.5MB)
    u16* w2T = (u16*)klongp;                          // 3,145,728 B in klongp+qlat+klatp
    // big-path dedicated regions
    u16* w1Tb   = (u16*)(base + 79691776);            // 786,432 B
    u16* w2Tb   = (u16*)(base + 80478208);            // 3,145,728 B
    u16* hidden = (u16*)(base + 83886080);            // 100,663,296 B (32768x1536 bf16)

    zero_kernel<<<1, 32, 0, stream>>>(gnstat, 32);
    bessel_kernel<<<256, 256, 0, stream>>>(lon, 256, pe_long_freq, 64, pe_long_w, modlong, 1);
    bessel_kernel<<<128, 128, 0, stream>>>(lat, 128, pe_lat_freq, 32, pe_lat_w, modlat, 0);
    // owT[256][256] <- out_w^T (coalesced)
    transpose_f32_bf16_kernel<<<dim3(8, 8), 256, 0, stream>>>(out_w, owT, 256, 256);
    if (BIG) {
        // w1Tb[1536][256] <- cm_w1^T; w2Tb[1024][1536] <- cm_w2^T (coalesced)
        transpose_f32_bf16_kernel<<<dim3(48, 8), 256, 0, stream>>>(cm_w1, w1Tb, 256, 1536);
        transpose_f32_bf16_kernel<<<dim3(32, 48), 256, 0, stream>>>(cm_w2, w2Tb, 1536, 1024);
    }

    for (int b = 0; b < 2; ++b) {
        const float* u_b  = u + (size_t)b * 32768 * 256;
        float* uskip_b    = out + (size_t)b * 8388608;
        float* gnstat_b   = gnstat + b * 16;

        if (BIG) {
            // u -> bf16 once (bit-identical to the old in-GEMM pack)
            conv_ubf_kernel<<<8192, 256, 0, stream>>>(u_b, ubf);
            // GEMM1: hidden = gelu(u@W1+b1)  [32768 x 1536], K=256, NCOL=12
            gemm128_kernel<256, 0, false, 12><<<3072, 256, 0, stream>>>(
                ubf, w1Tb, cm_b1, nullptr, hidden, nullptr, nullptr);
            // GEMM2: hidden@W2+b2 -> v|uu|uskip  [32768 x 1024], K=1536, NCOL=8
            gemm128_kernel<1536, 1, false, 8><<<2048, 256, 0, stream>>>(
                hidden, w2Tb, cm_b2, nullptr, vA, uu, uskip_b);
        } else {
            transpose_f32_bf16_kernel<<<dim3(48, 8), 256, 0, stream>>>(cm_w1, w1T, 256, 1536);
            transpose_f32_bf16_kernel<<<dim3(32, 48), 256, 0, stream>>>(cm_w2, w2T, 1536, 1024);
            cm_mlp_mfma_kernel<<<2048, 256, 0, stream>>>(u_b, w1T, cm_b1, w2T, cm_b2,
                                                         vA, uu, uskip_b);
        }
        mean_over_lat_kernel<<<256, 256, 0, stream>>>(uu, Mlong);
        mean_over_lon_kernel<<<128, 256, 0, stream>>>(uu, Mlat);
        pool_mlp_kernel<<<256, 256, 0, stream>>>(Mlong, long_in_w, long_ln_g, long_ln_b,
                                                 long_fc1_w, long_fc1_b, long_fc2_w, long_fc2_b,
                                                 nullptr, ulong);
        pool_mlp_kernel<<<128, 256, 0, stream>>>(Mlat, lat_in_w, lat_ln_g, lat_ln_b,
                                                 lat_fc1_w, lat_fc1_b, lat_fc2_w, lat_fc2_b,
                                                 lat, ulat);
        // all 4 projections in one launch (clobbers w1T/w2T regions — dead)
        proj_tile4_kernel<<<dim3(32, 6, 4), 256, 0, stream>>>(
            ulong, ulat, klong_q_w, klong_k_w, klat_q_w, klat_k_w,
            qlong, klongp, qlat, klatp);
        kmat_long_kernel<<<2048, 256, 0, stream>>>(qlong, klongp, modlong, KlongA);
        kmat_lat_kernel<<<1024, 128, 0, stream>>>(qlat, klatp, modlat, lat, KlatA);
        einsum1_kernel<<<2048, 256, 0, stream>>>(KlatA, vA, tmp1);       // tmp1 over uu (dead)
        einsum2_kernel<<<1024, 256, 0, stream>>>(tmp1, KlongA, vA, gnstat_b); // Aout over v (dead)
        gn_fold_kernel<<<256, 256, 0, stream>>>(gnstat_b, gn_g, gn_b, merge_w, Wp, bias2);
        // merge: Dbf = bf16(GN(Aout)@mw + uskip)   [32768 x 256], K=512, NCOL=2
        gemm128_kernel<512, 4, false, 2><<<512, 256, 0, stream>>>(
            vA, Wp, bias2, uskip_b, Dbf, nullptr, nullptr);
        // out: out = Dbf@ow                [32768 x 256], K=256, NCOL=2
        gemm128_kernel<256, 3, false, 2><<<512, 256, 0, stream>>>(
            Dbf, owT, nullptr, nullptr, out + (size_t)b * 8388608, nullptr, nullptr);
    }
}

// Round 9
// 1248.396 us; speedup vs baseline: 1.5712x; 1.0665x over previous
//
#include <hip/hip_runtime.h>
#include <math.h>
#include <stdint.h>

#define NLAT 128
#define NLON 256
#define PI_F 3.14159265358979323846f
#define TWO_PI_F 6.28318530717958647692f

typedef unsigned short u16;
typedef __attribute__((ext_vector_type(8))) short bf16x8;
typedef __attribute__((ext_vector_type(4))) float f32x4;

__device__ __forceinline__ u16 f2b(float f) {
    union { float f; uint32_t u; } v; v.f = f;
    uint32_t r = v.u + 0x7fffu + ((v.u >> 16) & 1u);
    return (u16)(r >> 16);
}
__device__ __forceinline__ float b2f(u16 u) {
    union { uint32_t u; float f; } v; v.u = ((uint32_t)u) << 16;
    return v.f;
}
__device__ __forceinline__ ushort4 pack4(float a, float b, float c, float d) {
    ushort4 r; r.x = f2b(a); r.y = f2b(b); r.z = f2b(c); r.w = f2b(d); return r;
}
// tanh-approx gelu with fast exp: tanh(z) = 1 - 2/(e^{2z}+1).
// |err| ~1e-6 vs tanhf — invisible under bf16 output rounding (quantum ~8e-3).
__device__ __forceinline__ float gelu_tanh(float x) {
    float z = 0.7978845608028654f * (x + 0.044715f * x * x * x);
    float e = __expf(2.0f * z);
    float th = 1.0f - 2.0f / (e + 1.0f);
    return 0.5f * x * (1.0f + th);
}
__device__ __forceinline__ float leaky(float x) { return x >= 0.0f ? x : 0.2f * x; }

__device__ __forceinline__ float lat_weight(const float* __restrict__ lat, int i, int n) {
    float w = cosf(lat[i]);
    if ((i == 0 || i == n - 1) && w < 0.001f) {
        float dlat = lat[1] - lat[0];
        float s = sinf(dlat * 0.25f);
        w = s * s / sinf(dlat * 0.5f);
    }
    return w;
}

// async global->LDS, 16B per lane; LDS dest is wave-uniform base + lane*16
__device__ __forceinline__ void gload16(const void* g, void* l) {
    __builtin_amdgcn_global_load_lds(
        (const __attribute__((address_space(1))) void*)(uintptr_t)g,
        (__attribute__((address_space(3))) void*)(uintptr_t)l,
        16, 0, 0);
}

// ================================================================ generic 128x128 MFMA GEMM
// A: [M][KD] (bf16 K-major, or fp32 if AF32). B: [N][KD] bf16 (n-major rows).
// BK=64, global_load_lds staging, both-sides XOR chunk swizzle (chunk ^= row&7).
// Grid: 1D nwg = (M/128)*NCOL, XCD-aware decode: bid%8 selects XCD (HW round-robin),
// each XCD owns a contiguous row band and iterates cols fastest -> A row-panel is
// fetched by exactly ONE XCD's L2 and reused across its NCOL col-blocks; B stays
// L2-resident. (R7 measured: GEMM2 FETCH 209->98.5 MB = optimal single pass.)
// EPI: 0 gelu->bf16 O0[row][1536]; 1 split v/uu/uskip; 2 +bias2+uskip -> fp32 O0[row][256];
//      3 plain fp32 O0[row][256]; 4 +bias2+uskip -> bf16 O0[row][256].
template<int KD, int EPI, bool AF32, int NCOL>
__global__ __launch_bounds__(256) void gemm128_kernel(
    const void* __restrict__ Aptr, const u16* __restrict__ B,
    const float* __restrict__ bias, const float* __restrict__ uskip,
    void* __restrict__ O0, void* __restrict__ O1, void* __restrict__ O2)
{
    __shared__ __align__(16) u16 sA[128][64];
    __shared__ __align__(16) u16 sB[128][64];
    const int t = threadIdx.x;
    const int lane = t & 63, w = t >> 6;
    const int ln = lane & 15, q = lane >> 4;
    const int wr = w >> 1, wc = w & 1;
    // XCD-aware bijective remap (nwg % 8 == 0 for all instantiations)
    const int bid = blockIdx.x;
    const int xcd = bid & 7, idx = bid >> 3;
    const int rowsPerXcd = ((int)gridDim.x >> 3) / NCOL;
    const int row0 = (xcd * rowsPerXcd + idx / NCOL) * 128;
    const int col0 = (idx % NCOL) * 128;
    // async staging geometry: wave w, issue s covers rows s*32 + w*8 + (lane>>3);
    // each lane loads the 16B chunk (lane&7) XOR-swizzled by row&7 (= (lane>>3))
    const int grow = w * 8 + (lane >> 3);
    const int gcol = ((lane & 7) ^ (lane >> 3)) * 8;
    const int sr = t >> 1, sh = t & 1;

    f32x4 acc[16];
    #pragma unroll
    for (int i = 0; i < 16; ++i) acc[i] = (f32x4){0.f, 0.f, 0.f, 0.f};

    for (int k0 = 0; k0 < KD; k0 += 64) {
        __syncthreads();
        if (AF32) {
            // reg-stage fp32 -> bf16 (can't async): thread t covers row sr, cols sh*32..+31
            const float* Ag = (const float*)Aptr + (size_t)(row0 + sr) * KD + k0 + sh * 32;
            #pragma unroll
            for (int j = 0; j < 8; ++j) {
                float4 f = *(const float4*)(Ag + j * 4);
                int cp = (((4 * sh + (j >> 1)) ^ (sr & 7)) * 8) + (j & 1) * 4;
                *(ushort4*)&sA[sr][cp] = pack4(f.x, f.y, f.z, f.w);
            }
        } else {
            const u16* Ag = (const u16*)Aptr + (size_t)(row0 + grow) * KD + k0 + gcol;
            #pragma unroll
            for (int s = 0; s < 4; ++s)
                gload16(Ag + (size_t)(s * 32) * KD, &sA[s * 32 + w * 8][0]);
        }
        {
            const u16* Bg = B + (size_t)(col0 + grow) * KD + k0 + gcol;
            #pragma unroll
            for (int s = 0; s < 4; ++s)
                gload16(Bg + (size_t)(s * 32) * KD, &sB[s * 32 + w * 8][0]);
        }
        __syncthreads();
        #pragma unroll
        for (int kk = 0; kk < 2; ++kk) {
            bf16x8 af[4], bfr[4];
            #pragma unroll
            for (int x = 0; x < 4; ++x) {
                int ra = wr * 64 + x * 16 + ln;
                af[x] = *(const bf16x8*)&sA[ra][((kk * 4 + q) ^ (ra & 7)) * 8];
            }
            #pragma unroll
            for (int x = 0; x < 4; ++x) {
                int rb = wc * 64 + x * 16 + ln;
                bfr[x] = *(const bf16x8*)&sB[rb][((kk * 4 + q) ^ (rb & 7)) * 8];
            }
            #pragma unroll
            for (int rt = 0; rt < 4; ++rt)
                #pragma unroll
                for (int ct = 0; ct < 4; ++ct)
                    acc[rt * 4 + ct] = __builtin_amdgcn_mfma_f32_16x16x32_bf16(af[rt], bfr[ct], acc[rt * 4 + ct], 0, 0, 0);
        }
    }

    #pragma unroll
    for (int rt = 0; rt < 4; ++rt)
        #pragma unroll
        for (int ct = 0; ct < 4; ++ct) {
            int col = col0 + wc * 64 + ct * 16 + ln;
            float bv = (EPI == 3) ? 0.f : bias[col];
            #pragma unroll
            for (int r = 0; r < 4; ++r) {
                int row = row0 + wr * 64 + rt * 16 + q * 4 + r;
                float x = acc[rt * 4 + ct][r] + bv;
                if (EPI == 0) {
                    ((u16*)O0)[(size_t)row * 1536 + col] = f2b(gelu_tanh(x));
                } else if (EPI == 1) {
                    if (col < 512)      ((u16*)O0)[(size_t)row * 512 + col] = f2b(x);
                    else if (col < 768) ((u16*)O1)[(size_t)row * 256 + col - 512] = f2b(x);
                    else                ((float*)O2)[(size_t)row * 256 + col - 768] = x;
                } else if (EPI == 2) {
                    ((float*)O0)[(size_t)row * 256 + col] = x + uskip[(size_t)row * 256 + col];
                } else if (EPI == 4) {
                    ((u16*)O0)[(size_t)row * 256 + col] = f2b(x + uskip[(size_t)row * 256 + col]);
                } else {
                    ((float*)O0)[(size_t)row * 256 + col] = x;
                }
            }
        }
}

// ---------------------------------------------------------------- coalesced fp32->bf16 transpose
// out[c][r] = f2b(in[r][c]); R,C multiples of 32. Grid (C/32, R/32), 256 threads.
__global__ __launch_bounds__(256) void transpose_f32_bf16_kernel(
    const float* __restrict__ in, u16* __restrict__ out, int R, int C)
{
    __shared__ float tile[32][33];
    const int tx = threadIdx.x & 31, ty = threadIdx.x >> 5;   // ty 0..7
    const int c0 = blockIdx.x * 32, r0 = blockIdx.y * 32;
    #pragma unroll
    for (int p = 0; p < 4; ++p)
        tile[ty + p * 8][tx] = in[(size_t)(r0 + ty + p * 8) * C + c0 + tx];
    __syncthreads();
    #pragma unroll
    for (int p = 0; p < 4; ++p)
        out[(size_t)(c0 + ty + p * 8) * R + r0 + tx] = f2b(tile[tx][ty + p * 8]);
}

// u fp32 -> bf16, same layout (bit-identical f2b rounding as the old in-GEMM pack)
__global__ void conv_ubf_kernel(const float* __restrict__ u, u16* __restrict__ ub) {
    size_t i = ((size_t)blockIdx.x * 256 + threadIdx.x) * 4;
    float4 f = *(const float4*)(u + i);
    *(ushort4*)(ub + i) = pack4(f.x, f.y, f.z, f.w);
}

// ---------------------------------------------------------------- K1 fallback: fused cm MLP (R4, verified)
__global__ __launch_bounds__(256, 2) void cm_mlp_mfma_kernel(
    const float* __restrict__ u, const u16* __restrict__ w1t, const float* __restrict__ b1,
    const u16* __restrict__ w2t, const float* __restrict__ b2,
    u16* __restrict__ v, u16* __restrict__ uu, float* __restrict__ uskip)
{
    __shared__ __align__(16) u16 sA[16][264];
    __shared__ __align__(16) u16 sH[16][520];
    const int t = threadIdx.x;
    const int lane = t & 63, w = t >> 6;
    const int ln = lane & 15, q = lane >> 4;
    const int row0 = blockIdx.x * 16;

    for (int x = t; x < 1024; x += 256) {
        int r = x >> 6, c0 = (x & 63) * 4;
        float4 xx = *(const float4*)(u + (size_t)(row0 + r) * 256 + c0);
        sA[r][c0 + 0] = f2b(xx.x); sA[r][c0 + 1] = f2b(xx.y);
        sA[r][c0 + 2] = f2b(xx.z); sA[r][c0 + 3] = f2b(xx.w);
    }
    f32x4 c2[16];
    #pragma unroll
    for (int i = 0; i < 16; ++i) c2[i] = (f32x4){0.f, 0.f, 0.f, 0.f};

    for (int jj = 0; jj < 3; ++jj) {
        __syncthreads();
        f32x4 c1[8];
        #pragma unroll
        for (int i = 0; i < 8; ++i) c1[i] = (f32x4){0.f, 0.f, 0.f, 0.f};
        {
            const u16* w1p = w1t + (size_t)(jj * 512 + w * 128 + ln) * 256 + q * 8;
            #pragma unroll
            for (int k0 = 0; k0 < 256; k0 += 32) {
                bf16x8 a = *(const bf16x8*)&sA[ln][k0 + q * 8];
                #pragma unroll
                for (int nt = 0; nt < 8; ++nt) {
                    bf16x8 b = *(const bf16x8*)(w1p + (size_t)nt * 16 * 256 + k0);
                    c1[nt] = __builtin_amdgcn_mfma_f32_16x16x32_bf16(a, b, c1[nt], 0, 0, 0);
                }
            }
        }
        #pragma unroll
        for (int nt = 0; nt < 8; ++nt) {
            int col = w * 128 + nt * 16 + ln;
            float bias = b1[jj * 512 + col];
            #pragma unroll
            for (int r = 0; r < 4; ++r)
                sH[q * 4 + r][col] = f2b(gelu_tanh(c1[nt][r] + bias));
        }
        __syncthreads();
        const u16* w2p = w2t + (size_t)(w * 256 + ln) * 1536 + jj * 512 + q * 8;
        #pragma unroll 2
        for (int k0 = 0; k0 < 512; k0 += 32) {
            bf16x8 a = *(const bf16x8*)&sH[ln][k0 + q * 8];
            #pragma unroll
            for (int nt = 0; nt < 16; ++nt) {
                bf16x8 b = *(const bf16x8*)(w2p + (size_t)nt * 16 * 1536 + k0);
                c2[nt] = __builtin_amdgcn_mfma_f32_16x16x32_bf16(a, b, c2[nt], 0, 0, 0);
            }
        }
    }
    #pragma unroll
    for (int nt = 0; nt < 16; ++nt) {
        int col = w * 256 + nt * 16 + ln;
        float bias = b2[col];
        #pragma unroll
        for (int r = 0; r < 4; ++r) {
            int row = row0 + q * 4 + r;
            float val = c2[nt][r] + bias;
            if (col < 512)      v[(size_t)row * 512 + col] = f2b(val);
            else if (col < 768) uu[(size_t)row * 256 + (col - 512)] = f2b(val);
            else                uskip[(size_t)row * 256 + (col - 768)] = val;
        }
    }
}

// ---------------------------------------------------------------- K2: both means, split 8-way, one launch
// bid<2048: Mlong partial (l=bid&255, i-range (bid>>8)*16..+15)
// bid>=2048: Mlat partial (i=blk&127, l-range (blk>>7)*32..+31)
// fp32 atomicAdd combine (Mlong/Mlat pre-zeroed). Reassociation only (~1e-6 rel).
__global__ void mean_fused_kernel(const u16* __restrict__ uu,
                                  float* __restrict__ Mlong, float* __restrict__ Mlat)
{
    int bid = blockIdx.x, d = threadIdx.x;
    if (bid < 2048) {
        int l = bid & 255, seg = bid >> 8;
        const u16* p = uu + ((size_t)(seg * 16) * NLON + l) * 256 + d;
        float s0 = 0.f, s1 = 0.f;
        for (int i = 0; i < 8; ++i) {
            s0 += b2f(p[(size_t)(2 * i    ) * NLON * 256]);
            s1 += b2f(p[(size_t)(2 * i + 1) * NLON * 256]);
        }
        atomicAdd(&Mlong[(size_t)l * 256 + d], (s0 + s1) * (1.0f / NLAT));
    } else {
        int blk = bid - 2048;
        int i = blk & 127, seg = blk >> 7;
        const u16* p = uu + ((size_t)i * NLON + seg * 32) * 256 + d;
        float s0 = 0.f, s1 = 0.f;
        for (int l = 0; l < 16; ++l) {
            s0 += b2f(p[(size_t)(2 * l    ) * 256]);
            s1 += b2f(p[(size_t)(2 * l + 1) * 256]);
        }
        atomicAdd(&Mlat[(size_t)i * 256 + d], (s0 + s1) * (1.0f / NLON));
    }
}

__device__ float block_sum256(float x, float* red) {
    #pragma unroll
    for (int o = 32; o > 0; o >>= 1) x += __shfl_down(x, o, 64);
    int wid = threadIdx.x >> 6, lane = threadIdx.x & 63;
    if (lane == 0) red[wid] = x;
    __syncthreads();
    float s = red[0] + red[1] + red[2] + red[3];
    __syncthreads();
    return s;
}

// ---------------------------------------------------------------- K3: both pool MLPs in one launch
// bid<256: long pool row=bid; bid>=256 (128 blocks): lat pool row=bid-256 (with lat weight).
__global__ __launch_bounds__(256) void pool_fused_kernel(
    const float* __restrict__ Mlong, const float* __restrict__ Mlat,
    const float* __restrict__ liw, const float* __restrict__ lg, const float* __restrict__ lb,
    const float* __restrict__ lf1w, const float* __restrict__ lf1b,
    const float* __restrict__ lf2w, const float* __restrict__ lf2b,
    const float* __restrict__ aiw, const float* __restrict__ ag, const float* __restrict__ ab,
    const float* __restrict__ af1w, const float* __restrict__ af1b,
    const float* __restrict__ af2w, const float* __restrict__ af2b,
    const float* __restrict__ lat, float* __restrict__ ulong, float* __restrict__ ulat)
{
    __shared__ float sx[256], sy[256], sg[256], red[4];
    const int bid = blockIdx.x, t = threadIdx.x;
    const bool islong = bid < 256;
    const int row = islong ? bid : bid - 256;
    const float* xin   = islong ? Mlong : Mlat;
    const float* in_w  = islong ? liw  : aiw;
    const float* ln_g  = islong ? lg   : ag;
    const float* ln_b  = islong ? lb   : ab;
    const float* fc1_w = islong ? lf1w : af1w;
    const float* fc1_b = islong ? lf1b : af1b;
    const float* fc2_w = islong ? lf2w : af2w;
    const float* fc2_b = islong ? lf2b : af2b;
    float* outp        = islong ? ulong : ulat;

    sx[t] = xin[(size_t)row * 256 + t];
    __syncthreads();
    float a0 = 0.f, a1 = 0.f;
    #pragma unroll 4
    for (int i = 0; i < 128; ++i) {
        a0 = fmaf(sx[i],       in_w[i * 256 + t],         a0);
        a1 = fmaf(sx[i + 128], in_w[(i + 128) * 256 + t], a1);
    }
    float acc = a0 + a1;
    if (!islong) acc *= lat_weight(lat, row, NLAT);
    float m = block_sum256(acc, red) * (1.f / 256.f);
    float var = block_sum256(acc * acc, red) * (1.f / 256.f) - m * m;
    float xn = (acc - m) * rsqrtf(var + 1e-5f) * ln_g[t] + ln_b[t];
    sy[t] = xn;
    __syncthreads();
    float h1a = 0.f, h1b = 0.f, h2a = 0.f, h2b = 0.f;
    #pragma unroll 4
    for (int i = 0; i < 128; ++i) {
        float s0 = sy[i], s1 = sy[i + 128];
        h1a = fmaf(s0, fc1_w[i * 512 + t], h1a);
        h1b = fmaf(s1, fc1_w[(i + 128) * 512 + t], h1b);
        h2a = fmaf(s0, fc1_w[i * 512 + 256 + t], h2a);
        h2b = fmaf(s1, fc1_w[(i + 128) * 512 + 256 + t], h2b);
    }
    float h1 = fc1_b[t] + h1a + h1b;
    float h2 = fc1_b[t + 256] + h2a + h2b;
    float g = h1 * gelu_tanh(h2);
    sg[t] = g;
    __syncthreads();
    float o0 = 0.f, o1 = 0.f;
    #pragma unroll 4
    for (int i = 0; i < 128; ++i) {
        o0 = fmaf(sg[i],       fc2_w[i * 256 + t],         o0);
        o1 = fmaf(sg[i + 128], fc2_w[(i + 128) * 256 + t], o1);
    }
    outp[(size_t)row * 256 + t] = fc2_b[t] + o0 + o1;
}

// ---------------------------------------------------------------- K4: bessel
__global__ void bessel_kernel(const float* __restrict__ coord, int n,
                              const float* __restrict__ freq, int nf,
                              const float* __restrict__ w, float* __restrict__ mod,
                              int periodic)
{
    int i = blockIdx.x, j = threadIdx.x;
    float d = fabsf(coord[j] - coord[i]);
    if (periodic) d = fminf(d, TWO_PI_F - d);
    float acc[8];
    #pragma unroll
    for (int h = 0; h < 8; ++h) acc[h] = 0.f;
    bool big = d > 1e-6f;
    float inv = big ? 1.f / d : 0.f;
    for (int k = 0; k < nf; ++k) {
        float f = freq[k];
        float basis = big ? sinf(f * d) * inv : f;
        #pragma unroll
        for (int h = 0; h < 8; ++h) acc[h] = fmaf(basis, w[k * 8 + h], acc[h]);
    }
    #pragma unroll
    for (int h = 0; h < 8; ++h) mod[((size_t)h * n + i) * n + j] = acc[h];
}

// ---------------------------------------------------------------- K5: all 4 projections in ONE launch
// z selects {long_q, long_k, lat_q, lat_k}; 8 rows/block. (R8: -271 us vs 4 launches.)
__global__ __launch_bounds__(256) void proj_tile4_kernel(
    const float* __restrict__ xlong, const float* __restrict__ xlat,
    const float* __restrict__ wlq, const float* __restrict__ wlk,
    const float* __restrict__ waq, const float* __restrict__ wak,
    float* __restrict__ clq, float* __restrict__ clk,
    float* __restrict__ caq, float* __restrict__ cak)
{
    const int z = blockIdx.z;
    const int nblk = (z < 2) ? 32 : 16;            // 256/8 or 128/8 row-blocks
    if ((int)blockIdx.x >= nblk) return;
    const float* x = (z < 2) ? xlong : xlat;
    const float* w = (z == 0) ? wlq : (z == 1) ? wlk : (z == 2) ? waq : wak;
    float* c       = (z == 0) ? clq : (z == 1) ? clk : (z == 2) ? caq : cak;
    const int t = threadIdx.x;
    const int j = blockIdx.y * 256 + t;
    const float* xp = x + (size_t)blockIdx.x * 8 * 256;
    const float* wp = w + j;
    float acc[8];
    #pragma unroll
    for (int r = 0; r < 8; ++r) acc[r] = 0.f;
    for (int i0 = 0; i0 < 256; i0 += 4) {
        float w0 = wp[(size_t)(i0 + 0) * 1536];
        float w1 = wp[(size_t)(i0 + 1) * 1536];
        float w2 = wp[(size_t)(i0 + 2) * 1536];
        float w3 = wp[(size_t)(i0 + 3) * 1536];
        #pragma unroll
        for (int r = 0; r < 8; ++r) {
            float4 xv = *(const float4*)(xp + r * 256 + i0);   // uniform -> s_load_dwordx4
            acc[r] = fmaf(xv.x, w0, acc[r]);
            acc[r] = fmaf(xv.y, w1, acc[r]);
            acc[r] = fmaf(xv.z, w2, acc[r]);
            acc[r] = fmaf(xv.w, w3, acc[r]);
        }
    }
    float* cp = c + (size_t)blockIdx.x * 8 * 1536 + j;
    #pragma unroll
    for (int r = 0; r < 8; ++r) cp[(size_t)r * 1536] = acc[r];
}

// ---------------------------------------------------------------- K6: both kmats in one launch
// bid<2048: k_long (l=bid&255, h=bid>>8), 256 active threads.
// bid>=2048 (1024 blocks): k_lat (i=blk&127, h=blk>>7), threads t<128 active.
__global__ __launch_bounds__(256) void kmat_fused_kernel(
    const float* __restrict__ qlong, const float* __restrict__ klongp,
    const float* __restrict__ modlong, u16* __restrict__ KlongA,
    const float* __restrict__ qlat, const float* __restrict__ klatp,
    const float* __restrict__ modlat, const float* __restrict__ lat,
    u16* __restrict__ KlatA)
{
    __shared__ float sq[192];
    const int bid = blockIdx.x, t = threadIdx.x;
    if (bid < 2048) {
        int l = bid & 255, h = bid >> 8;
        if (t < 192) sq[t] = qlong[(size_t)l * 1536 + h * 192 + t];
        __syncthreads();
        const float* kpp = klongp + (size_t)t * 1536 + h * 192;
        float acc = 0.f;
        #pragma unroll 4
        for (int c = 0; c < 192; ++c) acc = fmaf(kpp[c], sq[c], acc);
        float mv = modlong[((size_t)h * 256 + l) * 256 + t];
        float val = leaky(acc * mv) * (TWO_PI_F / 256.f);
        KlongA[((size_t)h * 256 + l) * 256 + t] = f2b(val);
    } else {
        int blk = bid - 2048;
        int i = blk & 127, h = blk >> 7;
        if (t < 192) sq[t] = qlat[(size_t)i * 1536 + h * 192 + t];
        __syncthreads();
        if (t < 128) {
            const float* kpp = klatp + (size_t)t * 1536 + h * 192;
            float acc = 0.f;
            #pragma unroll 4
            for (int c = 0; c < 192; ++c) acc = fmaf(kpp[c], sq[c], acc);
            float mv = modlat[((size_t)h * 128 + i) * 128 + t];
            float wl = lat_weight(lat, t, NLAT);
            float val = leaky(acc * mv) * wl * (PI_F / 128.f);
            KlatA[((size_t)h * 128 + i) * 128 + t] = f2b(val);
        }
    }
}

// ---------------------------------------------------------------- K7: einsum1 MFMA (per batch)
__global__ __launch_bounds__(256) void einsum1_kernel(
    const u16* __restrict__ KlatA, const u16* __restrict__ v, u16* __restrict__ tmp1)
{
    int blk = blockIdx.x;              // h*256 + m (grid 2048)
    int m = blk & 255, h = blk >> 8;
    __shared__ __align__(16) u16 sV[64][136];   // [c][j], rows 272 B (16-aligned)
    const int t = threadIdx.x;
    const int lane = t & 63, w = t >> 6;
    const int ln = lane & 15, q = lane >> 4;

    {   // transpose-stage v slice [j=128][c=64] -> sV[c][j]
        int j = t >> 1, c0 = (t & 1) * 32;
        const u16* vp = v + ((size_t)j * 256 + m) * 512 + h * 64 + c0;
        union { uint4 q4[4]; u16 s[32]; } buf;
        buf.q4[0] = *(const uint4*)(vp);
        buf.q4[1] = *(const uint4*)(vp + 8);
        buf.q4[2] = *(const uint4*)(vp + 16);
        buf.q4[3] = *(const uint4*)(vp + 24);
        #pragma unroll
        for (int cc = 0; cc < 32; ++cc) sV[c0 + cc][j] = buf.s[cc];
    }
    __syncthreads();

    f32x4 acc[8];
    #pragma unroll
    for (int i = 0; i < 8; ++i) acc[i] = (f32x4){0.f, 0.f, 0.f, 0.f};
    const u16* ka = KlatA + (size_t)h * 128 * 128;
    for (int ch = 0; ch < 4; ++ch) {
        int j0 = ch * 32;
        bf16x8 b = *(const bf16x8*)&sV[w * 16 + ln][j0 + q * 8];
        #pragma unroll
        for (int it = 0; it < 8; ++it) {
            bf16x8 a = *(const bf16x8*)(ka + (size_t)(it * 16 + ln) * 128 + j0 + q * 8);
            acc[it] = __builtin_amdgcn_mfma_f32_16x16x32_bf16(a, b, acc[it], 0, 0, 0);
        }
    }
    int c = w * 16 + ln;
    #pragma unroll
    for (int it = 0; it < 8; ++it)
        #pragma unroll
        for (int r = 0; r < 4; ++r) {
            int i = it * 16 + q * 4 + r;
            tmp1[(((size_t)h * 128 + i) * 256 + m) * 64 + c] = f2b(acc[it][r]);
        }
}

// ---------------------------------------------------------------- K8: einsum2 MFMA + GN stats (per batch)
__global__ __launch_bounds__(256) void einsum2_kernel(
    const u16* __restrict__ tmp1, const u16* __restrict__ KlongA,
    u16* __restrict__ Aout, float* __restrict__ gnstat)
{
    int blk = blockIdx.x;              // h*128 + i (grid 1024)
    int i = blk & 127, h = blk >> 7;
    __shared__ __align__(16) u16 sT[64][264];   // [c][m], rows 528 B (16-aligned)
    __shared__ float red2[8];
    const int t = threadIdx.x;
    const int lane = t & 63, w = t >> 6;
    const int ln = lane & 15, q = lane >> 4;

    {   // transpose-stage tmp1 slice [m=256][c=64] -> sT[c][m]
        const u16* tp = tmp1 + (((size_t)h * 128 + i) * 256 + t) * 64;
        union { uint4 q4[8]; u16 s[64]; } buf;
        #pragma unroll
        for (int x = 0; x < 8; ++x) buf.q4[x] = *(const uint4*)(tp + x * 8);
        #pragma unroll
        for (int cc = 0; cc < 64; ++cc) sT[cc][t] = buf.s[cc];
    }
    __syncthreads();

    f32x4 acc[16];
    #pragma unroll
    for (int x = 0; x < 16; ++x) acc[x] = (f32x4){0.f, 0.f, 0.f, 0.f};
    const u16* ka = KlongA + (size_t)h * 256 * 256;
    for (int ch = 0; ch < 8; ++ch) {
        int m0 = ch * 32;
        bf16x8 bf[4];
        #pragma unroll
        for (int ct = 0; ct < 4; ++ct) bf[ct] = *(const bf16x8*)&sT[ct * 16 + ln][m0 + q * 8];
        #pragma unroll
        for (int lt = 0; lt < 4; ++lt) {
            bf16x8 a = *(const bf16x8*)(ka + (size_t)(w * 64 + lt * 16 + ln) * 256 + m0 + q * 8);
            #pragma unroll
            for (int ct = 0; ct < 4; ++ct)
                acc[lt * 4 + ct] = __builtin_amdgcn_mfma_f32_16x16x32_bf16(a, bf[ct], acc[lt * 4 + ct], 0, 0, 0);
        }
    }
    float lsum = 0.f, lsq = 0.f;
    #pragma unroll
    for (int lt = 0; lt < 4; ++lt)
        #pragma unroll
        for (int ct = 0; ct < 4; ++ct) {
            int c = ct * 16 + ln;
            #pragma unroll
            for (int r = 0; r < 4; ++r) {
                int l = w * 64 + lt * 16 + q * 4 + r;
                float val = acc[lt * 4 + ct][r];
                Aout[((size_t)i * 256 + l) * 512 + h * 64 + c] = f2b(val);
                lsum += val; lsq += val * val;
            }
        }
    #pragma unroll
    for (int o = 32; o > 0; o >>= 1) {
        lsum += __shfl_down(lsum, o, 64);
        lsq  += __shfl_down(lsq, o, 64);
    }
    if ((t & 63) == 0) { red2[w] = lsum; red2[4 + w] = lsq; }
    __syncthreads();
    if (t == 0) {
        atomicAdd(&gnstat[h * 2],     red2[0] + red2[1] + red2[2] + red2[3]);
        atomicAdd(&gnstat[h * 2 + 1], red2[4] + red2[5] + red2[6] + red2[7]);
    }
}

// ---------------------------------------------------------------- K9: fold GN into merge weights (per batch)
__global__ __launch_bounds__(256) void gn_fold_kernel(
    const float* __restrict__ gnstat, const float* __restrict__ gn_g, const float* __restrict__ gn_b,
    const float* __restrict__ mw, u16* __restrict__ Wp, float* __restrict__ bias2)
{
    __shared__ float red[4];
    int j = blockIdx.x, t = threadIdx.x;
    const float Ninv = 1.f / 2097152.f;   // 128*256*64
    float partial = 0.f;
    for (int k = t; k < 512; k += 256) {
        int h = k >> 6;
        float m = gnstat[h * 2] * Ninv;
        float var = gnstat[h * 2 + 1] * Ninv - m * m;
        float siv = rsqrtf(var + 1e-5f);
        float s = siv * gn_g[k];
        float tt = gn_b[k] - m * s;
        float wv = mw[(size_t)k * 256 + j];
        Wp[(size_t)j * 512 + k] = f2b(s * wv);
        partial += tt * wv;
    }
    float tot = block_sum256(partial, red);
    if (t == 0) bias2[j] = tot;
}

__global__ void zero_kernel(float* __restrict__ p, int n) {
    int i = blockIdx.x * blockDim.x + threadIdx.x;
    if (i < n) p[i] = 0.f;
}

// ================================================================ launch
extern "C" void kernel_launch(void* const* d_in, const int* in_sizes, int n_in,
                              void* d_out, int out_size, void* d_ws, size_t ws_size,
                              hipStream_t stream) {
    if (ws_size < 77856896ULL) return;   // known-good minimum from R3/R4
    const bool BIG = (ws_size >= 184549376ULL);  // de-fused cm path needs 96MB hidden

    const float* u        = (const float*)d_in[0];
    const float* lat      = (const float*)d_in[1];
    const float* lon      = (const float*)d_in[2];
    const float* cm_w1    = (const float*)d_in[3];
    const float* cm_b1    = (const float*)d_in[4];
    const float* cm_w2    = (const float*)d_in[5];
    const float* cm_b2    = (const float*)d_in[6];
    const float* long_in_w  = (const float*)d_in[7];
    const float* long_ln_g  = (const float*)d_in[8];
    const float* long_ln_b  = (const float*)d_in[9];
    const float* long_fc1_w = (const float*)d_in[10];
    const float* long_fc1_b = (const float*)d_in[11];
    const float* long_fc2_w = (const float*)d_in[12];
    const float* long_fc2_b = (const float*)d_in[13];
    const float* lat_in_w   = (const float*)d_in[14];
    const float* lat_ln_g   = (const float*)d_in[15];
    const float* lat_ln_b   = (const float*)d_in[16];
    const float* lat_fc1_w  = (const float*)d_in[17];
    const float* lat_fc1_b  = (const float*)d_in[18];
    const float* lat_fc2_w  = (const float*)d_in[19];
    const float* lat_fc2_b  = (const float*)d_in[20];
    const float* klong_q_w  = (const float*)d_in[21];
    const float* klong_k_w  = (const float*)d_in[22];
    const float* klat_q_w   = (const float*)d_in[23];
    const float* klat_k_w   = (const float*)d_in[24];
    const float* pe_long_freq = (const float*)d_in[25];
    const float* pe_long_w    = (const float*)d_in[26];
    const float* pe_lat_freq  = (const float*)d_in[27];
    const float* pe_lat_w     = (const float*)d_in[28];
    const float* gn_g    = (const float*)d_in[29];
    const float* gn_b    = (const float*)d_in[30];
    const float* merge_w = (const float*)d_in[31];
    const float* out_w   = (const float*)d_in[32];
    float* out = (float*)d_out;

    char* base = (char*)d_ws;
    u16*  vA   = (u16*)base;                          // v bf16 (32MB) -> Aout bf16 (32MB)
    char* reg1 = base + 33554432;                     // ubf bf16 (16MB) -> uu bf16 (16MB) -> tmp1 bf16 (32MB) -> Dbf bf16 (16MB)
    u16*  ubf  = (u16*)reg1;
    u16*  uu   = (u16*)reg1;
    u16*  tmp1 = (u16*)reg1;
    u16*  Dbf  = (u16*)reg1;
    // small pool (floats from base+64MB); end = 76,940,416 B < 77,856,896 guard
    float* pool    = (float*)(base + 67108864);
    float* modlong = pool;                            // 524288
    float* modlat  = modlong + 524288;                // 131072
    float* Mlong   = modlat + 131072;                 // 65536
    float* Mlat    = Mlong + 65536;                   // 32768 (contiguous after Mlong)
    float* ulong   = Mlat + 32768;                    // 65536
    float* ulat    = ulong + 65536;                   // 32768
    float* qlong   = ulat + 32768;                    // 393216
    float* klongp  = qlong + 393216;                  // 393216
    float* qlat    = klongp + 393216;                 // 196608
    float* klatp   = qlat + 196608;                   // 196608
    float* gnstat  = klatp + 196608;                  // 32
    float* bias2   = gnstat + 32;                     // 256
    u16* KlongA = (u16*)(bias2 + 256);                // 524288 elems (1MB)
    u16* KlatA  = KlongA + 524288;                    // 131072 elems
    u16* Wp     = KlatA + 131072;                     // 131072 elems
    u16* owT    = Wp + 131072;                        // 65536 elems
    // small-path weight aliases (dead at cm time, re-converted per batch)
    u16* w1T = (u16*)qlong;                           // 786,432 B in qlong (1.5MB)
    u16* w2T = (u16*)klongp;                          // 3,145,728 B in klongp+qlat+klatp
    // big-path dedicated regions
    u16* w1Tb   = (u16*)(base + 79691776);            // 786,432 B
    u16* w2Tb   = (u16*)(base + 80478208);            // 3,145,728 B
    u16* hidden = (u16*)(base + 83886080);            // 100,663,296 B (32768x1536 bf16)

    zero_kernel<<<1, 32, 0, stream>>>(gnstat, 32);
    bessel_kernel<<<256, 256, 0, stream>>>(lon, 256, pe_long_freq, 64, pe_long_w, modlong, 1);
    bessel_kernel<<<128, 128, 0, stream>>>(lat, 128, pe_lat_freq, 32, pe_lat_w, modlat, 0);
    // owT[256][256] <- out_w^T (coalesced)
    transpose_f32_bf16_kernel<<<dim3(8, 8), 256, 0, stream>>>(out_w, owT, 256, 256);
    if (BIG) {
        // w1Tb[1536][256] <- cm_w1^T; w2Tb[1024][1536] <- cm_w2^T (coalesced)
        transpose_f32_bf16_kernel<<<dim3(48, 8), 256, 0, stream>>>(cm_w1, w1Tb, 256, 1536);
        transpose_f32_bf16_kernel<<<dim3(32, 48), 256, 0, stream>>>(cm_w2, w2Tb, 1536, 1024);
    }

    for (int b = 0; b < 2; ++b) {
        const float* u_b  = u + (size_t)b * 32768 * 256;
        float* uskip_b    = out + (size_t)b * 8388608;
        float* gnstat_b   = gnstat + b * 16;

        if (BIG) {
            // u -> bf16 once (bit-identical to the old in-GEMM pack)
            conv_ubf_kernel<<<8192, 256, 0, stream>>>(u_b, ubf);
            // GEMM1: hidden = gelu(u@W1+b1)  [32768 x 1536], K=256, NCOL=12
            gemm128_kernel<256, 0, false, 12><<<3072, 256, 0, stream>>>(
                ubf, w1Tb, cm_b1, nullptr, hidden, nullptr, nullptr);
            // GEMM2: hidden@W2+b2 -> v|uu|uskip  [32768 x 1024], K=1536, NCOL=8
            gemm128_kernel<1536, 1, false, 8><<<2048, 256, 0, stream>>>(
                hidden, w2Tb, cm_b2, nullptr, vA, uu, uskip_b);
        } else {
            transpose_f32_bf16_kernel<<<dim3(48, 8), 256, 0, stream>>>(cm_w1, w1T, 256, 1536);
            transpose_f32_bf16_kernel<<<dim3(32, 48), 256, 0, stream>>>(cm_w2, w2T, 1536, 1024);
            cm_mlp_mfma_kernel<<<2048, 256, 0, stream>>>(u_b, w1T, cm_b1, w2T, cm_b2,
                                                         vA, uu, uskip_b);
        }
        // zero Mlong+Mlat (contiguous 98304 floats), then split-fused means
        zero_kernel<<<384, 256, 0, stream>>>(Mlong, 98304);
        mean_fused_kernel<<<3072, 256, 0, stream>>>(uu, Mlong, Mlat);
        // both pool MLPs in one launch
        pool_fused_kernel<<<384, 256, 0, stream>>>(
            Mlong, Mlat,
            long_in_w, long_ln_g, long_ln_b, long_fc1_w, long_fc1_b, long_fc2_w, long_fc2_b,
            lat_in_w,  lat_ln_g,  lat_ln_b,  lat_fc1_w,  lat_fc1_b,  lat_fc2_w,  lat_fc2_b,
            lat, ulong, ulat);
        // all 4 projections in one launch (clobbers w1T/w2T regions — dead)
        proj_tile4_kernel<<<dim3(32, 6, 4), 256, 0, stream>>>(
            ulong, ulat, klong_q_w, klong_k_w, klat_q_w, klat_k_w,
            qlong, klongp, qlat, klatp);
        // both kmats in one launch
        kmat_fused_kernel<<<3072, 256, 0, stream>>>(
            qlong, klongp, modlong, KlongA,
            qlat, klatp, modlat, lat, KlatA);
        einsum1_kernel<<<2048, 256, 0, stream>>>(KlatA, vA, tmp1);       // tmp1 over uu (dead)
        einsum2_kernel<<<1024, 256, 0, stream>>>(tmp1, KlongA, vA, gnstat_b); // Aout over v (dead)
        gn_fold_kernel<<<256, 256, 0, stream>>>(gnstat_b, gn_g, gn_b, merge_w, Wp, bias2);
        // merge: Dbf = bf16(GN(Aout)@mw + uskip)   [32768 x 256], K=512, NCOL=2
        gemm128_kernel<512, 4, false, 2><<<512, 256, 0, stream>>>(
            vA, Wp, bias2, uskip_b, Dbf, nullptr, nullptr);
        // out: out = Dbf@ow                [32768 x 256], K=256, NCOL=2
        gemm128_kernel<256, 3, false, 2><<<512, 256, 0, stream>>>(
            Dbf, owT, nullptr, nullptr, out + (size_t)b * 8388608, nullptr, nullptr);
    }
}

// Round 10
// 1122.399 us; speedup vs baseline: 1.7476x; 1.1123x over previous
//
#include <hip/hip_runtime.h>
#include <math.h>
#include <stdint.h>

#define NLAT 128
#define NLON 256
#define PI_F 3.14159265358979323846f
#define TWO_PI_F 6.28318530717958647692f

typedef unsigned short u16;
typedef __attribute__((ext_vector_type(8))) short bf16x8;
typedef __attribute__((ext_vector_type(4))) float f32x4;

__device__ __forceinline__ u16 f2b(float f) {
    union { float f; uint32_t u; } v; v.f = f;
    uint32_t r = v.u + 0x7fffu + ((v.u >> 16) & 1u);
    return (u16)(r >> 16);
}
__device__ __forceinline__ float b2f(u16 u) {
    union { uint32_t u; float f; } v; v.u = ((uint32_t)u) << 16;
    return v.f;
}
__device__ __forceinline__ ushort4 pack4(float a, float b, float c, float d) {
    ushort4 r; r.x = f2b(a); r.y = f2b(b); r.z = f2b(c); r.w = f2b(d); return r;
}
// tanh-approx gelu with fast exp: tanh(z) = 1 - 2/(e^{2z}+1).
// |err| ~1e-6 vs tanhf — invisible under bf16 output rounding (quantum ~8e-3).
__device__ __forceinline__ float gelu_tanh(float x) {
    float z = 0.7978845608028654f * (x + 0.044715f * x * x * x);
    float e = __expf(2.0f * z);
    float th = 1.0f - 2.0f / (e + 1.0f);
    return 0.5f * x * (1.0f + th);
}
__device__ __forceinline__ float leaky(float x) { return x >= 0.0f ? x : 0.2f * x; }

__device__ __forceinline__ float lat_weight(const float* __restrict__ lat, int i, int n) {
    float w = cosf(lat[i]);
    if ((i == 0 || i == n - 1) && w < 0.001f) {
        float dlat = lat[1] - lat[0];
        float s = sinf(dlat * 0.25f);
        w = s * s / sinf(dlat * 0.5f);
    }
    return w;
}

// async global->LDS, 16B per lane; LDS dest is wave-uniform base + lane*16
__device__ __forceinline__ void gload16(const void* g, void* l) {
    __builtin_amdgcn_global_load_lds(
        (const __attribute__((address_space(1))) void*)(uintptr_t)g,
        (__attribute__((address_space(3))) void*)(uintptr_t)l,
        16, 0, 0);
}

// ================================================================ generic 128x128 MFMA GEMM
// A: [M][KD] (bf16 K-major, or fp32 if AF32). B: [N][KD] bf16 (n-major rows).
// BK=64, global_load_lds staging, both-sides XOR chunk swizzle (chunk ^= row&7).
// Grid: 1D nwg = (M/128)*NCOL, XCD-aware decode: bid%8 selects XCD (HW round-robin),
// each XCD owns a contiguous row band and iterates cols fastest -> A row-panel is
// fetched by exactly ONE XCD's L2 and reused across its NCOL col-blocks; B stays
// L2-resident. (R7 measured: GEMM2 FETCH 209->98.5 MB = optimal single pass.)
// EPI: 0 gelu->bf16 O0[row][1536]; 1 split v/uu/uskip; 2 +bias2+uskip -> fp32 O0[row][256];
//      3 plain fp32 O0[row][256]; 4 +bias2+uskip -> bf16 O0[row][256].
template<int KD, int EPI, bool AF32, int NCOL>
__global__ __launch_bounds__(256) void gemm128_kernel(
    const void* __restrict__ Aptr, const u16* __restrict__ B,
    const float* __restrict__ bias, const float* __restrict__ uskip,
    void* __restrict__ O0, void* __restrict__ O1, void* __restrict__ O2)
{
    __shared__ __align__(16) u16 sA[128][64];
    __shared__ __align__(16) u16 sB[128][64];
    const int t = threadIdx.x;
    const int lane = t & 63, w = t >> 6;
    const int ln = lane & 15, q = lane >> 4;
    const int wr = w >> 1, wc = w & 1;
    // XCD-aware bijective remap (nwg % 8 == 0 for all instantiations)
    const int bid = blockIdx.x;
    const int xcd = bid & 7, idx = bid >> 3;
    const int rowsPerXcd = ((int)gridDim.x >> 3) / NCOL;
    const int row0 = (xcd * rowsPerXcd + idx / NCOL) * 128;
    const int col0 = (idx % NCOL) * 128;
    // async staging geometry: wave w, issue s covers rows s*32 + w*8 + (lane>>3);
    // each lane loads the 16B chunk (lane&7) XOR-swizzled by row&7 (= (lane>>3))
    const int grow = w * 8 + (lane >> 3);
    const int gcol = ((lane & 7) ^ (lane >> 3)) * 8;
    const int sr = t >> 1, sh = t & 1;

    f32x4 acc[16];
    #pragma unroll
    for (int i = 0; i < 16; ++i) acc[i] = (f32x4){0.f, 0.f, 0.f, 0.f};

    for (int k0 = 0; k0 < KD; k0 += 64) {
        __syncthreads();
        if (AF32) {
            // reg-stage fp32 -> bf16 (can't async): thread t covers row sr, cols sh*32..+31
            const float* Ag = (const float*)Aptr + (size_t)(row0 + sr) * KD + k0 + sh * 32;
            #pragma unroll
            for (int j = 0; j < 8; ++j) {
                float4 f = *(const float4*)(Ag + j * 4);
                int cp = (((4 * sh + (j >> 1)) ^ (sr & 7)) * 8) + (j & 1) * 4;
                *(ushort4*)&sA[sr][cp] = pack4(f.x, f.y, f.z, f.w);
            }
        } else {
            const u16* Ag = (const u16*)Aptr + (size_t)(row0 + grow) * KD + k0 + gcol;
            #pragma unroll
            for (int s = 0; s < 4; ++s)
                gload16(Ag + (size_t)(s * 32) * KD, &sA[s * 32 + w * 8][0]);
        }
        {
            const u16* Bg = B + (size_t)(col0 + grow) * KD + k0 + gcol;
            #pragma unroll
            for (int s = 0; s < 4; ++s)
                gload16(Bg + (size_t)(s * 32) * KD, &sB[s * 32 + w * 8][0]);
        }
        __syncthreads();
        #pragma unroll
        for (int kk = 0; kk < 2; ++kk) {
            bf16x8 af[4], bfr[4];
            #pragma unroll
            for (int x = 0; x < 4; ++x) {
                int ra = wr * 64 + x * 16 + ln;
                af[x] = *(const bf16x8*)&sA[ra][((kk * 4 + q) ^ (ra & 7)) * 8];
            }
            #pragma unroll
            for (int x = 0; x < 4; ++x) {
                int rb = wc * 64 + x * 16 + ln;
                bfr[x] = *(const bf16x8*)&sB[rb][((kk * 4 + q) ^ (rb & 7)) * 8];
            }
            #pragma unroll
            for (int rt = 0; rt < 4; ++rt)
                #pragma unroll
                for (int ct = 0; ct < 4; ++ct)
                    acc[rt * 4 + ct] = __builtin_amdgcn_mfma_f32_16x16x32_bf16(af[rt], bfr[ct], acc[rt * 4 + ct], 0, 0, 0);
        }
    }

    #pragma unroll
    for (int rt = 0; rt < 4; ++rt)
        #pragma unroll
        for (int ct = 0; ct < 4; ++ct) {
            int col = col0 + wc * 64 + ct * 16 + ln;
            float bv = (EPI == 3) ? 0.f : bias[col];
            #pragma unroll
            for (int r = 0; r < 4; ++r) {
                int row = row0 + wr * 64 + rt * 16 + q * 4 + r;
                float x = acc[rt * 4 + ct][r] + bv;
                if (EPI == 0) {
                    ((u16*)O0)[(size_t)row * 1536 + col] = f2b(gelu_tanh(x));
                } else if (EPI == 1) {
                    if (col < 512)      ((u16*)O0)[(size_t)row * 512 + col] = f2b(x);
                    else if (col < 768) ((u16*)O1)[(size_t)row * 256 + col - 512] = f2b(x);
                    else                ((float*)O2)[(size_t)row * 256 + col - 768] = x;
                } else if (EPI == 2) {
                    ((float*)O0)[(size_t)row * 256 + col] = x + uskip[(size_t)row * 256 + col];
                } else if (EPI == 4) {
                    ((u16*)O0)[(size_t)row * 256 + col] = f2b(x + uskip[(size_t)row * 256 + col]);
                } else {
                    ((float*)O0)[(size_t)row * 256 + col] = x;
                }
            }
        }
}

// ---------------------------------------------------------------- coalesced fp32->bf16 transpose
// out[c][r] = f2b(in[r][c]); R,C multiples of 32. Grid (C/32, R/32), 256 threads.
__global__ __launch_bounds__(256) void transpose_f32_bf16_kernel(
    const float* __restrict__ in, u16* __restrict__ out, int R, int C)
{
    __shared__ float tile[32][33];
    const int tx = threadIdx.x & 31, ty = threadIdx.x >> 5;   // ty 0..7
    const int c0 = blockIdx.x * 32, r0 = blockIdx.y * 32;
    #pragma unroll
    for (int p = 0; p < 4; ++p)
        tile[ty + p * 8][tx] = in[(size_t)(r0 + ty + p * 8) * C + c0 + tx];
    __syncthreads();
    #pragma unroll
    for (int p = 0; p < 4; ++p)
        out[(size_t)(c0 + ty + p * 8) * R + r0 + tx] = f2b(tile[tx][ty + p * 8]);
}

// ---------------------------------------------------------------- fp32 transpose of both k-projections
// grid (48, 12): y<8 -> klongp [256x1536] -> klT [1536][256]; y>=8 -> klatp [128x1536] -> kaT [1536][128].
__global__ __launch_bounds__(256) void kpT_kernel(
    const float* __restrict__ kl, const float* __restrict__ ka,
    float* __restrict__ klT, float* __restrict__ kaT)
{
    __shared__ float tile[32][33];
    const bool isLong = blockIdx.y < 8;
    const float* in = isLong ? kl : ka;
    float* out      = isLong ? klT : kaT;
    const int R = isLong ? 256 : 128;
    const int r0 = (isLong ? blockIdx.y : blockIdx.y - 8) * 32;
    const int c0 = blockIdx.x * 32;
    const int tx = threadIdx.x & 31, ty = threadIdx.x >> 5;
    #pragma unroll
    for (int p = 0; p < 4; ++p)
        tile[ty + p * 8][tx] = in[(size_t)(r0 + ty + p * 8) * 1536 + c0 + tx];
    __syncthreads();
    #pragma unroll
    for (int p = 0; p < 4; ++p)
        out[(size_t)(c0 + ty + p * 8) * R + r0 + tx] = tile[tx][ty + p * 8];
}

// u fp32 -> bf16, same layout (bit-identical f2b rounding as the old in-GEMM pack)
__global__ void conv_ubf_kernel(const float* __restrict__ u, u16* __restrict__ ub) {
    size_t i = ((size_t)blockIdx.x * 256 + threadIdx.x) * 4;
    float4 f = *(const float4*)(u + i);
    *(ushort4*)(ub + i) = pack4(f.x, f.y, f.z, f.w);
}

// ---------------------------------------------------------------- K1 fallback: fused cm MLP (R4, verified)
__global__ __launch_bounds__(256, 2) void cm_mlp_mfma_kernel(
    const float* __restrict__ u, const u16* __restrict__ w1t, const float* __restrict__ b1,
    const u16* __restrict__ w2t, const float* __restrict__ b2,
    u16* __restrict__ v, u16* __restrict__ uu, float* __restrict__ uskip)
{
    __shared__ __align__(16) u16 sA[16][264];
    __shared__ __align__(16) u16 sH[16][520];
    const int t = threadIdx.x;
    const int lane = t & 63, w = t >> 6;
    const int ln = lane & 15, q = lane >> 4;
    const int row0 = blockIdx.x * 16;

    for (int x = t; x < 1024; x += 256) {
        int r = x >> 6, c0 = (x & 63) * 4;
        float4 xx = *(const float4*)(u + (size_t)(row0 + r) * 256 + c0);
        sA[r][c0 + 0] = f2b(xx.x); sA[r][c0 + 1] = f2b(xx.y);
        sA[r][c0 + 2] = f2b(xx.z); sA[r][c0 + 3] = f2b(xx.w);
    }
    f32x4 c2[16];
    #pragma unroll
    for (int i = 0; i < 16; ++i) c2[i] = (f32x4){0.f, 0.f, 0.f, 0.f};

    for (int jj = 0; jj < 3; ++jj) {
        __syncthreads();
        f32x4 c1[8];
        #pragma unroll
        for (int i = 0; i < 8; ++i) c1[i] = (f32x4){0.f, 0.f, 0.f, 0.f};
        {
            const u16* w1p = w1t + (size_t)(jj * 512 + w * 128 + ln) * 256 + q * 8;
            #pragma unroll
            for (int k0 = 0; k0 < 256; k0 += 32) {
                bf16x8 a = *(const bf16x8*)&sA[ln][k0 + q * 8];
                #pragma unroll
                for (int nt = 0; nt < 8; ++nt) {
                    bf16x8 b = *(const bf16x8*)(w1p + (size_t)nt * 16 * 256 + k0);
                    c1[nt] = __builtin_amdgcn_mfma_f32_16x16x32_bf16(a, b, c1[nt], 0, 0, 0);
                }
            }
        }
        #pragma unroll
        for (int nt = 0; nt < 8; ++nt) {
            int col = w * 128 + nt * 16 + ln;
            float bias = b1[jj * 512 + col];
            #pragma unroll
            for (int r = 0; r < 4; ++r)
                sH[q * 4 + r][col] = f2b(gelu_tanh(c1[nt][r] + bias));
        }
        __syncthreads();
        const u16* w2p = w2t + (size_t)(w * 256 + ln) * 1536 + jj * 512 + q * 8;
        #pragma unroll 2
        for (int k0 = 0; k0 < 512; k0 += 32) {
            bf16x8 a = *(const bf16x8*)&sH[ln][k0 + q * 8];
            #pragma unroll
            for (int nt = 0; nt < 16; ++nt) {
                bf16x8 b = *(const bf16x8*)(w2p + (size_t)nt * 16 * 1536 + k0);
                c2[nt] = __builtin_amdgcn_mfma_f32_16x16x32_bf16(a, b, c2[nt], 0, 0, 0);
            }
        }
    }
    #pragma unroll
    for (int nt = 0; nt < 16; ++nt) {
        int col = w * 256 + nt * 16 + ln;
        float bias = b2[col];
        #pragma unroll
        for (int r = 0; r < 4; ++r) {
            int row = row0 + q * 4 + r;
            float val = c2[nt][r] + bias;
            if (col < 512)      v[(size_t)row * 512 + col] = f2b(val);
            else if (col < 768) uu[(size_t)row * 256 + (col - 512)] = f2b(val);
            else                uskip[(size_t)row * 256 + (col - 768)] = val;
        }
    }
}

// ---------------------------------------------------------------- K2: both means, split 8-way, one launch
__global__ void mean_fused_kernel(const u16* __restrict__ uu,
                                  float* __restrict__ Mlong, float* __restrict__ Mlat)
{
    int bid = blockIdx.x, d = threadIdx.x;
    if (bid < 2048) {
        int l = bid & 255, seg = bid >> 8;
        const u16* p = uu + ((size_t)(seg * 16) * NLON + l) * 256 + d;
        float s0 = 0.f, s1 = 0.f;
        for (int i = 0; i < 8; ++i) {
            s0 += b2f(p[(size_t)(2 * i    ) * NLON * 256]);
            s1 += b2f(p[(size_t)(2 * i + 1) * NLON * 256]);
        }
        atomicAdd(&Mlong[(size_t)l * 256 + d], (s0 + s1) * (1.0f / NLAT));
    } else {
        int blk = bid - 2048;
        int i = blk & 127, seg = blk >> 7;
        const u16* p = uu + ((size_t)i * NLON + seg * 32) * 256 + d;
        float s0 = 0.f, s1 = 0.f;
        for (int l = 0; l < 16; ++l) {
            s0 += b2f(p[(size_t)(2 * l    ) * 256]);
            s1 += b2f(p[(size_t)(2 * l + 1) * 256]);
        }
        atomicAdd(&Mlat[(size_t)i * 256 + d], (s0 + s1) * (1.0f / NLON));
    }
}

__device__ float block_sum256(float x, float* red) {
    #pragma unroll
    for (int o = 32; o > 0; o >>= 1) x += __shfl_down(x, o, 64);
    int wid = threadIdx.x >> 6, lane = threadIdx.x & 63;
    if (lane == 0) red[wid] = x;
    __syncthreads();
    float s = red[0] + red[1] + red[2] + red[3];
    __syncthreads();
    return s;
}

// ---------------------------------------------------------------- K3: both pool MLPs in one launch
__global__ __launch_bounds__(256) void pool_fused_kernel(
    const float* __restrict__ Mlong, const float* __restrict__ Mlat,
    const float* __restrict__ liw, const float* __restrict__ lg, const float* __restrict__ lb,
    const float* __restrict__ lf1w, const float* __restrict__ lf1b,
    const float* __restrict__ lf2w, const float* __restrict__ lf2b,
    const float* __restrict__ aiw, const float* __restrict__ ag, const float* __restrict__ ab,
    const float* __restrict__ af1w, const float* __restrict__ af1b,
    const float* __restrict__ af2w, const float* __restrict__ af2b,
    const float* __restrict__ lat, float* __restrict__ ulong, float* __restrict__ ulat)
{
    __shared__ float sx[256], sy[256], sg[256], red[4];
    const int bid = blockIdx.x, t = threadIdx.x;
    const bool islong = bid < 256;
    const int row = islong ? bid : bid - 256;
    const float* xin   = islong ? Mlong : Mlat;
    const float* in_w  = islong ? liw  : aiw;
    const float* ln_g  = islong ? lg   : ag;
    const float* ln_b  = islong ? lb   : ab;
    const float* fc1_w = islong ? lf1w : af1w;
    const float* fc1_b = islong ? lf1b : af1b;
    const float* fc2_w = islong ? lf2w : af2w;
    const float* fc2_b = islong ? lf2b : af2b;
    float* outp        = islong ? ulong : ulat;

    sx[t] = xin[(size_t)row * 256 + t];
    __syncthreads();
    float a0 = 0.f, a1 = 0.f;
    #pragma unroll 4
    for (int i = 0; i < 128; ++i) {
        a0 = fmaf(sx[i],       in_w[i * 256 + t],         a0);
        a1 = fmaf(sx[i + 128], in_w[(i + 128) * 256 + t], a1);
    }
    float acc = a0 + a1;
    if (!islong) acc *= lat_weight(lat, row, NLAT);
    float m = block_sum256(acc, red) * (1.f / 256.f);
    float var = block_sum256(acc * acc, red) * (1.f / 256.f) - m * m;
    float xn = (acc - m) * rsqrtf(var + 1e-5f) * ln_g[t] + ln_b[t];
    sy[t] = xn;
    __syncthreads();
    float h1a = 0.f, h1b = 0.f, h2a = 0.f, h2b = 0.f;
    #pragma unroll 4
    for (int i = 0; i < 128; ++i) {
        float s0 = sy[i], s1 = sy[i + 128];
        h1a = fmaf(s0, fc1_w[i * 512 + t], h1a);
        h1b = fmaf(s1, fc1_w[(i + 128) * 512 + t], h1b);
        h2a = fmaf(s0, fc1_w[i * 512 + 256 + t], h2a);
        h2b = fmaf(s1, fc1_w[(i + 128) * 512 + 256 + t], h2b);
    }
    float h1 = fc1_b[t] + h1a + h1b;
    float h2 = fc1_b[t + 256] + h2a + h2b;
    float g = h1 * gelu_tanh(h2);
    sg[t] = g;
    __syncthreads();
    float o0 = 0.f, o1 = 0.f;
    #pragma unroll 4
    for (int i = 0; i < 128; ++i) {
        o0 = fmaf(sg[i],       fc2_w[i * 256 + t],         o0);
        o1 = fmaf(sg[i + 128], fc2_w[(i + 128) * 256 + t], o1);
    }
    outp[(size_t)row * 256 + t] = fc2_b[t] + o0 + o1;
}

// ---------------------------------------------------------------- K4: bessel
__global__ void bessel_kernel(const float* __restrict__ coord, int n,
                              const float* __restrict__ freq, int nf,
                              const float* __restrict__ w, float* __restrict__ mod,
                              int periodic)
{
    int i = blockIdx.x, j = threadIdx.x;
    float d = fabsf(coord[j] - coord[i]);
    if (periodic) d = fminf(d, TWO_PI_F - d);
    float acc[8];
    #pragma unroll
    for (int h = 0; h < 8; ++h) acc[h] = 0.f;
    bool big = d > 1e-6f;
    float inv = big ? 1.f / d : 0.f;
    for (int k = 0; k < nf; ++k) {
        float f = freq[k];
        float basis = big ? sinf(f * d) * inv : f;
        #pragma unroll
        for (int h = 0; h < 8; ++h) acc[h] = fmaf(basis, w[k * 8 + h], acc[h]);
    }
    #pragma unroll
    for (int h = 0; h < 8; ++h) mod[((size_t)h * n + i) * n + j] = acc[h];
}

// ---------------------------------------------------------------- K5: all 4 projections in ONE launch
__global__ __launch_bounds__(256) void proj_tile4_kernel(
    const float* __restrict__ xlong, const float* __restrict__ xlat,
    const float* __restrict__ wlq, const float* __restrict__ wlk,
    const float* __restrict__ waq, const float* __restrict__ wak,
    float* __restrict__ clq, float* __restrict__ clk,
    float* __restrict__ caq, float* __restrict__ cak)
{
    const int z = blockIdx.z;
    const int nblk = (z < 2) ? 32 : 16;            // 256/8 or 128/8 row-blocks
    if ((int)blockIdx.x >= nblk) return;
    const float* x = (z < 2) ? xlong : xlat;
    const float* w = (z == 0) ? wlq : (z == 1) ? wlk : (z == 2) ? waq : wak;
    float* c       = (z == 0) ? clq : (z == 1) ? clk : (z == 2) ? caq : cak;
    const int t = threadIdx.x;
    const int j = blockIdx.y * 256 + t;
    const float* xp = x + (size_t)blockIdx.x * 8 * 256;
    const float* wp = w + j;
    float acc[8];
    #pragma unroll
    for (int r = 0; r < 8; ++r) acc[r] = 0.f;
    for (int i0 = 0; i0 < 256; i0 += 4) {
        float w0 = wp[(size_t)(i0 + 0) * 1536];
        float w1 = wp[(size_t)(i0 + 1) * 1536];
        float w2 = wp[(size_t)(i0 + 2) * 1536];
        float w3 = wp[(size_t)(i0 + 3) * 1536];
        #pragma unroll
        for (int r = 0; r < 8; ++r) {
            float4 xv = *(const float4*)(xp + r * 256 + i0);   // uniform -> s_load_dwordx4
            acc[r] = fmaf(xv.x, w0, acc[r]);
            acc[r] = fmaf(xv.y, w1, acc[r]);
            acc[r] = fmaf(xv.z, w2, acc[r]);
            acc[r] = fmaf(xv.w, w3, acc[r]);
        }
    }
    float* cp = c + (size_t)blockIdx.x * 8 * 1536 + j;
    #pragma unroll
    for (int r = 0; r < 8; ++r) cp[(size_t)r * 1536] = acc[r];
}

// ---------------------------------------------------------------- K6 (BIG): kmats with TRANSPOSED kp (coalesced)
// klT [1536][256], kaT [1536][128]. Lane t reads kpT[(h*192+c)*W + t] — lane-contiguous.
// Same fmaf order/values as the row-major version -> bit-identical output.
__global__ __launch_bounds__(256) void kmat_fusedT_kernel(
    const float* __restrict__ qlong, const float* __restrict__ klT,
    const float* __restrict__ modlong, u16* __restrict__ KlongA,
    const float* __restrict__ qlat, const float* __restrict__ kaT,
    const float* __restrict__ modlat, const float* __restrict__ lat,
    u16* __restrict__ KlatA)
{
    __shared__ float sq[192];
    const int bid = blockIdx.x, t = threadIdx.x;
    if (bid < 2048) {
        int l = bid & 255, h = bid >> 8;
        if (t < 192) sq[t] = qlong[(size_t)l * 1536 + h * 192 + t];
        __syncthreads();
        const float* kp = klT + (size_t)(h * 192) * 256 + t;
        float acc = 0.f;
        #pragma unroll 4
        for (int c = 0; c < 192; ++c) acc = fmaf(kp[(size_t)c * 256], sq[c], acc);
        float mv = modlong[((size_t)h * 256 + l) * 256 + t];
        float val = leaky(acc * mv) * (TWO_PI_F / 256.f);
        KlongA[((size_t)h * 256 + l) * 256 + t] = f2b(val);
    } else {
        int blk = bid - 2048;
        int i = blk & 127, h = blk >> 7;
        if (t < 192) sq[t] = qlat[(size_t)i * 1536 + h * 192 + t];
        __syncthreads();
        if (t < 128) {
            const float* kp = kaT + (size_t)(h * 192) * 128 + t;
            float acc = 0.f;
            #pragma unroll 4
            for (int c = 0; c < 192; ++c) acc = fmaf(kp[(size_t)c * 128], sq[c], acc);
            float mv = modlat[((size_t)h * 128 + i) * 128 + t];
            float wl = lat_weight(lat, t, NLAT);
            float val = leaky(acc * mv) * wl * (PI_F / 128.f);
            KlatA[((size_t)h * 128 + i) * 128 + t] = f2b(val);
        }
    }
}

// ---------------------------------------------------------------- K6 (small-path fallback): row-major kmats
__global__ __launch_bounds__(256) void kmat_fused_kernel(
    const float* __restrict__ qlong, const float* __restrict__ klongp,
    const float* __restrict__ modlong, u16* __restrict__ KlongA,
    const float* __restrict__ qlat, const float* __restrict__ klatp,
    const float* __restrict__ modlat, const float* __restrict__ lat,
    u16* __restrict__ KlatA)
{
    __shared__ float sq[192];
    const int bid = blockIdx.x, t = threadIdx.x;
    if (bid < 2048) {
        int l = bid & 255, h = bid >> 8;
        if (t < 192) sq[t] = qlong[(size_t)l * 1536 + h * 192 + t];
        __syncthreads();
        const float* kpp = klongp + (size_t)t * 1536 + h * 192;
        float acc = 0.f;
        #pragma unroll 4
        for (int c = 0; c < 192; ++c) acc = fmaf(kpp[c], sq[c], acc);
        float mv = modlong[((size_t)h * 256 + l) * 256 + t];
        float val = leaky(acc * mv) * (TWO_PI_F / 256.f);
        KlongA[((size_t)h * 256 + l) * 256 + t] = f2b(val);
    } else {
        int blk = bid - 2048;
        int i = blk & 127, h = blk >> 7;
        if (t < 192) sq[t] = qlat[(size_t)i * 1536 + h * 192 + t];
        __syncthreads();
        if (t < 128) {
            const float* kpp = klatp + (size_t)t * 1536 + h * 192;
            float acc = 0.f;
            #pragma unroll 4
            for (int c = 0; c < 192; ++c) acc = fmaf(kpp[c], sq[c], acc);
            float mv = modlat[((size_t)h * 128 + i) * 128 + t];
            float wl = lat_weight(lat, t, NLAT);
            float val = leaky(acc * mv) * wl * (PI_F / 128.f);
            KlatA[((size_t)h * 128 + i) * 128 + t] = f2b(val);
        }
    }
}

// ---------------------------------------------------------------- K7: einsum1 MFMA (per batch)
__global__ __launch_bounds__(256) void einsum1_kernel(
    const u16* __restrict__ KlatA, const u16* __restrict__ v, u16* __restrict__ tmp1)
{
    int blk = blockIdx.x;              // h*256 + m (grid 2048)
    int m = blk & 255, h = blk >> 8;
    __shared__ __align__(16) u16 sV[64][136];   // [c][j], rows 272 B (16-aligned)
    const int t = threadIdx.x;
    const int lane = t & 63, w = t >> 6;
    const int ln = lane & 15, q = lane >> 4;

    {   // transpose-stage v slice [j=128][c=64] -> sV[c][j]
        int j = t >> 1, c0 = (t & 1) * 32;
        const u16* vp = v + ((size_t)j * 256 + m) * 512 + h * 64 + c0;
        union { uint4 q4[4]; u16 s[32]; } buf;
        buf.q4[0] = *(const uint4*)(vp);
        buf.q4[1] = *(const uint4*)(vp + 8);
        buf.q4[2] = *(const uint4*)(vp + 16);
        buf.q4[3] = *(const uint4*)(vp + 24);
        #pragma unroll
        for (int cc = 0; cc < 32; ++cc) sV[c0 + cc][j] = buf.s[cc];
    }
    __syncthreads();

    f32x4 acc[8];
    #pragma unroll
    for (int i = 0; i < 8; ++i) acc[i] = (f32x4){0.f, 0.f, 0.f, 0.f};
    const u16* ka = KlatA + (size_t)h * 128 * 128;
    for (int ch = 0; ch < 4; ++ch) {
        int j0 = ch * 32;
        bf16x8 b = *(const bf16x8*)&sV[w * 16 + ln][j0 + q * 8];
        #pragma unroll
        for (int it = 0; it < 8; ++it) {
            bf16x8 a = *(const bf16x8*)(ka + (size_t)(it * 16 + ln) * 128 + j0 + q * 8);
            acc[it] = __builtin_amdgcn_mfma_f32_16x16x32_bf16(a, b, acc[it], 0, 0, 0);
        }
    }
    int c = w * 16 + ln;
    #pragma unroll
    for (int it = 0; it < 8; ++it)
        #pragma unroll
        for (int r = 0; r < 4; ++r) {
            int i = it * 16 + q * 4 + r;
            tmp1[(((size_t)h * 128 + i) * 256 + m) * 64 + c] = f2b(acc[it][r]);
        }
}

// ---------------------------------------------------------------- K8: einsum2 MFMA + GN stats (per batch)
__global__ __launch_bounds__(256) void einsum2_kernel(
    const u16* __restrict__ tmp1, const u16* __restrict__ KlongA,
    u16* __restrict__ Aout, float* __restrict__ gnstat)
{
    int blk = blockIdx.x;              // h*128 + i (grid 1024)
    int i = blk & 127, h = blk >> 7;
    __shared__ __align__(16) u16 sT[64][264];   // [c][m], rows 528 B (16-aligned)
    __shared__ float red2[8];
    const int t = threadIdx.x;
    const int lane = t & 63, w = t >> 6;
    const int ln = lane & 15, q = lane >> 4;

    {   // transpose-stage tmp1 slice [m=256][c=64] -> sT[c][m]
        const u16* tp = tmp1 + (((size_t)h * 128 + i) * 256 + t) * 64;
        union { uint4 q4[8]; u16 s[64]; } buf;
        #pragma unroll
        for (int x = 0; x < 8; ++x) buf.q4[x] = *(const uint4*)(tp + x * 8);
        #pragma unroll
        for (int cc = 0; cc < 64; ++cc) sT[cc][t] = buf.s[cc];
    }
    __syncthreads();

    f32x4 acc[16];
    #pragma unroll
    for (int x = 0; x < 16; ++x) acc[x] = (f32x4){0.f, 0.f, 0.f, 0.f};
    const u16* ka = KlongA + (size_t)h * 256 * 256;
    for (int ch = 0; ch < 8; ++ch) {
        int m0 = ch * 32;
        bf16x8 bf[4];
        #pragma unroll
        for (int ct = 0; ct < 4; ++ct) bf[ct] = *(const bf16x8*)&sT[ct * 16 + ln][m0 + q * 8];
        #pragma unroll
        for (int lt = 0; lt < 4; ++lt) {
            bf16x8 a = *(const bf16x8*)(ka + (size_t)(w * 64 + lt * 16 + ln) * 256 + m0 + q * 8);
            #pragma unroll
            for (int ct = 0; ct < 4; ++ct)
                acc[lt * 4 + ct] = __builtin_amdgcn_mfma_f32_16x16x32_bf16(a, bf[ct], acc[lt * 4 + ct], 0, 0, 0);
        }
    }
    float lsum = 0.f, lsq = 0.f;
    #pragma unroll
    for (int lt = 0; lt < 4; ++lt)
        #pragma unroll
        for (int ct = 0; ct < 4; ++ct) {
            int c = ct * 16 + ln;
            #pragma unroll
            for (int r = 0; r < 4; ++r) {
                int l = w * 64 + lt * 16 + q * 4 + r;
                float val = acc[lt * 4 + ct][r];
                Aout[((size_t)i * 256 + l) * 512 + h * 64 + c] = f2b(val);
                lsum += val; lsq += val * val;
            }
        }
    #pragma unroll
    for (int o = 32; o > 0; o >>= 1) {
        lsum += __shfl_down(lsum, o, 64);
        lsq  += __shfl_down(lsq, o, 64);
    }
    if ((t & 63) == 0) { red2[w] = lsum; red2[4 + w] = lsq; }
    __syncthreads();
    if (t == 0) {
        atomicAdd(&gnstat[h * 2],     red2[0] + red2[1] + red2[2] + red2[3]);
        atomicAdd(&gnstat[h * 2 + 1], red2[4] + red2[5] + red2[6] + red2[7]);
    }
}

// ---------------------------------------------------------------- K9: fold GN into merge weights (per batch)
__global__ __launch_bounds__(256) void gn_fold_kernel(
    const float* __restrict__ gnstat, const float* __restrict__ gn_g, const float* __restrict__ gn_b,
    const float* __restrict__ mw, u16* __restrict__ Wp, float* __restrict__ bias2)
{
    __shared__ float red[4];
    int j = blockIdx.x, t = threadIdx.x;
    const float Ninv = 1.f / 2097152.f;   // 128*256*64
    float partial = 0.f;
    for (int k = t; k < 512; k += 256) {
        int h = k >> 6;
        float m = gnstat[h * 2] * Ninv;
        float var = gnstat[h * 2 + 1] * Ninv - m * m;
        float siv = rsqrtf(var + 1e-5f);
        float s = siv * gn_g[k];
        float tt = gn_b[k] - m * s;
        float wv = mw[(size_t)k * 256 + j];
        Wp[(size_t)j * 512 + k] = f2b(s * wv);
        partial += tt * wv;
    }
    float tot = block_sum256(partial, red);
    if (t == 0) bias2[j] = tot;
}

__global__ void zero_kernel(float* __restrict__ p, int n) {
    int i = blockIdx.x * blockDim.x + threadIdx.x;
    if (i < n) p[i] = 0.f;
}

// ================================================================ launch
extern "C" void kernel_launch(void* const* d_in, const int* in_sizes, int n_in,
                              void* d_out, int out_size, void* d_ws, size_t ws_size,
                              hipStream_t stream) {
    if (ws_size < 77856896ULL) return;   // known-good minimum from R3/R4
    const bool BIG = (ws_size >= 184549376ULL);  // de-fused cm path needs 96MB hidden

    const float* u        = (const float*)d_in[0];
    const float* lat      = (const float*)d_in[1];
    const float* lon      = (const float*)d_in[2];
    const float* cm_w1    = (const float*)d_in[3];
    const float* cm_b1    = (const float*)d_in[4];
    const float* cm_w2    = (const float*)d_in[5];
    const float* cm_b2    = (const float*)d_in[6];
    const float* long_in_w  = (const float*)d_in[7];
    const float* long_ln_g  = (const float*)d_in[8];
    const float* long_ln_b  = (const float*)d_in[9];
    const float* long_fc1_w = (const float*)d_in[10];
    const float* long_fc1_b = (const float*)d_in[11];
    const float* long_fc2_w = (const float*)d_in[12];
    const float* long_fc2_b = (const float*)d_in[13];
    const float* lat_in_w   = (const float*)d_in[14];
    const float* lat_ln_g   = (const float*)d_in[15];
    const float* lat_ln_b   = (const float*)d_in[16];
    const float* lat_fc1_w  = (const float*)d_in[17];
    const float* lat_fc1_b  = (const float*)d_in[18];
    const float* lat_fc2_w  = (const float*)d_in[19];
    const float* lat_fc2_b  = (const float*)d_in[20];
    const float* klong_q_w  = (const float*)d_in[21];
    const float* klong_k_w  = (const float*)d_in[22];
    const float* klat_q_w   = (const float*)d_in[23];
    const float* klat_k_w   = (const float*)d_in[24];
    const float* pe_long_freq = (const float*)d_in[25];
    const float* pe_long_w    = (const float*)d_in[26];
    const float* pe_lat_freq  = (const float*)d_in[27];
    const float* pe_lat_w     = (const float*)d_in[28];
    const float* gn_g    = (const float*)d_in[29];
    const float* gn_b    = (const float*)d_in[30];
    const float* merge_w = (const float*)d_in[31];
    const float* out_w   = (const float*)d_in[32];
    float* out = (float*)d_out;

    char* base = (char*)d_ws;
    u16*  vA   = (u16*)base;                          // v bf16 (32MB) -> Aout bf16 (32MB)
    char* reg1 = base + 33554432;                     // ubf bf16 (16MB) -> uu bf16 (16MB) -> tmp1 bf16 (32MB) -> Dbf bf16 (16MB)
    u16*  ubf  = (u16*)reg1;
    u16*  uu   = (u16*)reg1;
    u16*  tmp1 = (u16*)reg1;
    u16*  Dbf  = (u16*)reg1;
    // small pool (floats from base+64MB); end = 76,940,416 B < 77,856,896 guard
    float* pool    = (float*)(base + 67108864);
    float* modlong = pool;                            // 524288
    float* modlat  = modlong + 524288;                // 131072
    float* Mlong   = modlat + 131072;                 // 65536
    float* Mlat    = Mlong + 65536;                   // 32768 (contiguous after Mlong)
    float* ulong   = Mlat + 32768;                    // 65536
    float* ulat    = ulong + 65536;                   // 32768
    float* qlong   = ulat + 32768;                    // 393216
    float* klongp  = qlong + 393216;                  // 393216
    float* qlat    = klongp + 393216;                 // 196608
    float* klatp   = qlat + 196608;                   // 196608
    float* gnstat  = klatp + 196608;                  // 32
    float* bias2   = gnstat + 32;                     // 256
    u16* KlongA = (u16*)(bias2 + 256);                // 524288 elems (1MB)
    u16* KlatA  = KlongA + 524288;                    // 131072 elems
    u16* Wp     = KlatA + 131072;                     // 131072 elems
    u16* owT    = Wp + 131072;                        // 65536 elems
    // small-path weight aliases (dead at cm time, re-converted per batch)
    u16* w1T = (u16*)qlong;                           // 786,432 B in qlong (1.5MB)
    u16* w2T = (u16*)klongp;                          // 3,145,728 B in klongp+qlat+klatp
    // big-path dedicated regions
    u16* w1Tb   = (u16*)(base + 79691776);            // 786,432 B
    u16* w2Tb   = (u16*)(base + 80478208);            // 3,145,728 B
    u16* hidden = (u16*)(base + 83886080);            // 100,663,296 B (32768x1536 bf16)
    // kp transposes live in hidden (dead between GEMM2 and next batch's GEMM1)
    float* klT = (float*)hidden;                      // 393,216 floats [1536][256]
    float* kaT = klT + 393216;                        // 196,608 floats [1536][128]

    zero_kernel<<<1, 32, 0, stream>>>(gnstat, 32);
    bessel_kernel<<<256, 256, 0, stream>>>(lon, 256, pe_long_freq, 64, pe_long_w, modlong, 1);
    bessel_kernel<<<128, 128, 0, stream>>>(lat, 128, pe_lat_freq, 32, pe_lat_w, modlat, 0);
    // owT[256][256] <- out_w^T (coalesced)
    transpose_f32_bf16_kernel<<<dim3(8, 8), 256, 0, stream>>>(out_w, owT, 256, 256);
    if (BIG) {
        // w1Tb[1536][256] <- cm_w1^T; w2Tb[1024][1536] <- cm_w2^T (coalesced)
        transpose_f32_bf16_kernel<<<dim3(48, 8), 256, 0, stream>>>(cm_w1, w1Tb, 256, 1536);
        transpose_f32_bf16_kernel<<<dim3(32, 48), 256, 0, stream>>>(cm_w2, w2Tb, 1536, 1024);
    }

    for (int b = 0; b < 2; ++b) {
        const float* u_b  = u + (size_t)b * 32768 * 256;
        float* uskip_b    = out + (size_t)b * 8388608;
        float* gnstat_b   = gnstat + b * 16;

        if (BIG) {
            // u -> bf16 once (bit-identical to the old in-GEMM pack)
            conv_ubf_kernel<<<8192, 256, 0, stream>>>(u_b, ubf);
            // GEMM1: hidden = gelu(u@W1+b1)  [32768 x 1536], K=256, NCOL=12
            gemm128_kernel<256, 0, false, 12><<<3072, 256, 0, stream>>>(
                ubf, w1Tb, cm_b1, nullptr, hidden, nullptr, nullptr);
            // GEMM2: hidden@W2+b2 -> v|uu|uskip  [32768 x 1024], K=1536, NCOL=8
            gemm128_kernel<1536, 1, false, 8><<<2048, 256, 0, stream>>>(
                hidden, w2Tb, cm_b2, nullptr, vA, uu, uskip_b);
        } else {
            transpose_f32_bf16_kernel<<<dim3(48, 8), 256, 0, stream>>>(cm_w1, w1T, 256, 1536);
            transpose_f32_bf16_kernel<<<dim3(32, 48), 256, 0, stream>>>(cm_w2, w2T, 1536, 1024);
            cm_mlp_mfma_kernel<<<2048, 256, 0, stream>>>(u_b, w1T, cm_b1, w2T, cm_b2,
                                                         vA, uu, uskip_b);
        }
        // zero Mlong+Mlat (contiguous 98304 floats), then split-fused means
        zero_kernel<<<384, 256, 0, stream>>>(Mlong, 98304);
        mean_fused_kernel<<<3072, 256, 0, stream>>>(uu, Mlong, Mlat);
        // both pool MLPs in one launch
        pool_fused_kernel<<<384, 256, 0, stream>>>(
            Mlong, Mlat,
            long_in_w, long_ln_g, long_ln_b, long_fc1_w, long_fc1_b, long_fc2_w, long_fc2_b,
            lat_in_w,  lat_ln_g,  lat_ln_b,  lat_fc1_w,  lat_fc1_b,  lat_fc2_w,  lat_fc2_b,
            lat, ulong, ulat);
        // all 4 projections in one launch (clobbers w1T/w2T regions — dead)
        proj_tile4_kernel<<<dim3(32, 6, 4), 256, 0, stream>>>(
            ulong, ulat, klong_q_w, klong_k_w, klat_q_w, klat_k_w,
            qlong, klongp, qlat, klatp);
        if (BIG) {
            // transpose both k-projections (hidden region is dead here), then coalesced kmat
            kpT_kernel<<<dim3(48, 12), 256, 0, stream>>>(klongp, klatp, klT, kaT);
            kmat_fusedT_kernel<<<3072, 256, 0, stream>>>(
                qlong, klT, modlong, KlongA,
                qlat, kaT, modlat, lat, KlatA);
        } else {
            kmat_fused_kernel<<<3072, 256, 0, stream>>>(
                qlong, klongp, modlong, KlongA,
                qlat, klatp, modlat, lat, KlatA);
        }
        einsum1_kernel<<<2048, 256, 0, stream>>>(KlatA, vA, tmp1);       // tmp1 over uu (dead)
        einsum2_kernel<<<1024, 256, 0, stream>>>(tmp1, KlongA, vA, gnstat_b); // Aout over v (dead)
        gn_fold_kernel<<<256, 256, 0, stream>>>(gnstat_b, gn_g, gn_b, merge_w, Wp, bias2);
        // merge: Dbf = bf16(GN(Aout)@mw + uskip)   [32768 x 256], K=512, NCOL=2
        gemm128_kernel<512, 4, false, 2><<<512, 256, 0, stream>>>(
            vA, Wp, bias2, uskip_b, Dbf, nullptr, nullptr);
        // out: out = Dbf@ow                [32768 x 256], K=256, NCOL=2
        gemm128_kernel<256, 3, false, 2><<<512, 256, 0, stream>>>(
            Dbf, owT, nullptr, nullptr, out + (size_t)b * 8388608, nullptr, nullptr);
    }
}